// Round 17
// baseline (563.355 us; speedup 1.0000x reference)
//
#include <hip/hip_runtime.h>
#include <math.h>

constexpr int B_ = 4;
constexpr int C_ = 128;
constexpr int HW_ = 16384;
constexpr int W_ = 128;
constexpr int M_ = 6;
constexpr int TDIM_ = 64;
constexpr int NT_ = 1; // NUM_TASKS

static __device__ __forceinline__ float gelu_f(float x){
  return 0.5f * x * (1.0f + erff(x * 0.7071067811865476f));
}
static __device__ __forceinline__ int imin(int a, int b){ return a < b ? a : b; }

// ---------- block reduce (256 threads) ----------
static __device__ __forceinline__ float block_reduce_sum256(float v, float* lds){
  int t = threadIdx.x;
  lds[t] = v; __syncthreads();
  for (int s = 128; s > 0; s >>= 1){ if (t < s) lds[t] += lds[t + s]; __syncthreads(); }
  float r = lds[0]; __syncthreads();
  return r;
}

// ---------- align-corners bilinear resize ----------
__global__ void k_resize(const float* __restrict__ in, float* __restrict__ out,
                         int BC, int Hi, int Wi, int Ho, int Wo){
  int idx = blockIdx.x * 256 + threadIdx.x;
  int total = BC * Ho * Wo;
  if (idx >= total) return;
  int xo = idx % Wo; int yo = (idx / Wo) % Ho; int bc = idx / (Wo * Ho);
  float sy = (Ho > 1) ? yo * (float)(Hi - 1) / (float)(Ho - 1) : 0.f;
  float sx = (Wo > 1) ? xo * (float)(Wi - 1) / (float)(Wo - 1) : 0.f;
  int y0 = (int)floorf(sy); int y1 = imin(y0 + 1, Hi - 1); float wy = sy - (float)y0;
  int x0 = (int)floorf(sx); int x1 = imin(x0 + 1, Wi - 1); float wx = sx - (float)x0;
  const float* p = in + (size_t)bc * Hi * Wi;
  float a = p[y0 * Wi + x0], b = p[y1 * Wi + x0];
  float c = p[y0 * Wi + x1], d = p[y1 * Wi + x1];
  float t0 = a * (1.f - wy) + b * wy;
  float t1 = c * (1.f - wy) + d * wy;
  out[idx] = t0 * (1.f - wx) + t1 * wx;
}

// ---------- stats finalize ----------
__global__ void k_stat2(const float* __restrict__ ps, const float* __restrict__ pq,
                        float* __restrict__ gm, float* __restrict__ gi,
                        int nper, float nelem){
  int idx = blockIdx.x; int t = threadIdx.x;
  __shared__ float l1[128], l2[128];
  float s = 0.f, ss = 0.f;
  for (int i = t; i < nper; i += 128){ s += ps[idx * nper + i]; ss += pq[idx * nper + i]; }
  l1[t] = s; l2[t] = ss; __syncthreads();
  for (int st = 64; st > 0; st >>= 1){
    if (t < st){ l1[t] += l1[t + st]; l2[t] += l2[t + st]; }
    __syncthreads();
  }
  if (t == 0){
    float mu = l1[0] / nelem;
    float var = l2[0] / nelem - mu * mu;
    gm[idx] = mu; gi[idx] = rsqrtf(var + 1e-5f);
  }
}

// ---------- dual stats finalize ----------
__global__ void k_stat2_dual(const float* __restrict__ psA, const float* __restrict__ pqA,
                             float* __restrict__ gmA, float* __restrict__ giA, float nelemA,
                             const float* __restrict__ psB, const float* __restrict__ pqB,
                             float* __restrict__ gmB, float* __restrict__ giB, float nelemB){
  int idx = blockIdx.x; int t = threadIdx.x;
  __shared__ float l1[128], l2[128];
  const float* ps; const float* pq; float* gm; float* gi; float nelem; int id2;
  if (idx < 4){ ps = psA; pq = pqA; gm = gmA; gi = giA; nelem = nelemA; id2 = idx; }
  else        { ps = psB; pq = pqB; gm = gmB; gi = giB; nelem = nelemB; id2 = idx - 4; }
  float s = 0.f, ss = 0.f;
  for (int i = t; i < 256; i += 128){ s += ps[id2 * 256 + i]; ss += pq[id2 * 256 + i]; }
  l1[t] = s; l2[t] = ss; __syncthreads();
  for (int st = 64; st > 0; st >>= 1){
    if (t < st){ l1[t] += l1[t + st]; l2[t] += l2[t + st]; }
    __syncthreads();
  }
  if (t == 0){
    float mu = l1[0] / nelem;
    float var = l2[0] / nelem - mu * mu;
    gm[id2] = mu; gi[id2] = rsqrtf(var + 1e-5f);
  }
}

// ---------- merged weight transposes ----------
__global__ void k_wtall(const float* __restrict__ ph_w, const float* __restrict__ pl_w,
                        const float* __restrict__ fu_w, const float* __restrict__ se_w2,
                        float* __restrict__ wTph, float* __restrict__ wTpl,
                        float* __restrict__ wTfu, float* __restrict__ wTse){
  int idx = blockIdx.x * 256 + threadIdx.x;
  if (idx < 16384){
    int ci = idx / 128, co = idx % 128;
    wTph[idx] = ph_w[co * 128 + ci];
  } else if (idx < 20480){
    int r = idx - 16384; int ci = r / 64, co = r % 64;
    wTpl[r] = pl_w[co * 64 + ci];
  } else if (idx < 45056){
    int r = idx - 20480; int ci = r / 128, co = r % 128;
    wTfu[r] = fu_w[(size_t)co * 192 + ci];
  } else if (idx < 61440){
    int r = idx - 45056; int ci = r / 128, co = r % 128;
    wTse[r] = se_w2[co * 128 + ci];
  }
}

// ---------- shared GEMM body (raw input, K-chunk 16) --------
template<int CO, int CIT>
static __device__ __forceinline__ void gemm_body(
    const float* __restrict__ in1, const float* __restrict__ wT,
    float* __restrict__ out, float* __restrict__ psum, float* __restrict__ psq,
    int b, int j0, int slot, float* As, float* Bs, float* red){
  const int tid = threadIdx.x;
  const int tj = tid & 15, tco = tid >> 4;
  constexpr int CPT = CO / 16;
  constexpr int AST = CO + 4;
  float acc[CPT][4];
  #pragma unroll
  for (int i = 0; i < CPT; ++i)
    #pragma unroll
    for (int j = 0; j < 4; ++j) acc[i][j] = 0.f;

  for (int k0 = 0; k0 < CIT; k0 += 16){
    const int kk = tid >> 4;
    if constexpr (CO == 128){
      int co = (tid & 15) * 8;
      const float* wp = &wT[(size_t)(k0 + kk) * CO + co];
      *(float4*)&As[kk * AST + co] = *(const float4*)wp;
      *(float4*)&As[kk * AST + co + 4] = *(const float4*)(wp + 4);
    } else {
      int co = (tid & 15) * 4;
      *(float4*)&As[kk * AST + co] = *(const float4*)&wT[(size_t)(k0 + kk) * CO + co];
    }
    {
      int jj = (tid & 15) * 4;
      int ci = k0 + kk;
      float4 v = *(const float4*)&in1[((size_t)b * CIT + ci) * HW_ + j0 + jj];
      *(float4*)&Bs[kk * 68 + jj] = v;
    }
    __syncthreads();
    #pragma unroll
    for (int kkk = 0; kkk < 16; ++kkk){
      float4 bq = *(const float4*)&Bs[kkk * 68 + tj * 4];
      float av[CPT];
      if constexpr (CPT == 8){
        float4 a0 = *(const float4*)&As[kkk * AST + tco * 8];
        float4 a1 = *(const float4*)&As[kkk * AST + tco * 8 + 4];
        av[0] = a0.x; av[1] = a0.y; av[2] = a0.z; av[3] = a0.w;
        av[4] = a1.x; av[5] = a1.y; av[6] = a1.z; av[7] = a1.w;
      } else {
        float4 a0 = *(const float4*)&As[kkk * AST + tco * 4];
        av[0] = a0.x; av[1] = a0.y; av[2] = a0.z; av[3] = a0.w;
      }
      #pragma unroll
      for (int i = 0; i < CPT; ++i){
        acc[i][0] = fmaf(av[i], bq.x, acc[i][0]);
        acc[i][1] = fmaf(av[i], bq.y, acc[i][1]);
        acc[i][2] = fmaf(av[i], bq.z, acc[i][2]);
        acc[i][3] = fmaf(av[i], bq.w, acc[i][3]);
      }
    }
    __syncthreads();
  }
  float s = 0.f, ss = 0.f;
  #pragma unroll
  for (int i = 0; i < CPT; ++i){
    int co = tco * CPT + i;
    float4 o;
    o.x = acc[i][0]; o.y = acc[i][1]; o.z = acc[i][2]; o.w = acc[i][3];
    *(float4*)&out[((size_t)b * CO + co) * HW_ + j0 + tj * 4] = o;
    s += o.x + o.y + o.z + o.w;
    ss += o.x * o.x + o.y * o.y + o.z * o.z + o.w * o.w;
  }
  s = block_reduce_sum256(s, red);
  ss = block_reduce_sum256(ss, red);
  if (tid == 0){ psum[slot] = s; psq[slot] = ss; }
}

// ---------- dual GEMM: ph (128->128) || pl (64->64), 2048 blocks -------------
__global__ __launch_bounds__(256, 4) void k_gemm_dual(
    const float* __restrict__ in_ph, const float* __restrict__ wT_ph,
    float* __restrict__ out_ph, float* __restrict__ psA, float* __restrict__ pqA,
    const float* __restrict__ in_pl, const float* __restrict__ wT_pl,
    float* __restrict__ out_pl, float* __restrict__ psB, float* __restrict__ pqB){
  __shared__ float As[16 * 132];
  __shared__ float Bs[16 * 68];
  __shared__ float red[256];
  int b = blockIdx.x;
  if (blockIdx.y < 256){
    int yb = blockIdx.y;
    gemm_body<128, 128>(in_ph, wT_ph, out_ph, psA, pqA, b, yb * 64, b * 256 + yb, As, Bs, red);
  } else {
    int yb = blockIdx.y - 256;
    gemm_body<64, 64>(in_pl, wT_pl, out_pl, psB, pqB, b, yb * 64, b * 256 + yb, As, Bs, red);
  }
}

// ---------- tiled 1x1-conv GEMM (K-chunk 16) with GN+GELU on input -----------
template<int CO, int CIT>
__global__ __launch_bounds__(256, 4) void k_gemm1x1(
    const float* __restrict__ in1, const float* __restrict__ in2, int CI1,
    const float* __restrict__ wT, const float* __restrict__ bias,
    const float* __restrict__ gm1, const float* __restrict__ gi1,
    const float* __restrict__ ga1, const float* __restrict__ be1, int sh1, int ng1,
    const float* __restrict__ gm2, const float* __restrict__ gi2,
    const float* __restrict__ ga2, const float* __restrict__ be2, int sh2, int ng2,
    float* __restrict__ out, float* __restrict__ psum, float* __restrict__ psq){
  __shared__ float As[16][CO + 4];
  __shared__ float Bs[16][68];
  __shared__ float red[256];
  const int b = blockIdx.x;
  const int j0 = blockIdx.y * 64;
  const int tid = threadIdx.x;
  const int tj = tid & 15, tco = tid >> 4;
  constexpr int CPT = CO / 16;

  float acc[CPT][4];
  #pragma unroll
  for (int i = 0; i < CPT; ++i)
    #pragma unroll
    for (int j = 0; j < 4; ++j) acc[i][j] = 0.f;

  for (int k0 = 0; k0 < CIT; k0 += 16){
    const int kk = tid >> 4;
    if constexpr (CO == 128){
      int co = (tid & 15) * 8;
      const float* wp = &wT[(size_t)(k0 + kk) * CO + co];
      *(float4*)&As[kk][co] = *(const float4*)wp;
      *(float4*)&As[kk][co + 4] = *(const float4*)(wp + 4);
    } else {
      int co = (tid & 15) * 4;
      *(float4*)&As[kk][co] = *(const float4*)&wT[(size_t)(k0 + kk) * CO + co];
    }
    {
      int jj = (tid & 15) * 4;
      int ci = k0 + kk;
      float4 v;
      if (ci < CI1){
        v = *(const float4*)&in1[((size_t)b * CI1 + ci) * HW_ + j0 + jj];
        if (gm1){
          int g = ci >> sh1;
          float rs = gi1[b * ng1 + g];
          float ga = ga1[ci] * rs;
          float be = be1[ci] - gm1[b * ng1 + g] * ga;
          v.x = gelu_f(fmaf(v.x, ga, be)); v.y = gelu_f(fmaf(v.y, ga, be));
          v.z = gelu_f(fmaf(v.z, ga, be)); v.w = gelu_f(fmaf(v.w, ga, be));
        }
      } else {
        int c2 = ci - CI1;
        v = *(const float4*)&in2[((size_t)b * (CIT - CI1) + c2) * HW_ + j0 + jj];
        if (gm2){
          int g = c2 >> sh2;
          float rs = gi2[b * ng2 + g];
          float ga = ga2[c2] * rs;
          float be = be2[c2] - gm2[b * ng2 + g] * ga;
          v.x = gelu_f(fmaf(v.x, ga, be)); v.y = gelu_f(fmaf(v.y, ga, be));
          v.z = gelu_f(fmaf(v.z, ga, be)); v.w = gelu_f(fmaf(v.w, ga, be));
        }
      }
      *(float4*)&Bs[kk][jj] = v;
    }
    __syncthreads();
    #pragma unroll
    for (int kkk = 0; kkk < 16; ++kkk){
      float4 bq = *(const float4*)&Bs[kkk][tj * 4];
      float av[CPT];
      if constexpr (CPT == 8){
        float4 a0 = *(const float4*)&As[kkk][tco * 8];
        float4 a1 = *(const float4*)&As[kkk][tco * 8 + 4];
        av[0] = a0.x; av[1] = a0.y; av[2] = a0.z; av[3] = a0.w;
        av[4] = a1.x; av[5] = a1.y; av[6] = a1.z; av[7] = a1.w;
      } else {
        float4 a0 = *(const float4*)&As[kkk][tco * 4];
        av[0] = a0.x; av[1] = a0.y; av[2] = a0.z; av[3] = a0.w;
      }
      #pragma unroll
      for (int i = 0; i < CPT; ++i){
        acc[i][0] = fmaf(av[i], bq.x, acc[i][0]);
        acc[i][1] = fmaf(av[i], bq.y, acc[i][1]);
        acc[i][2] = fmaf(av[i], bq.z, acc[i][2]);
        acc[i][3] = fmaf(av[i], bq.w, acc[i][3]);
      }
    }
    __syncthreads();
  }
  float s = 0.f, ss = 0.f;
  #pragma unroll
  for (int i = 0; i < CPT; ++i){
    int co = tco * CPT + i;
    float bb = bias ? bias[co] : 0.f;
    float4 o;
    o.x = acc[i][0] + bb; o.y = acc[i][1] + bb;
    o.z = acc[i][2] + bb; o.w = acc[i][3] + bb;
    *(float4*)&out[((size_t)b * CO + co) * HW_ + j0 + tj * 4] = o;
    s += o.x + o.y + o.z + o.w;
    ss += o.x * o.x + o.y * o.y + o.z * o.z + o.w * o.w;
  }
  if (psum){
    s = block_reduce_sum256(s, red);
    ss = block_reduce_sum256(ss, red);
    if (tid == 0){
      psum[b * gridDim.y + blockIdx.y] = s;
      psq [b * gridDim.y + blockIdx.y] = ss;
    }
  }
}

// ---------- grouped 3x3 conv, windowed float4 reads --------------------------
// R16 diagnosis: old inner loop = 36 scalar ds_read_b32 per output -> LDS-issue
// bound (~45us of pipe time; VALUBusy 33%, occupancy insensitive). New: thread
// owns (co_l, row-half, 4-col strip) = 16 outputs; per (cil,xsrow) build 6-wide
// window from 1 ds_read_b128 + 2 guarded b32 -> 72 LDS instrs/thread (was 576).
__global__ __launch_bounds__(256) void k_se3(const float* __restrict__ x,
    const float* __restrict__ gm, const float* __restrict__ gi,
    const float* __restrict__ gamma, const float* __restrict__ beta,
    const float* __restrict__ w, const float* __restrict__ bias,
    float* __restrict__ out, float* __restrict__ psum, float* __restrict__ psq){
  __shared__ float xs[4][10][128];
  __shared__ float ws[144];
  __shared__ float wb[4];
  __shared__ float red[256];
  const int bgc = blockIdx.x; const int b = bgc >> 5, gc = bgc & 31;
  const int r0 = blockIdx.y * 8;
  const int tid = threadIdx.x;
  const float mu = gm[b], rs = gi[b];
  for (int ch = 0; ch < 4; ++ch){
    int c = gc * 4 + ch;
    float ga = gamma[c] * rs, be = beta[c] - mu * rs * gamma[c];
    const float* px = x + ((size_t)b * C_ + c) * HW_;
    for (int i = tid; i < 10 * 128; i += 256){
      int rr = i >> 7, cc = i & 127;
      int row = r0 - 1 + rr;
      float v = 0.f;
      if ((unsigned)row < 128u) v = gelu_f(fmaf(px[row * W_ + cc], ga, be));
      xs[ch][rr][cc] = v;
    }
  }
  if (tid < 144) ws[tid] = w[(size_t)(gc * 4) * 36 + tid];
  if (tid < 4)   wb[tid] = bias[gc * 4 + tid];
  __syncthreads();
  const int co_l = tid >> 6;        // 0..3 (wave-uniform)
  const int half = (tid >> 5) & 1;  // 0..1
  const int c4 = (tid & 31) * 4;    // 0,4,...,124
  float acc[4][4];
  {
    float bb = wb[co_l];
    #pragma unroll
    for (int r = 0; r < 4; ++r)
      #pragma unroll
      for (int cc = 0; cc < 4; ++cc) acc[r][cc] = bb;
  }
  #pragma unroll
  for (int cil = 0; cil < 4; ++cil){
    float w9[9];
    #pragma unroll
    for (int i = 0; i < 9; ++i) w9[i] = ws[(co_l * 4 + cil) * 9 + i];
    #pragma unroll
    for (int rr = 0; rr < 6; ++rr){
      int xsrow = half * 4 + rr;
      float4 cen = *(const float4*)&xs[cil][xsrow][c4];
      float left  = (c4 > 0)   ? xs[cil][xsrow][c4 - 1] : 0.f;
      float right = (c4 < 124) ? xs[cil][xsrow][c4 + 4] : 0.f;
      float win[6] = {left, cen.x, cen.y, cen.z, cen.w, right};
      #pragma unroll
      for (int r = 0; r < 4; ++r){
        int ky = rr - r;
        if (ky < 0 || ky > 2) continue;
        #pragma unroll
        for (int cc = 0; cc < 4; ++cc){
          acc[r][cc] = fmaf(w9[ky * 3 + 0], win[cc],     acc[r][cc]);
          acc[r][cc] = fmaf(w9[ky * 3 + 1], win[cc + 1], acc[r][cc]);
          acc[r][cc] = fmaf(w9[ky * 3 + 2], win[cc + 2], acc[r][cc]);
        }
      }
    }
  }
  float s = 0.f, ss = 0.f;
  #pragma unroll
  for (int r = 0; r < 4; ++r){
    int row = r0 + half * 4 + r;
    float4 o = {acc[r][0], acc[r][1], acc[r][2], acc[r][3]};
    *(float4*)&out[((size_t)b * C_ + gc * 4 + co_l) * HW_ + row * W_ + c4] = o;
    s += o.x + o.y + o.z + o.w;
    ss += o.x * o.x + o.y * o.y + o.z * o.z + o.w * o.w;
  }
  s = block_reduce_sum256(s, red);
  ss = block_reduce_sum256(ss, red);
  if (tid == 0){
    int idx = (b * 4 + (gc >> 3)) * 128 + (gc & 7) * 16 + blockIdx.y;
    psum[idx] = s; psq[idx] = ss;
  }
}

// ---------- fused: x_enh -> y (3x3 dyn) -> h (3x3 dw) + GN stats for h -------
__global__ __launch_bounds__(256) void k_ydw(const float* __restrict__ x,
    const float* __restrict__ factor,
    const float* __restrict__ gm, const float* __restrict__ gi,
    const float* __restrict__ gamma, const float* __restrict__ beta,
    const float* __restrict__ w_eff, const float* __restrict__ dw_w,
    const float* __restrict__ dw_b, float* __restrict__ y_out,
    float* __restrict__ h_out, float* __restrict__ psum, float* __restrict__ psq){
  __shared__ float xs[36][128];
  __shared__ float ys[34][128];
  __shared__ float red[256];
  const int bc = blockIdx.x; const int b = bc >> 7, c = bc & 127;
  const int r0 = blockIdx.y * 32;
  const int tid = threadIdx.x;
  const float mu = gm[b], rs = gi[b];
  const float ga = gamma[c] * rs, be = beta[c] - mu * rs * gamma[c];
  const float* px = x + ((size_t)b * C_ + c) * HW_;
  const float* pf = factor + (size_t)b * HW_;
  for (int i = tid; i < 36 * 128; i += 256){
    int rr = i >> 7, cc = i & 127;
    int row = r0 - 2 + rr;
    float v = 0.f;
    if ((unsigned)row < 128u)
      v = gelu_f(fmaf(px[row * W_ + cc], ga, be)) * pf[row * W_ + cc];
    xs[rr][cc] = v;
  }
  __syncthreads();
  float w9[9];
  #pragma unroll
  for (int r = 0; r < 9; ++r) w9[r] = w_eff[b * 1152 + c * 9 + r];
  for (int i = tid; i < 34 * 128; i += 256){
    int rr = i >> 7, cc = i & 127;
    int row = r0 - 1 + rr;
    float acc = 0.f;
    if ((unsigned)row < 128u){
      #pragma unroll
      for (int ky = 0; ky < 3; ++ky){
        #pragma unroll
        for (int kx = 0; kx < 3; ++kx){
          int xc = cc + kx - 1;
          if ((unsigned)xc < 128u) acc += w9[ky * 3 + kx] * xs[rr + ky][xc];
        }
      }
    }
    ys[rr][cc] = acc;
    if (rr >= 1 && rr <= 32)
      y_out[((size_t)b * C_ + c) * HW_ + row * W_ + cc] = acc;
  }
  __syncthreads();
  float wd[9];
  #pragma unroll
  for (int r = 0; r < 9; ++r) wd[r] = dw_w[c * 9 + r];
  const float bb = dw_b[c];
  float s = 0.f, ss = 0.f;
  for (int i = tid; i < 32 * 128; i += 256){
    int rr = i >> 7, cc = i & 127;
    int row = r0 + rr;
    float acc = bb;
    #pragma unroll
    for (int ky = 0; ky < 3; ++ky){
      #pragma unroll
      for (int kx = 0; kx < 3; ++kx){
        int yc = cc + kx - 1;
        if ((unsigned)yc < 128u) acc += wd[ky * 3 + kx] * ys[rr + ky][yc];
      }
    }
    h_out[((size_t)b * C_ + c) * HW_ + row * W_ + cc] = acc;
    s += acc; ss += acc * acc;
  }
  s = block_reduce_sum256(s, red);
  ss = block_reduce_sum256(ss, red);
  if (tid == 0){
    int idx = b * 512 + c * 4 + blockIdx.y;
    psum[idx] = s; psq[idx] = ss;
  }
}

// ---------- prototype init MLP (per b) ----------
__global__ void k_pinit(const float* __restrict__ temb, const float* __restrict__ w1,
                        const float* __restrict__ b1, const float* __restrict__ w2,
                        const float* __restrict__ b2, float* __restrict__ pinit){
  int b = blockIdx.x; int t = threadIdx.x;
  __shared__ float h1[256], p2[256], nrm[2];
  float acc = b1[t];
  for (int i = 0; i < TDIM_; ++i) acc += temb[b * TDIM_ + i] * w1[t * TDIM_ + i];
  h1[t] = gelu_f(acc); __syncthreads();
  acc = b2[t];
  for (int i = 0; i < 256; ++i) acc += h1[i] * w2[t * 256 + i];
  p2[t] = acc; __syncthreads();
  if (t < 2){
    float s = 0.f;
    for (int c = 0; c < 128; ++c){ float v = p2[t * 128 + c]; s += v * v; }
    nrm[t] = fmaxf(sqrtf(s), 1e-12f);
  }
  __syncthreads();
  pinit[b * 256 + t] = p2[t] / nrm[t / 128];
}

// ---------- table / protos / fg,bg ----------
__global__ void k_protos(const float* __restrict__ pinit, const int* __restrict__ task_ids,
                         float* __restrict__ fg, float* __restrict__ bg){
  __shared__ int tbl[NT_];
  __shared__ int src[B_];
  __shared__ float nr[B_ * 2];
  int t = threadIdx.x;
  if (t < NT_){
    int idx = 0;
    for (int b = B_ - 1; b >= 0; --b) if (task_ids[b] == t) idx = b;
    tbl[t] = idx;
  }
  __syncthreads();
  if (t < B_){
    int ti = task_ids[t]; ti = ti < 0 ? 0 : (ti >= NT_ ? NT_ - 1 : ti);
    src[t] = tbl[ti];
  }
  __syncthreads();
  if (t < 2 * B_){
    int b = t / 2, r = t % 2;
    float s = 0.f;
    for (int c = 0; c < 128; ++c){ float v = pinit[src[b] * 256 + r * 128 + c]; s += v * v; }
    nr[t] = fmaxf(sqrtf(s), 1e-12f);
  }
  __syncthreads();
  for (int i = t; i < B_ * 128; i += 256){
    int b = i / 128, c = i % 128;
    fg[i] = pinit[src[b] * 256 + c] / nr[b * 2 + 0];
    bg[i] = pinit[src[b] * 256 + 128 + c] / nr[b * 2 + 1];
  }
}

// ---------- q projection folded into key space ----------
__global__ void k_qk(const float* __restrict__ fg, const float* __restrict__ bg,
                     const float* __restrict__ at_in_w, const float* __restrict__ at_in_b,
                     float* __restrict__ qkvec, float* __restrict__ kdot){
  int b = blockIdx.x, t = threadIdx.x;
  __shared__ float pq[256], qf[256];
  pq[t] = (t < 128) ? fg[b * 128 + t] : bg[b * 128 + (t - 128)];
  __syncthreads();
  {
    int qi = t / 128, o = t % 128;
    float acc = at_in_b[o];
    const float* wr = at_in_w + (size_t)o * 128;
    for (int c = 0; c < 128; ++c) acc += wr[c] * pq[qi * 128 + c];
    qf[qi * 128 + o] = acc;
  }
  __syncthreads();
  for (int e = t; e < 1024; e += 256){
    int p = e / 128, c = e % 128, qi = p / 4, h = p % 4;
    float acc = 0.f;
    for (int d = 0; d < 32; ++d)
      acc += qf[qi * 128 + h * 32 + d] * at_in_w[(size_t)(128 + h * 32 + d) * 128 + c];
    qkvec[b * 1024 + e] = acc;
  }
  if (t < 8){
    int qi = t / 4, h = t % 4;
    float acc = 0.f;
    for (int d = 0; d < 32; ++d) acc += qf[qi * 128 + h * 32 + d] * at_in_b[128 + h * 32 + d];
    kdot[b * 8 + t] = acc;
  }
}

// ---------- fused: sim + factor + 8 score rows + |sim| partials --------------
__global__ __launch_bounds__(256) void k_simscores(const float* __restrict__ sf,
                          const float* __restrict__ fg, const float* __restrict__ bg,
                          const float* __restrict__ qkvec, const float* __restrict__ kdot,
                          float* __restrict__ sim, float* __restrict__ factor,
                          float* __restrict__ scores, float* __restrict__ psim){
  int b = blockIdx.x; int j = blockIdx.y * 256 + threadIdx.x;
  __shared__ float L[10 * 128];
  __shared__ float red[256];
  for (int i = threadIdx.x; i < 1280; i += 256){
    int r = i >> 7, c = i & 127;
    L[i] = (r == 0) ? fg[b * 128 + c]
         : (r == 1) ? bg[b * 128 + c]
                    : qkvec[b * 1024 + (r - 2) * 128 + c];
  }
  __syncthreads();
  const float* p = sf + (size_t)b * C_ * HW_ + j;
  float a0=0,a1=0,q0=0,q1=0,q2=0,q3=0,q4=0,q5=0,q6=0,q7=0,nn=0;
  #pragma unroll 8
  for (int c = 0; c < C_; ++c){
    float v = p[(size_t)c * HW_];
    nn += v * v;
    a0 += L[c] * v;          a1 += L[128 + c] * v;
    q0 += L[256 + c] * v;    q1 += L[384 + c] * v;
    q2 += L[512 + c] * v;    q3 += L[640 + c] * v;
    q4 += L[768 + c] * v;    q5 += L[896 + c] * v;
    q6 += L[1024 + c] * v;   q7 += L[1152 + c] * v;
  }
  float inv = 1.f / fmaxf(sqrtf(nn), 1e-12f);
  float sv = (a0 - a1) * inv;
  sim[b * HW_ + j] = sv;
  factor[b * HW_ + j] = 1.f + 0.5f / (1.f + expf(-sv));
  const float scale = 0.17677669529663689f;
  float qs[8] = {q0,q1,q2,q3,q4,q5,q6,q7};
  #pragma unroll
  for (int pp = 0; pp < 8; ++pp)
    scores[((size_t)(b * 8 + pp)) * HW_ + j] = (qs[pp] + kdot[b * 8 + pp]) * scale;
  float as = block_reduce_sum256(fabsf(sv), red);
  if (threadIdx.x == 0) psim[b * 64 + blockIdx.y] = as;
}

__global__ void k_smstats(const float* __restrict__ scores, float* __restrict__ smax,
                          float* __restrict__ ssum){
  __shared__ float lds[256];
  int row = blockIdx.x;
  const float* p = scores + (size_t)row * HW_;
  float m = -1e30f;
  for (int j = threadIdx.x; j < HW_; j += 256) m = fmaxf(m, p[j]);
  lds[threadIdx.x] = m; __syncthreads();
  for (int s = 128; s > 0; s >>= 1){
    if (threadIdx.x < s) lds[threadIdx.x] = fmaxf(lds[threadIdx.x], lds[threadIdx.x + s]);
    __syncthreads();
  }
  m = lds[0]; __syncthreads();
  float z = 0.f;
  for (int j = threadIdx.x; j < HW_; j += 256) z += expf(p[j] - m);
  z = block_reduce_sum256(z, lds);
  if (threadIdx.x == 0){ smax[row] = m; ssum[row] = z; }
}

// ---------- wsum, 4-way j-split ----------------------------------------------
__global__ void k_wsum(const float* __restrict__ sf, const float* __restrict__ scores,
                       const float* __restrict__ smax, const float* __restrict__ ssum,
                       float* __restrict__ wsum4){
  int bc = blockIdx.x; int b = bc / C_, c = bc % C_;
  int chunk = blockIdx.y;
  __shared__ float lds[8 * 256];
  __shared__ float mr[8], zr[8];
  if (threadIdx.x < 8){
    mr[threadIdx.x] = smax[b * 8 + threadIdx.x];
    zr[threadIdx.x] = 1.f / ssum[b * 8 + threadIdx.x];
  }
  __syncthreads();
  const float* p = sf + (size_t)bc * HW_;
  const float* sc = scores + (size_t)b * 8 * HW_;
  int j0 = chunk * (HW_ / 4), j1 = j0 + HW_ / 4;
  float acc[8] = {0,0,0,0,0,0,0,0};
  for (int j = j0 + threadIdx.x; j < j1; j += 256){
    float v = p[j];
    #pragma unroll
    for (int pp = 0; pp < 8; ++pp)
      acc[pp] = fmaf(expf(sc[(size_t)pp * HW_ + j] - mr[pp]) * zr[pp], v, acc[pp]);
  }
  #pragma unroll
  for (int pp = 0; pp < 8; ++pp) lds[pp * 256 + threadIdx.x] = acc[pp];
  __syncthreads();
  for (int s = 128; s > 0; s >>= 1){
    if (threadIdx.x < s){
      #pragma unroll
      for (int pp = 0; pp < 8; ++pp) lds[pp * 256 + threadIdx.x] += lds[pp * 256 + threadIdx.x + s];
    }
    __syncthreads();
  }
  if (threadIdx.x < 8)
    wsum4[chunk * 4096 + b * 1024 + threadIdx.x * 128 + c] = lds[threadIdx.x * 256];
}

// ---------- small head chain (sums the 4 wsum partials on load) --------------
__global__ void k_small(const float* __restrict__ wsum4, const float* __restrict__ at_in_w,
                        const float* __restrict__ at_in_b, const float* __restrict__ at_out_w,
                        const float* __restrict__ at_out_b, const float* __restrict__ pf_w,
                        const float* __restrict__ pf_b, const float* __restrict__ eg_w1,
                        const float* __restrict__ eg_b1, const float* __restrict__ ewg_w,
                        const float* __restrict__ ewg_b, float* __restrict__ eg1_out,
                        float* __restrict__ ew_out){
  int b = blockIdx.x; int t = threadIdx.x;
  __shared__ float wsl[1024], att[256], ao[256], pf[128], ewl[8];
  for (int i = t; i < 1024; i += 256)
    wsl[i] = wsum4[b * 1024 + i] + wsum4[4096 + b * 1024 + i]
           + wsum4[8192 + b * 1024 + i] + wsum4[12288 + b * 1024 + i];
  __syncthreads();
  {
    int qi = t / 128, o = t % 128, h = o / 32, d = o % 32, p = qi * 4 + h;
    float acc = at_in_b[256 + h * 32 + d];
    const float* wr = at_in_w + (size_t)(256 + h * 32 + d) * 128;
    for (int c = 0; c < 128; ++c) acc += wr[c] * wsl[p * 128 + c];
    att[qi * 128 + o] = acc;
  }
  __syncthreads();
  {
    int qi = t / 128, o = t % 128;
    float acc = at_out_b[o];
    const float* wr = at_out_w + (size_t)o * 128;
    for (int c = 0; c < 128; ++c) acc += wr[c] * att[qi * 128 + c];
    ao[qi * 128 + o] = acc;
  }
  __syncthreads();
  if (t < 128){
    float acc = pf_b[t];
    const float* wr = pf_w + (size_t)t * 384;
    for (int c = 0; c < 128; ++c){
      float fa = ao[c], ba = ao[128 + c];
      acc += wr[c] * fa + wr[128 + c] * ba + wr[256 + c] * (fa - ba);
    }
    pf[t] = acc;
  }
  __syncthreads();
  {
    float acc = eg_b1[t];
    const float* wr = eg_w1 + (size_t)t * 128;
    for (int c = 0; c < 128; ++c) acc += wr[c] * pf[c];
    eg1_out[b * 256 + t] = gelu_f(acc);
  }
  if (t < M_){
    float acc = ewg_b[t];
    const float* wr = ewg_w + (size_t)t * 128;
    for (int c = 0; c < 128; ++c) acc += wr[c] * pf[c];
    ewl[t] = acc;
  }
  __syncthreads();
  if (t == 0){
    float m = -1e30f;
    for (int i = 0; i < M_; ++i) m = fmaxf(m, ewl[i]);
    float z = 0.f;
    for (int i = 0; i < M_; ++i){ ewl[i] = expf(ewl[i] - m); z += ewl[i]; }
    for (int i = 0; i < M_; ++i) ew_out[b * M_ + i] = ewl[i] / z;
  }
}

// ---------- w_eff[b,c,r] ----------
__global__ void k_weff(const float* __restrict__ eg1, const float* __restrict__ ew,
                       const float* __restrict__ eg_w2, const float* __restrict__ eg_b2,
                       const float* __restrict__ eis_p, float* __restrict__ w_eff){
  int b = blockIdx.x; int cr = blockIdx.y * 256 + threadIdx.x;
  __shared__ float e1[256]; __shared__ float ewl[M_];
  e1[threadIdx.x] = eg1[b * 256 + threadIdx.x];
  if (threadIdx.x < M_) ewl[threadIdx.x] = ew[b * M_ + threadIdx.x];
  __syncthreads();
  if (cr >= C_ * 9) return;
  int c = cr / 9, r = cr % 9;
  float eis = eis_p[0];
  float acc = 0.f;
  for (int m = 0; m < M_; ++m){
    size_t row = ((size_t)m * C_ + c) * 9 + r;
    float v = eg_b2[row];
    const float* wr = eg_w2 + row * 256;
    for (int i = 0; i < 256; ++i) v += wr[i] * e1[i];
    float ekv = v * eis + ((r == 4) ? (1.f - eis) : 0.f);
    acc += ewl[m] * ekv;
  }
  w_eff[b * (C_ * 9) + cr] = acc;
}

// ---------- head: gn+gelu fused into 1x1 conv to NT channel ----------
__global__ void k_logits(const float* __restrict__ h, const float* __restrict__ gmean,
                         const float* __restrict__ ginv, const float* __restrict__ hd_g,
                         const float* __restrict__ hd_be, const float* __restrict__ hd_w2,
                         const float* __restrict__ hd_b2, const int* __restrict__ task_ids,
                         float* __restrict__ logits){
  int b = blockIdx.x; int j = blockIdx.y * 256 + threadIdx.x;
  int it = task_ids[b]; it = it < 0 ? 0 : (it >= NT_ ? NT_ - 1 : it);
  __shared__ float wg[128], wb[128], w2[128];
  if (threadIdx.x < 128){
    wg[threadIdx.x] = hd_g[threadIdx.x];
    wb[threadIdx.x] = hd_be[threadIdx.x];
    w2[threadIdx.x] = hd_w2[it * C_ + threadIdx.x];
  }
  __syncthreads();
  float mu = gmean[b], rs = ginv[b];
  const float* p = h + (size_t)b * C_ * HW_ + j;
  float acc = hd_b2[it];
  #pragma unroll 4
  for (int c = 0; c < C_; ++c){
    float v = p[(size_t)c * HW_];
    v = (v - mu) * rs * wg[c] + wb[c];
    acc += w2[c] * gelu_f(v);
  }
  logits[b * HW_ + j] = acc;
}

// ---------- final: |sim| partial reduce inline + fsw write -------------------
__global__ void k_final(float* __restrict__ logits, const float* __restrict__ sim,
                        const float* __restrict__ psim, const float* __restrict__ sim_temp,
                        const float* __restrict__ proto_amp,
                        const float* __restrict__ asw, float* __restrict__ fsw_out){
  __shared__ float red[256];
  float s = psim[threadIdx.x];  // exactly B_*64 = 256 partials
  s = block_reduce_sum256(s, red);
  int idx = blockIdx.x * 256 + threadIdx.x;
  float mean = s / (float)(B_ * HW_);
  float denom = mean + 1e-6f;
  float temp = fmaxf(sim_temp[0], 0.001f);
  float v = tanhf(sim[idx] / denom / temp);
  logits[idx] += 5.0f * proto_amp[0] * v;
  if (blockIdx.x == 0 && threadIdx.x < B_){
    float a = 1.0f * asw[0];
    fsw_out[threadIdx.x] = a / a;
  }
}

extern "C" void kernel_launch(void* const* d_in, const int* in_sizes, int n_in,
                              void* d_out, int out_size, void* d_ws, size_t ws_size,
                              hipStream_t stream){
  const float* x_low   = (const float*)d_in[0];
  const float* x_high  = (const float*)d_in[1];
  const float* temb    = (const float*)d_in[2];
  const float* pl_w    = (const float*)d_in[3];
  const float* pl_g    = (const float*)d_in[4];
  const float* pl_b    = (const float*)d_in[5];
  const float* ph_w    = (const float*)d_in[6];
  const float* ph_g    = (const float*)d_in[7];
  const float* ph_b    = (const float*)d_in[8];
  const float* fu_w    = (const float*)d_in[9];
  const float* fu_g    = (const float*)d_in[10];
  const float* fu_b    = (const float*)d_in[11];
  const float* pi_w1   = (const float*)d_in[12];
  const float* pi_b1   = (const float*)d_in[13];
  const float* pi_w2   = (const float*)d_in[14];
  const float* pi_b2   = (const float*)d_in[15];
  const float* se_w1   = (const float*)d_in[16];
  const float* se_b1   = (const float*)d_in[17];
  const float* se_g    = (const float*)d_in[18];
  const float* se_be   = (const float*)d_in[19];
  const float* se_w2   = (const float*)d_in[20];
  const float* se_b2   = (const float*)d_in[21];
  const float* at_in_w = (const float*)d_in[22];
  const float* at_in_b = (const float*)d_in[23];
  const float* at_out_w= (const float*)d_in[24];
  const float* at_out_b= (const float*)d_in[25];
  const float* pf_w    = (const float*)d_in[26];
  const float* pf_b    = (const float*)d_in[27];
  const float* asw     = (const float*)d_in[32];
  const float* eg_w1   = (const float*)d_in[33];
  const float* eg_b1   = (const float*)d_in[34];
  const float* eg_w2   = (const float*)d_in[35];
  const float* eg_b2   = (const float*)d_in[36];
  const float* ewg_w   = (const float*)d_in[37];
  const float* ewg_b   = (const float*)d_in[38];
  const float* hd_w1   = (const float*)d_in[39];
  const float* hd_b1   = (const float*)d_in[40];
  const float* hd_g    = (const float*)d_in[41];
  const float* hd_be   = (const float*)d_in[42];
  const float* hd_w2   = (const float*)d_in[43];
  const float* hd_b2   = (const float*)d_in[44];
  const float* eis     = (const float*)d_in[45];
  const float* sim_temp= (const float*)d_in[46];
  const float* proto_amp=(const float*)d_in[47];
  const int*   task_ids= (const int*)d_in[48];

  float* ws = (float*)d_ws;
  const size_t BIG = (size_t)B_ * C_ * HW_; // 8,388,608
  float* S0 = ws;
  float* S1 = ws + BIG;
  float* S2 = ws + 2 * BIG;
  float* scores = ws + 3 * BIG;              // B*8*HW = 524288
  float* sm = scores + (size_t)B_ * 8 * HW_;
  float* sim     = sm;             sm += (size_t)B_ * HW_;
  float* factor  = sm;             sm += (size_t)B_ * HW_;
  float* logitsb = sm;             sm += (size_t)B_ * HW_;
  float* psA = sm; sm += 1024; float* pqA = sm; sm += 1024;
  float* psB = sm; sm += 1024; float* pqB = sm; sm += 1024;
  float* psC = sm; sm += 1024; float* pqC = sm; sm += 1024;
  float* ps3 = sm; sm += 2048; float* pq3 = sm; sm += 2048;
  float* psH = sm; sm += 2048; float* pqH = sm; sm += 2048;
  float* gmA = sm; sm += 4;  float* giA = sm; sm += 4;
  float* gmB = sm; sm += 4;  float* giB = sm; sm += 4;
  float* gmC = sm; sm += 4;  float* giC = sm; sm += 4;
  float* gm3 = sm; sm += 16; float* gi3 = sm; sm += 16;
  float* gmH = sm; sm += 4;  float* giH = sm; sm += 4;
  float* pinitb  = sm;             sm += 1024;
  float* fgb     = sm;             sm += 512;
  float* bgb     = sm;             sm += 512;
  float* qkvecb  = sm;             sm += 4096;
  float* kdotb   = sm;             sm += 32;
  float* smaxb   = sm;             sm += 32;
  float* ssumb   = sm;             sm += 32;
  float* wsum4b  = sm;             sm += 16384;
  float* eg1b    = sm;             sm += 1024;
  float* ewb     = sm;             sm += 32;
  float* weffb   = sm;             sm += 4608;
  float* psimb   = sm;             sm += 256;
  float* wTph    = sm;             sm += 128 * 128;
  float* wTpl    = sm;             sm += 64 * 64;
  float* wTfu    = sm;             sm += 192 * 128;
  float* wTse    = sm;             sm += 128 * 128;

  float* pred_out = (float*)d_out;                       // 4*512*512
  float* y_out    = pred_out + (size_t)B_ * 512 * 512;   // 4*128*128*128
  float* fsw_out  = y_out + BIG;                         // 4

  dim3 blk(256);
  const float* NF = nullptr;
  float* NFm = nullptr;

  // 0. merged weight transposes
  k_wtall<<<240, blk, 0, stream>>>(ph_w, pl_w, fu_w, se_w2, wTph, wTpl, wTfu, wTse);
  // 1. resize x_high -> S0
  k_resize<<<(unsigned)(BIG / 256), blk, 0, stream>>>(x_high, S0, B_ * C_, 64, 64, 128, 128);
  // 2. DUAL gemm: ph (S0 -> S1) || pl (x_low -> S2 low)
  k_gemm_dual<<<dim3(B_, 512), blk, 0, stream>>>(S0, wTph, S1, psA, pqA,
                                                 x_low, wTpl, S2, psB, pqB);
  k_stat2_dual<<<8, 128, 0, stream>>>(psA, pqA, gmA, giA, (float)(128 * HW_),
                                      psB, pqB, gmB, giB, (float)(64 * HW_));
  // 3. fu conv: concat(gelu(gn(S1)), gelu(gn(S2 low))) -> S0
  k_gemm1x1<128,192><<<dim3(B_, 256), blk, 0, stream>>>(S1, S2, 128, wTfu, NF,
      gmA,giA,ph_g,ph_b,7,1, gmB,giB,pl_g,pl_b,6,1, S0, psC, pqC);
  k_stat2<<<B_, 128, 0, stream>>>(psC, pqC, gmC, giC, 256, (float)(128 * HW_));
  // 4. se grouped conv3x3 (windowed) on x=gelu(gn(S0)) -> S2, GN(4) stats
  k_se3<<<dim3(B_ * 32, 16), blk, 0, stream>>>(S0, gmC, giC, fu_g, fu_b,
      se_w1, se_b1, S2, ps3, pq3);
  k_stat2<<<B_ * 4, 128, 0, stream>>>(ps3, pq3, gm3, gi3, 128, (float)(32 * HW_));
  // 5. se conv1x1 on gelu(gn4(S2)) (+bias) -> S1 = sf
  k_gemm1x1<128,128><<<dim3(B_, 256), blk, 0, stream>>>(S2, NF, 128, wTse, se_b2,
      gm3,gi3,se_g,se_be,5,4, NF,NF,NF,NF,0,0, S1, NFm, NFm);
  // 6. prototypes + folded q
  k_pinit<<<B_, blk, 0, stream>>>(temb, pi_w1, pi_b1, pi_w2, pi_b2, pinitb);
  k_protos<<<1, blk, 0, stream>>>(pinitb, task_ids, fgb, bgb);
  k_qk<<<B_, blk, 0, stream>>>(fgb, bgb, at_in_w, at_in_b, qkvecb, kdotb);
  // 7. fused sim+factor+scores+|sim| partials
  k_simscores<<<dim3(B_, 64), blk, 0, stream>>>(S1, fgb, bgb, qkvecb, kdotb,
                                                sim, factor, scores, psimb);
  // 8. softmax stats + weighted sums (4-way j-split)
  k_smstats<<<B_ * 8, blk, 0, stream>>>(scores, smaxb, ssumb);
  k_wsum<<<dim3(B_ * C_, 4), blk, 0, stream>>>(S1, scores, smaxb, ssumb, wsum4b);
  // 9. small head chain + w_eff
  k_small<<<B_, blk, 0, stream>>>(wsum4b, at_in_w, at_in_b, at_out_w, at_out_b,
                                  pf_w, pf_b, eg_w1, eg_b1, ewg_w, ewg_b, eg1b, ewb);
  k_weff<<<dim3(B_, 5), blk, 0, stream>>>(eg1b, ewb, eg_w2, eg_b2, eis, weffb);
  // 10. fused x_enh -> y -> h (x = fu raw out = S0; h -> S2)
  k_ydw<<<dim3(B_ * C_, 4), blk, 0, stream>>>(S0, factor, gmC, giC, fu_g, fu_b,
      weffb, hd_w1, hd_b1, y_out, S2, psH, pqH);
  k_stat2<<<B_, 128, 0, stream>>>(psH, pqH, gmH, giH, 512, (float)(128 * HW_));
  // 11. logits
  k_logits<<<dim3(B_, 64), blk, 0, stream>>>(S2, gmH, giH, hd_g, hd_be, hd_w2, hd_b2,
                                             task_ids, logitsb);
  // 12. sim scaling + fsw
  k_final<<<(unsigned)((size_t)B_ * HW_ / 256), blk, 0, stream>>>(logitsb, sim, psimb,
                                                                  sim_temp, proto_amp,
                                                                  asw, fsw_out);
  // 13. resize logits 128->512 -> pred
  k_resize<<<(unsigned)((size_t)B_ * 512 * 512 / 256), blk, 0, stream>>>(logitsb, pred_out,
                                                                          B_, 128, 128, 512, 512);
}

// Round 18
// 525.276 us; speedup vs baseline: 1.0725x; 1.0725x over previous
//
#include <hip/hip_runtime.h>
#include <math.h>

constexpr int B_ = 4;
constexpr int C_ = 128;
constexpr int HW_ = 16384;
constexpr int W_ = 128;
constexpr int M_ = 6;
constexpr int TDIM_ = 64;
constexpr int NT_ = 1; // NUM_TASKS

static __device__ __forceinline__ float gelu_f(float x){
  return 0.5f * x * (1.0f + erff(x * 0.7071067811865476f));
}
static __device__ __forceinline__ int imin(int a, int b){ return a < b ? a : b; }

// ---------- block reduce (256 threads) ----------
static __device__ __forceinline__ float block_reduce_sum256(float v, float* lds){
  int t = threadIdx.x;
  lds[t] = v; __syncthreads();
  for (int s = 128; s > 0; s >>= 1){ if (t < s) lds[t] += lds[t + s]; __syncthreads(); }
  float r = lds[0]; __syncthreads();
  return r;
}

// ---------- align-corners bilinear resize ----------
__global__ void k_resize(const float* __restrict__ in, float* __restrict__ out,
                         int BC, int Hi, int Wi, int Ho, int Wo){
  int idx = blockIdx.x * 256 + threadIdx.x;
  int total = BC * Ho * Wo;
  if (idx >= total) return;
  int xo = idx % Wo; int yo = (idx / Wo) % Ho; int bc = idx / (Wo * Ho);
  float sy = (Ho > 1) ? yo * (float)(Hi - 1) / (float)(Ho - 1) : 0.f;
  float sx = (Wo > 1) ? xo * (float)(Wi - 1) / (float)(Wo - 1) : 0.f;
  int y0 = (int)floorf(sy); int y1 = imin(y0 + 1, Hi - 1); float wy = sy - (float)y0;
  int x0 = (int)floorf(sx); int x1 = imin(x0 + 1, Wi - 1); float wx = sx - (float)x0;
  const float* p = in + (size_t)bc * Hi * Wi;
  float a = p[y0 * Wi + x0], b = p[y1 * Wi + x0];
  float c = p[y0 * Wi + x1], d = p[y1 * Wi + x1];
  float t0 = a * (1.f - wy) + b * wy;
  float t1 = c * (1.f - wy) + d * wy;
  out[idx] = t0 * (1.f - wx) + t1 * wx;
}

// ---------- stats finalize ----------
__global__ void k_stat2(const float* __restrict__ ps, const float* __restrict__ pq,
                        float* __restrict__ gm, float* __restrict__ gi,
                        int nper, float nelem){
  int idx = blockIdx.x; int t = threadIdx.x;
  __shared__ float l1[128], l2[128];
  float s = 0.f, ss = 0.f;
  for (int i = t; i < nper; i += 128){ s += ps[idx * nper + i]; ss += pq[idx * nper + i]; }
  l1[t] = s; l2[t] = ss; __syncthreads();
  for (int st = 64; st > 0; st >>= 1){
    if (t < st){ l1[t] += l1[t + st]; l2[t] += l2[t + st]; }
    __syncthreads();
  }
  if (t == 0){
    float mu = l1[0] / nelem;
    float var = l2[0] / nelem - mu * mu;
    gm[idx] = mu; gi[idx] = rsqrtf(var + 1e-5f);
  }
}

// ---------- dual stats finalize ----------
__global__ void k_stat2_dual(const float* __restrict__ psA, const float* __restrict__ pqA,
                             float* __restrict__ gmA, float* __restrict__ giA, float nelemA,
                             const float* __restrict__ psB, const float* __restrict__ pqB,
                             float* __restrict__ gmB, float* __restrict__ giB, float nelemB){
  int idx = blockIdx.x; int t = threadIdx.x;
  __shared__ float l1[128], l2[128];
  const float* ps; const float* pq; float* gm; float* gi; float nelem; int id2;
  if (idx < 4){ ps = psA; pq = pqA; gm = gmA; gi = giA; nelem = nelemA; id2 = idx; }
  else        { ps = psB; pq = pqB; gm = gmB; gi = giB; nelem = nelemB; id2 = idx - 4; }
  float s = 0.f, ss = 0.f;
  for (int i = t; i < 256; i += 128){ s += ps[id2 * 256 + i]; ss += pq[id2 * 256 + i]; }
  l1[t] = s; l2[t] = ss; __syncthreads();
  for (int st = 64; st > 0; st >>= 1){
    if (t < st){ l1[t] += l1[t + st]; l2[t] += l2[t + st]; }
    __syncthreads();
  }
  if (t == 0){
    float mu = l1[0] / nelem;
    float var = l2[0] / nelem - mu * mu;
    gm[id2] = mu; gi[id2] = rsqrtf(var + 1e-5f);
  }
}

// ---------- merged weight transposes ----------
__global__ void k_wtall(const float* __restrict__ ph_w, const float* __restrict__ pl_w,
                        const float* __restrict__ fu_w, const float* __restrict__ se_w2,
                        float* __restrict__ wTph, float* __restrict__ wTpl,
                        float* __restrict__ wTfu, float* __restrict__ wTse){
  int idx = blockIdx.x * 256 + threadIdx.x;
  if (idx < 16384){
    int ci = idx / 128, co = idx % 128;
    wTph[idx] = ph_w[co * 128 + ci];
  } else if (idx < 20480){
    int r = idx - 16384; int ci = r / 64, co = r % 64;
    wTpl[r] = pl_w[co * 64 + ci];
  } else if (idx < 45056){
    int r = idx - 20480; int ci = r / 128, co = r % 128;
    wTfu[r] = fu_w[(size_t)co * 192 + ci];
  } else if (idx < 61440){
    int r = idx - 45056; int ci = r / 128, co = r % 128;
    wTse[r] = se_w2[co * 128 + ci];
  }
}

// ---------- shared GEMM body (raw input, K-chunk 16) --------
template<int CO, int CIT>
static __device__ __forceinline__ void gemm_body(
    const float* __restrict__ in1, const float* __restrict__ wT,
    float* __restrict__ out, float* __restrict__ psum, float* __restrict__ psq,
    int b, int j0, int slot, float* As, float* Bs, float* red){
  const int tid = threadIdx.x;
  const int tj = tid & 15, tco = tid >> 4;
  constexpr int CPT = CO / 16;
  constexpr int AST = CO + 4;
  float acc[CPT][4];
  #pragma unroll
  for (int i = 0; i < CPT; ++i)
    #pragma unroll
    for (int j = 0; j < 4; ++j) acc[i][j] = 0.f;

  for (int k0 = 0; k0 < CIT; k0 += 16){
    const int kk = tid >> 4;
    if constexpr (CO == 128){
      int co = (tid & 15) * 8;
      const float* wp = &wT[(size_t)(k0 + kk) * CO + co];
      *(float4*)&As[kk * AST + co] = *(const float4*)wp;
      *(float4*)&As[kk * AST + co + 4] = *(const float4*)(wp + 4);
    } else {
      int co = (tid & 15) * 4;
      *(float4*)&As[kk * AST + co] = *(const float4*)&wT[(size_t)(k0 + kk) * CO + co];
    }
    {
      int jj = (tid & 15) * 4;
      int ci = k0 + kk;
      float4 v = *(const float4*)&in1[((size_t)b * CIT + ci) * HW_ + j0 + jj];
      *(float4*)&Bs[kk * 68 + jj] = v;
    }
    __syncthreads();
    #pragma unroll
    for (int kkk = 0; kkk < 16; ++kkk){
      float4 bq = *(const float4*)&Bs[kkk * 68 + tj * 4];
      float av[CPT];
      if constexpr (CPT == 8){
        float4 a0 = *(const float4*)&As[kkk * AST + tco * 8];
        float4 a1 = *(const float4*)&As[kkk * AST + tco * 8 + 4];
        av[0] = a0.x; av[1] = a0.y; av[2] = a0.z; av[3] = a0.w;
        av[4] = a1.x; av[5] = a1.y; av[6] = a1.z; av[7] = a1.w;
      } else {
        float4 a0 = *(const float4*)&As[kkk * AST + tco * 4];
        av[0] = a0.x; av[1] = a0.y; av[2] = a0.z; av[3] = a0.w;
      }
      #pragma unroll
      for (int i = 0; i < CPT; ++i){
        acc[i][0] = fmaf(av[i], bq.x, acc[i][0]);
        acc[i][1] = fmaf(av[i], bq.y, acc[i][1]);
        acc[i][2] = fmaf(av[i], bq.z, acc[i][2]);
        acc[i][3] = fmaf(av[i], bq.w, acc[i][3]);
      }
    }
    __syncthreads();
  }
  float s = 0.f, ss = 0.f;
  #pragma unroll
  for (int i = 0; i < CPT; ++i){
    int co = tco * CPT + i;
    float4 o;
    o.x = acc[i][0]; o.y = acc[i][1]; o.z = acc[i][2]; o.w = acc[i][3];
    *(float4*)&out[((size_t)b * CO + co) * HW_ + j0 + tj * 4] = o;
    s += o.x + o.y + o.z + o.w;
    ss += o.x * o.x + o.y * o.y + o.z * o.z + o.w * o.w;
  }
  s = block_reduce_sum256(s, red);
  ss = block_reduce_sum256(ss, red);
  if (tid == 0){ psum[slot] = s; psq[slot] = ss; }
}

// ---------- dual GEMM: ph (128->128) || pl (64->64), 2048 blocks -------------
__global__ __launch_bounds__(256, 4) void k_gemm_dual(
    const float* __restrict__ in_ph, const float* __restrict__ wT_ph,
    float* __restrict__ out_ph, float* __restrict__ psA, float* __restrict__ pqA,
    const float* __restrict__ in_pl, const float* __restrict__ wT_pl,
    float* __restrict__ out_pl, float* __restrict__ psB, float* __restrict__ pqB){
  __shared__ float As[16 * 132];
  __shared__ float Bs[16 * 68];
  __shared__ float red[256];
  int b = blockIdx.x;
  if (blockIdx.y < 256){
    int yb = blockIdx.y;
    gemm_body<128, 128>(in_ph, wT_ph, out_ph, psA, pqA, b, yb * 64, b * 256 + yb, As, Bs, red);
  } else {
    int yb = blockIdx.y - 256;
    gemm_body<64, 64>(in_pl, wT_pl, out_pl, psB, pqB, b, yb * 64, b * 256 + yb, As, Bs, red);
  }
}

// ---------- tiled 1x1-conv GEMM (K-chunk 16) with GN+GELU on input -----------
template<int CO, int CIT>
__global__ __launch_bounds__(256, 4) void k_gemm1x1(
    const float* __restrict__ in1, const float* __restrict__ in2, int CI1,
    const float* __restrict__ wT, const float* __restrict__ bias,
    const float* __restrict__ gm1, const float* __restrict__ gi1,
    const float* __restrict__ ga1, const float* __restrict__ be1, int sh1, int ng1,
    const float* __restrict__ gm2, const float* __restrict__ gi2,
    const float* __restrict__ ga2, const float* __restrict__ be2, int sh2, int ng2,
    float* __restrict__ out, float* __restrict__ psum, float* __restrict__ psq){
  __shared__ float As[16][CO + 4];
  __shared__ float Bs[16][68];
  __shared__ float red[256];
  const int b = blockIdx.x;
  const int j0 = blockIdx.y * 64;
  const int tid = threadIdx.x;
  const int tj = tid & 15, tco = tid >> 4;
  constexpr int CPT = CO / 16;

  float acc[CPT][4];
  #pragma unroll
  for (int i = 0; i < CPT; ++i)
    #pragma unroll
    for (int j = 0; j < 4; ++j) acc[i][j] = 0.f;

  for (int k0 = 0; k0 < CIT; k0 += 16){
    const int kk = tid >> 4;
    if constexpr (CO == 128){
      int co = (tid & 15) * 8;
      const float* wp = &wT[(size_t)(k0 + kk) * CO + co];
      *(float4*)&As[kk][co] = *(const float4*)wp;
      *(float4*)&As[kk][co + 4] = *(const float4*)(wp + 4);
    } else {
      int co = (tid & 15) * 4;
      *(float4*)&As[kk][co] = *(const float4*)&wT[(size_t)(k0 + kk) * CO + co];
    }
    {
      int jj = (tid & 15) * 4;
      int ci = k0 + kk;
      float4 v;
      if (ci < CI1){
        v = *(const float4*)&in1[((size_t)b * CI1 + ci) * HW_ + j0 + jj];
        if (gm1){
          int g = ci >> sh1;
          float rs = gi1[b * ng1 + g];
          float ga = ga1[ci] * rs;
          float be = be1[ci] - gm1[b * ng1 + g] * ga;
          v.x = gelu_f(fmaf(v.x, ga, be)); v.y = gelu_f(fmaf(v.y, ga, be));
          v.z = gelu_f(fmaf(v.z, ga, be)); v.w = gelu_f(fmaf(v.w, ga, be));
        }
      } else {
        int c2 = ci - CI1;
        v = *(const float4*)&in2[((size_t)b * (CIT - CI1) + c2) * HW_ + j0 + jj];
        if (gm2){
          int g = c2 >> sh2;
          float rs = gi2[b * ng2 + g];
          float ga = ga2[c2] * rs;
          float be = be2[c2] - gm2[b * ng2 + g] * ga;
          v.x = gelu_f(fmaf(v.x, ga, be)); v.y = gelu_f(fmaf(v.y, ga, be));
          v.z = gelu_f(fmaf(v.z, ga, be)); v.w = gelu_f(fmaf(v.w, ga, be));
        }
      }
      *(float4*)&Bs[kk][jj] = v;
    }
    __syncthreads();
    #pragma unroll
    for (int kkk = 0; kkk < 16; ++kkk){
      float4 bq = *(const float4*)&Bs[kkk][tj * 4];
      float av[CPT];
      if constexpr (CPT == 8){
        float4 a0 = *(const float4*)&As[kkk][tco * 8];
        float4 a1 = *(const float4*)&As[kkk][tco * 8 + 4];
        av[0] = a0.x; av[1] = a0.y; av[2] = a0.z; av[3] = a0.w;
        av[4] = a1.x; av[5] = a1.y; av[6] = a1.z; av[7] = a1.w;
      } else {
        float4 a0 = *(const float4*)&As[kkk][tco * 4];
        av[0] = a0.x; av[1] = a0.y; av[2] = a0.z; av[3] = a0.w;
      }
      #pragma unroll
      for (int i = 0; i < CPT; ++i){
        acc[i][0] = fmaf(av[i], bq.x, acc[i][0]);
        acc[i][1] = fmaf(av[i], bq.y, acc[i][1]);
        acc[i][2] = fmaf(av[i], bq.z, acc[i][2]);
        acc[i][3] = fmaf(av[i], bq.w, acc[i][3]);
      }
    }
    __syncthreads();
  }
  float s = 0.f, ss = 0.f;
  #pragma unroll
  for (int i = 0; i < CPT; ++i){
    int co = tco * CPT + i;
    float bb = bias ? bias[co] : 0.f;
    float4 o;
    o.x = acc[i][0] + bb; o.y = acc[i][1] + bb;
    o.z = acc[i][2] + bb; o.w = acc[i][3] + bb;
    *(float4*)&out[((size_t)b * CO + co) * HW_ + j0 + tj * 4] = o;
    s += o.x + o.y + o.z + o.w;
    ss += o.x * o.x + o.y * o.y + o.z * o.z + o.w * o.w;
  }
  if (psum){
    s = block_reduce_sum256(s, red);
    ss = block_reduce_sum256(ss, red);
    if (tid == 0){
      psum[b * gridDim.y + blockIdx.y] = s;
      psq [b * gridDim.y + blockIdx.y] = ss;
    }
  }
}

// ---------- grouped 3x3 conv, strip mapping (register-lean, few LDS instrs) --
// R17: R15 scalar version = 36 b32/output (LDS-issue bound, 73us). R16 windowed
// = 132 VGPR + 3.4M conflicts (117us). This: thread owns fixed (rr, 4-col
// strip); loops co_l with only acc[4] live. Per (cil,ky): 1 b128 + 2 b32 + w9
// broadcast reads -> 9 LDS instr/output, VGPR ~45. Same staging/grid as R15.
__global__ __launch_bounds__(256) void k_se3(const float* __restrict__ x,
    const float* __restrict__ gm, const float* __restrict__ gi,
    const float* __restrict__ gamma, const float* __restrict__ beta,
    const float* __restrict__ w, const float* __restrict__ bias,
    float* __restrict__ out, float* __restrict__ psum, float* __restrict__ psq){
  __shared__ float xs[4][10][128];
  __shared__ float ws[144];
  __shared__ float wb[4];
  __shared__ float red[256];
  const int bgc = blockIdx.x; const int b = bgc >> 5, gc = bgc & 31;
  const int r0 = blockIdx.y * 8;
  const int tid = threadIdx.x;
  const float mu = gm[b], rs = gi[b];
  for (int ch = 0; ch < 4; ++ch){
    int c = gc * 4 + ch;
    float ga = gamma[c] * rs, be = beta[c] - mu * rs * gamma[c];
    const float* px = x + ((size_t)b * C_ + c) * HW_;
    for (int i = tid; i < 10 * 128; i += 256){
      int rr = i >> 7, cc = i & 127;
      int row = r0 - 1 + rr;
      float v = 0.f;
      if ((unsigned)row < 128u) v = gelu_f(fmaf(px[row * W_ + cc], ga, be));
      xs[ch][rr][cc] = v;
    }
  }
  if (tid < 144) ws[tid] = w[(size_t)(gc * 4) * 36 + tid];
  if (tid < 4)   wb[tid] = bias[gc * 4 + tid];
  __syncthreads();
  // thread -> (rr, 4-col strip); 256 threads = 8 rows x 32 strips
  const int c4 = (tid & 31) * 4;
  const int rr = tid >> 5;          // 0..7, output row r0+rr; xs rows rr..rr+2
  float s = 0.f, ss = 0.f;
  for (int co_l = 0; co_l < 4; ++co_l){
    float acc0 = wb[co_l], acc1 = acc0, acc2 = acc0, acc3 = acc0;
    #pragma unroll
    for (int cil = 0; cil < 4; ++cil){
      const float* wp = &ws[(co_l * 4 + cil) * 9];  // wave-uniform -> broadcast
      #pragma unroll
      for (int ky = 0; ky < 3; ++ky){
        float4 cen = *(const float4*)&xs[cil][rr + ky][c4];
        float left  = (c4 > 0)   ? xs[cil][rr + ky][c4 - 1] : 0.f;
        float right = (c4 < 124) ? xs[cil][rr + ky][c4 + 4] : 0.f;
        float w0 = wp[ky * 3 + 0], w1 = wp[ky * 3 + 1], w2 = wp[ky * 3 + 2];
        acc0 = fmaf(w0, left,  acc0); acc0 = fmaf(w1, cen.x, acc0); acc0 = fmaf(w2, cen.y, acc0);
        acc1 = fmaf(w0, cen.x, acc1); acc1 = fmaf(w1, cen.y, acc1); acc1 = fmaf(w2, cen.z, acc1);
        acc2 = fmaf(w0, cen.y, acc2); acc2 = fmaf(w1, cen.z, acc2); acc2 = fmaf(w2, cen.w, acc2);
        acc3 = fmaf(w0, cen.z, acc3); acc3 = fmaf(w1, cen.w, acc3); acc3 = fmaf(w2, right, acc3);
      }
    }
    float4 o = {acc0, acc1, acc2, acc3};
    *(float4*)&out[((size_t)b * C_ + gc * 4 + co_l) * HW_ + (r0 + rr) * W_ + c4] = o;
    s += o.x + o.y + o.z + o.w;
    ss += o.x * o.x + o.y * o.y + o.z * o.z + o.w * o.w;
  }
  s = block_reduce_sum256(s, red);
  ss = block_reduce_sum256(ss, red);
  if (tid == 0){
    int idx = (b * 4 + (gc >> 3)) * 128 + (gc & 7) * 16 + blockIdx.y;
    psum[idx] = s; psq[idx] = ss;
  }
}

// ---------- fused: x_enh -> y (3x3 dyn) -> h (3x3 dw) + GN stats for h -------
__global__ __launch_bounds__(256) void k_ydw(const float* __restrict__ x,
    const float* __restrict__ factor,
    const float* __restrict__ gm, const float* __restrict__ gi,
    const float* __restrict__ gamma, const float* __restrict__ beta,
    const float* __restrict__ w_eff, const float* __restrict__ dw_w,
    const float* __restrict__ dw_b, float* __restrict__ y_out,
    float* __restrict__ h_out, float* __restrict__ psum, float* __restrict__ psq){
  __shared__ float xs[36][128];
  __shared__ float ys[34][128];
  __shared__ float red[256];
  const int bc = blockIdx.x; const int b = bc >> 7, c = bc & 127;
  const int r0 = blockIdx.y * 32;
  const int tid = threadIdx.x;
  const float mu = gm[b], rs = gi[b];
  const float ga = gamma[c] * rs, be = beta[c] - mu * rs * gamma[c];
  const float* px = x + ((size_t)b * C_ + c) * HW_;
  const float* pf = factor + (size_t)b * HW_;
  for (int i = tid; i < 36 * 128; i += 256){
    int rr = i >> 7, cc = i & 127;
    int row = r0 - 2 + rr;
    float v = 0.f;
    if ((unsigned)row < 128u)
      v = gelu_f(fmaf(px[row * W_ + cc], ga, be)) * pf[row * W_ + cc];
    xs[rr][cc] = v;
  }
  __syncthreads();
  float w9[9];
  #pragma unroll
  for (int r = 0; r < 9; ++r) w9[r] = w_eff[b * 1152 + c * 9 + r];
  for (int i = tid; i < 34 * 128; i += 256){
    int rr = i >> 7, cc = i & 127;
    int row = r0 - 1 + rr;
    float acc = 0.f;
    if ((unsigned)row < 128u){
      #pragma unroll
      for (int ky = 0; ky < 3; ++ky){
        #pragma unroll
        for (int kx = 0; kx < 3; ++kx){
          int xc = cc + kx - 1;
          if ((unsigned)xc < 128u) acc += w9[ky * 3 + kx] * xs[rr + ky][xc];
        }
      }
    }
    ys[rr][cc] = acc;
    if (rr >= 1 && rr <= 32)
      y_out[((size_t)b * C_ + c) * HW_ + row * W_ + cc] = acc;
  }
  __syncthreads();
  float wd[9];
  #pragma unroll
  for (int r = 0; r < 9; ++r) wd[r] = dw_w[c * 9 + r];
  const float bb = dw_b[c];
  float s = 0.f, ss = 0.f;
  for (int i = tid; i < 32 * 128; i += 256){
    int rr = i >> 7, cc = i & 127;
    int row = r0 + rr;
    float acc = bb;
    #pragma unroll
    for (int ky = 0; ky < 3; ++ky){
      #pragma unroll
      for (int kx = 0; kx < 3; ++kx){
        int yc = cc + kx - 1;
        if ((unsigned)yc < 128u) acc += wd[ky * 3 + kx] * ys[rr + ky][yc];
      }
    }
    h_out[((size_t)b * C_ + c) * HW_ + row * W_ + cc] = acc;
    s += acc; ss += acc * acc;
  }
  s = block_reduce_sum256(s, red);
  ss = block_reduce_sum256(ss, red);
  if (tid == 0){
    int idx = b * 512 + c * 4 + blockIdx.y;
    psum[idx] = s; psq[idx] = ss;
  }
}

// ---------- prototype init MLP (per b) ----------
__global__ void k_pinit(const float* __restrict__ temb, const float* __restrict__ w1,
                        const float* __restrict__ b1, const float* __restrict__ w2,
                        const float* __restrict__ b2, float* __restrict__ pinit){
  int b = blockIdx.x; int t = threadIdx.x;
  __shared__ float h1[256], p2[256], nrm[2];
  float acc = b1[t];
  for (int i = 0; i < TDIM_; ++i) acc += temb[b * TDIM_ + i] * w1[t * TDIM_ + i];
  h1[t] = gelu_f(acc); __syncthreads();
  acc = b2[t];
  for (int i = 0; i < 256; ++i) acc += h1[i] * w2[t * 256 + i];
  p2[t] = acc; __syncthreads();
  if (t < 2){
    float s = 0.f;
    for (int c = 0; c < 128; ++c){ float v = p2[t * 128 + c]; s += v * v; }
    nrm[t] = fmaxf(sqrtf(s), 1e-12f);
  }
  __syncthreads();
  pinit[b * 256 + t] = p2[t] / nrm[t / 128];
}

// ---------- table / protos / fg,bg ----------
__global__ void k_protos(const float* __restrict__ pinit, const int* __restrict__ task_ids,
                         float* __restrict__ fg, float* __restrict__ bg){
  __shared__ int tbl[NT_];
  __shared__ int src[B_];
  __shared__ float nr[B_ * 2];
  int t = threadIdx.x;
  if (t < NT_){
    int idx = 0;
    for (int b = B_ - 1; b >= 0; --b) if (task_ids[b] == t) idx = b;
    tbl[t] = idx;
  }
  __syncthreads();
  if (t < B_){
    int ti = task_ids[t]; ti = ti < 0 ? 0 : (ti >= NT_ ? NT_ - 1 : ti);
    src[t] = tbl[ti];
  }
  __syncthreads();
  if (t < 2 * B_){
    int b = t / 2, r = t % 2;
    float s = 0.f;
    for (int c = 0; c < 128; ++c){ float v = pinit[src[b] * 256 + r * 128 + c]; s += v * v; }
    nr[t] = fmaxf(sqrtf(s), 1e-12f);
  }
  __syncthreads();
  for (int i = t; i < B_ * 128; i += 256){
    int b = i / 128, c = i % 128;
    fg[i] = pinit[src[b] * 256 + c] / nr[b * 2 + 0];
    bg[i] = pinit[src[b] * 256 + 128 + c] / nr[b * 2 + 1];
  }
}

// ---------- q projection folded into key space ----------
__global__ void k_qk(const float* __restrict__ fg, const float* __restrict__ bg,
                     const float* __restrict__ at_in_w, const float* __restrict__ at_in_b,
                     float* __restrict__ qkvec, float* __restrict__ kdot){
  int b = blockIdx.x, t = threadIdx.x;
  __shared__ float pq[256], qf[256];
  pq[t] = (t < 128) ? fg[b * 128 + t] : bg[b * 128 + (t - 128)];
  __syncthreads();
  {
    int qi = t / 128, o = t % 128;
    float acc = at_in_b[o];
    const float* wr = at_in_w + (size_t)o * 128;
    for (int c = 0; c < 128; ++c) acc += wr[c] * pq[qi * 128 + c];
    qf[qi * 128 + o] = acc;
  }
  __syncthreads();
  for (int e = t; e < 1024; e += 256){
    int p = e / 128, c = e % 128, qi = p / 4, h = p % 4;
    float acc = 0.f;
    for (int d = 0; d < 32; ++d)
      acc += qf[qi * 128 + h * 32 + d] * at_in_w[(size_t)(128 + h * 32 + d) * 128 + c];
    qkvec[b * 1024 + e] = acc;
  }
  if (t < 8){
    int qi = t / 4, h = t % 4;
    float acc = 0.f;
    for (int d = 0; d < 32; ++d) acc += qf[qi * 128 + h * 32 + d] * at_in_b[128 + h * 32 + d];
    kdot[b * 8 + t] = acc;
  }
}

// ---------- fused: sim + factor + 8 score rows + |sim| partials --------------
__global__ __launch_bounds__(256) void k_simscores(const float* __restrict__ sf,
                          const float* __restrict__ fg, const float* __restrict__ bg,
                          const float* __restrict__ qkvec, const float* __restrict__ kdot,
                          float* __restrict__ sim, float* __restrict__ factor,
                          float* __restrict__ scores, float* __restrict__ psim){
  int b = blockIdx.x; int j = blockIdx.y * 256 + threadIdx.x;
  __shared__ float L[10 * 128];
  __shared__ float red[256];
  for (int i = threadIdx.x; i < 1280; i += 256){
    int r = i >> 7, c = i & 127;
    L[i] = (r == 0) ? fg[b * 128 + c]
         : (r == 1) ? bg[b * 128 + c]
                    : qkvec[b * 1024 + (r - 2) * 128 + c];
  }
  __syncthreads();
  const float* p = sf + (size_t)b * C_ * HW_ + j;
  float a0=0,a1=0,q0=0,q1=0,q2=0,q3=0,q4=0,q5=0,q6=0,q7=0,nn=0;
  #pragma unroll 8
  for (int c = 0; c < C_; ++c){
    float v = p[(size_t)c * HW_];
    nn += v * v;
    a0 += L[c] * v;          a1 += L[128 + c] * v;
    q0 += L[256 + c] * v;    q1 += L[384 + c] * v;
    q2 += L[512 + c] * v;    q3 += L[640 + c] * v;
    q4 += L[768 + c] * v;    q5 += L[896 + c] * v;
    q6 += L[1024 + c] * v;   q7 += L[1152 + c] * v;
  }
  float inv = 1.f / fmaxf(sqrtf(nn), 1e-12f);
  float sv = (a0 - a1) * inv;
  sim[b * HW_ + j] = sv;
  factor[b * HW_ + j] = 1.f + 0.5f / (1.f + expf(-sv));
  const float scale = 0.17677669529663689f;
  float qs[8] = {q0,q1,q2,q3,q4,q5,q6,q7};
  #pragma unroll
  for (int pp = 0; pp < 8; ++pp)
    scores[((size_t)(b * 8 + pp)) * HW_ + j] = (qs[pp] + kdot[b * 8 + pp]) * scale;
  float as = block_reduce_sum256(fabsf(sv), red);
  if (threadIdx.x == 0) psim[b * 64 + blockIdx.y] = as;
}

__global__ void k_smstats(const float* __restrict__ scores, float* __restrict__ smax,
                          float* __restrict__ ssum){
  __shared__ float lds[256];
  int row = blockIdx.x;
  const float* p = scores + (size_t)row * HW_;
  float m = -1e30f;
  for (int j = threadIdx.x; j < HW_; j += 256) m = fmaxf(m, p[j]);
  lds[threadIdx.x] = m; __syncthreads();
  for (int s = 128; s > 0; s >>= 1){
    if (threadIdx.x < s) lds[threadIdx.x] = fmaxf(lds[threadIdx.x], lds[threadIdx.x + s]);
    __syncthreads();
  }
  m = lds[0]; __syncthreads();
  float z = 0.f;
  for (int j = threadIdx.x; j < HW_; j += 256) z += expf(p[j] - m);
  z = block_reduce_sum256(z, lds);
  if (threadIdx.x == 0){ smax[row] = m; ssum[row] = z; }
}

// ---------- wsum, 4-way j-split ----------------------------------------------
__global__ void k_wsum(const float* __restrict__ sf, const float* __restrict__ scores,
                       const float* __restrict__ smax, const float* __restrict__ ssum,
                       float* __restrict__ wsum4){
  int bc = blockIdx.x; int b = bc / C_, c = bc % C_;
  int chunk = blockIdx.y;
  __shared__ float lds[8 * 256];
  __shared__ float mr[8], zr[8];
  if (threadIdx.x < 8){
    mr[threadIdx.x] = smax[b * 8 + threadIdx.x];
    zr[threadIdx.x] = 1.f / ssum[b * 8 + threadIdx.x];
  }
  __syncthreads();
  const float* p = sf + (size_t)bc * HW_;
  const float* sc = scores + (size_t)b * 8 * HW_;
  int j0 = chunk * (HW_ / 4), j1 = j0 + HW_ / 4;
  float acc[8] = {0,0,0,0,0,0,0,0};
  for (int j = j0 + threadIdx.x; j < j1; j += 256){
    float v = p[j];
    #pragma unroll
    for (int pp = 0; pp < 8; ++pp)
      acc[pp] = fmaf(expf(sc[(size_t)pp * HW_ + j] - mr[pp]) * zr[pp], v, acc[pp]);
  }
  #pragma unroll
  for (int pp = 0; pp < 8; ++pp) lds[pp * 256 + threadIdx.x] = acc[pp];
  __syncthreads();
  for (int s = 128; s > 0; s >>= 1){
    if (threadIdx.x < s){
      #pragma unroll
      for (int pp = 0; pp < 8; ++pp) lds[pp * 256 + threadIdx.x] += lds[pp * 256 + threadIdx.x + s];
    }
    __syncthreads();
  }
  if (threadIdx.x < 8)
    wsum4[chunk * 4096 + b * 1024 + threadIdx.x * 128 + c] = lds[threadIdx.x * 256];
}

// ---------- small head chain (sums the 4 wsum partials on load) --------------
__global__ void k_small(const float* __restrict__ wsum4, const float* __restrict__ at_in_w,
                        const float* __restrict__ at_in_b, const float* __restrict__ at_out_w,
                        const float* __restrict__ at_out_b, const float* __restrict__ pf_w,
                        const float* __restrict__ pf_b, const float* __restrict__ eg_w1,
                        const float* __restrict__ eg_b1, const float* __restrict__ ewg_w,
                        const float* __restrict__ ewg_b, float* __restrict__ eg1_out,
                        float* __restrict__ ew_out){
  int b = blockIdx.x; int t = threadIdx.x;
  __shared__ float wsl[1024], att[256], ao[256], pf[128], ewl[8];
  for (int i = t; i < 1024; i += 256)
    wsl[i] = wsum4[b * 1024 + i] + wsum4[4096 + b * 1024 + i]
           + wsum4[8192 + b * 1024 + i] + wsum4[12288 + b * 1024 + i];
  __syncthreads();
  {
    int qi = t / 128, o = t % 128, h = o / 32, d = o % 32, p = qi * 4 + h;
    float acc = at_in_b[256 + h * 32 + d];
    const float* wr = at_in_w + (size_t)(256 + h * 32 + d) * 128;
    for (int c = 0; c < 128; ++c) acc += wr[c] * wsl[p * 128 + c];
    att[qi * 128 + o] = acc;
  }
  __syncthreads();
  {
    int qi = t / 128, o = t % 128;
    float acc = at_out_b[o];
    const float* wr = at_out_w + (size_t)o * 128;
    for (int c = 0; c < 128; ++c) acc += wr[c] * att[qi * 128 + c];
    ao[qi * 128 + o] = acc;
  }
  __syncthreads();
  if (t < 128){
    float acc = pf_b[t];
    const float* wr = pf_w + (size_t)t * 384;
    for (int c = 0; c < 128; ++c){
      float fa = ao[c], ba = ao[128 + c];
      acc += wr[c] * fa + wr[128 + c] * ba + wr[256 + c] * (fa - ba);
    }
    pf[t] = acc;
  }
  __syncthreads();
  {
    float acc = eg_b1[t];
    const float* wr = eg_w1 + (size_t)t * 128;
    for (int c = 0; c < 128; ++c) acc += wr[c] * pf[c];
    eg1_out[b * 256 + t] = gelu_f(acc);
  }
  if (t < M_){
    float acc = ewg_b[t];
    const float* wr = ewg_w + (size_t)t * 128;
    for (int c = 0; c < 128; ++c) acc += wr[c] * pf[c];
    ewl[t] = acc;
  }
  __syncthreads();
  if (t == 0){
    float m = -1e30f;
    for (int i = 0; i < M_; ++i) m = fmaxf(m, ewl[i]);
    float z = 0.f;
    for (int i = 0; i < M_; ++i){ ewl[i] = expf(ewl[i] - m); z += ewl[i]; }
    for (int i = 0; i < M_; ++i) ew_out[b * M_ + i] = ewl[i] / z;
  }
}

// ---------- w_eff[b,c,r] ----------
__global__ void k_weff(const float* __restrict__ eg1, const float* __restrict__ ew,
                       const float* __restrict__ eg_w2, const float* __restrict__ eg_b2,
                       const float* __restrict__ eis_p, float* __restrict__ w_eff){
  int b = blockIdx.x; int cr = blockIdx.y * 256 + threadIdx.x;
  __shared__ float e1[256]; __shared__ float ewl[M_];
  e1[threadIdx.x] = eg1[b * 256 + threadIdx.x];
  if (threadIdx.x < M_) ewl[threadIdx.x] = ew[b * M_ + threadIdx.x];
  __syncthreads();
  if (cr >= C_ * 9) return;
  int c = cr / 9, r = cr % 9;
  float eis = eis_p[0];
  float acc = 0.f;
  for (int m = 0; m < M_; ++m){
    size_t row = ((size_t)m * C_ + c) * 9 + r;
    float v = eg_b2[row];
    const float* wr = eg_w2 + row * 256;
    for (int i = 0; i < 256; ++i) v += wr[i] * e1[i];
    float ekv = v * eis + ((r == 4) ? (1.f - eis) : 0.f);
    acc += ewl[m] * ekv;
  }
  w_eff[b * (C_ * 9) + cr] = acc;
}

// ---------- head: gn+gelu fused into 1x1 conv to NT channel ----------
__global__ void k_logits(const float* __restrict__ h, const float* __restrict__ gmean,
                         const float* __restrict__ ginv, const float* __restrict__ hd_g,
                         const float* __restrict__ hd_be, const float* __restrict__ hd_w2,
                         const float* __restrict__ hd_b2, const int* __restrict__ task_ids,
                         float* __restrict__ logits){
  int b = blockIdx.x; int j = blockIdx.y * 256 + threadIdx.x;
  int it = task_ids[b]; it = it < 0 ? 0 : (it >= NT_ ? NT_ - 1 : it);
  __shared__ float wg[128], wb[128], w2[128];
  if (threadIdx.x < 128){
    wg[threadIdx.x] = hd_g[threadIdx.x];
    wb[threadIdx.x] = hd_be[threadIdx.x];
    w2[threadIdx.x] = hd_w2[it * C_ + threadIdx.x];
  }
  __syncthreads();
  float mu = gmean[b], rs = ginv[b];
  const float* p = h + (size_t)b * C_ * HW_ + j;
  float acc = hd_b2[it];
  #pragma unroll 4
  for (int c = 0; c < C_; ++c){
    float v = p[(size_t)c * HW_];
    v = (v - mu) * rs * wg[c] + wb[c];
    acc += w2[c] * gelu_f(v);
  }
  logits[b * HW_ + j] = acc;
}

// ---------- final: |sim| partial reduce inline + fsw write -------------------
__global__ void k_final(float* __restrict__ logits, const float* __restrict__ sim,
                        const float* __restrict__ psim, const float* __restrict__ sim_temp,
                        const float* __restrict__ proto_amp,
                        const float* __restrict__ asw, float* __restrict__ fsw_out){
  __shared__ float red[256];
  float s = psim[threadIdx.x];  // exactly B_*64 = 256 partials
  s = block_reduce_sum256(s, red);
  int idx = blockIdx.x * 256 + threadIdx.x;
  float mean = s / (float)(B_ * HW_);
  float denom = mean + 1e-6f;
  float temp = fmaxf(sim_temp[0], 0.001f);
  float v = tanhf(sim[idx] / denom / temp);
  logits[idx] += 5.0f * proto_amp[0] * v;
  if (blockIdx.x == 0 && threadIdx.x < B_){
    float a = 1.0f * asw[0];
    fsw_out[threadIdx.x] = a / a;
  }
}

extern "C" void kernel_launch(void* const* d_in, const int* in_sizes, int n_in,
                              void* d_out, int out_size, void* d_ws, size_t ws_size,
                              hipStream_t stream){
  const float* x_low   = (const float*)d_in[0];
  const float* x_high  = (const float*)d_in[1];
  const float* temb    = (const float*)d_in[2];
  const float* pl_w    = (const float*)d_in[3];
  const float* pl_g    = (const float*)d_in[4];
  const float* pl_b    = (const float*)d_in[5];
  const float* ph_w    = (const float*)d_in[6];
  const float* ph_g    = (const float*)d_in[7];
  const float* ph_b    = (const float*)d_in[8];
  const float* fu_w    = (const float*)d_in[9];
  const float* fu_g    = (const float*)d_in[10];
  const float* fu_b    = (const float*)d_in[11];
  const float* pi_w1   = (const float*)d_in[12];
  const float* pi_b1   = (const float*)d_in[13];
  const float* pi_w2   = (const float*)d_in[14];
  const float* pi_b2   = (const float*)d_in[15];
  const float* se_w1   = (const float*)d_in[16];
  const float* se_b1   = (const float*)d_in[17];
  const float* se_g    = (const float*)d_in[18];
  const float* se_be   = (const float*)d_in[19];
  const float* se_w2   = (const float*)d_in[20];
  const float* se_b2   = (const float*)d_in[21];
  const float* at_in_w = (const float*)d_in[22];
  const float* at_in_b = (const float*)d_in[23];
  const float* at_out_w= (const float*)d_in[24];
  const float* at_out_b= (const float*)d_in[25];
  const float* pf_w    = (const float*)d_in[26];
  const float* pf_b    = (const float*)d_in[27];
  const float* asw     = (const float*)d_in[32];
  const float* eg_w1   = (const float*)d_in[33];
  const float* eg_b1   = (const float*)d_in[34];
  const float* eg_w2   = (const float*)d_in[35];
  const float* eg_b2   = (const float*)d_in[36];
  const float* ewg_w   = (const float*)d_in[37];
  const float* ewg_b   = (const float*)d_in[38];
  const float* hd_w1   = (const float*)d_in[39];
  const float* hd_b1   = (const float*)d_in[40];
  const float* hd_g    = (const float*)d_in[41];
  const float* hd_be   = (const float*)d_in[42];
  const float* hd_w2   = (const float*)d_in[43];
  const float* hd_b2   = (const float*)d_in[44];
  const float* eis     = (const float*)d_in[45];
  const float* sim_temp= (const float*)d_in[46];
  const float* proto_amp=(const float*)d_in[47];
  const int*   task_ids= (const int*)d_in[48];

  float* ws = (float*)d_ws;
  const size_t BIG = (size_t)B_ * C_ * HW_; // 8,388,608
  float* S0 = ws;
  float* S1 = ws + BIG;
  float* S2 = ws + 2 * BIG;
  float* scores = ws + 3 * BIG;              // B*8*HW = 524288
  float* sm = scores + (size_t)B_ * 8 * HW_;
  float* sim     = sm;             sm += (size_t)B_ * HW_;
  float* factor  = sm;             sm += (size_t)B_ * HW_;
  float* logitsb = sm;             sm += (size_t)B_ * HW_;
  float* psA = sm; sm += 1024; float* pqA = sm; sm += 1024;
  float* psB = sm; sm += 1024; float* pqB = sm; sm += 1024;
  float* psC = sm; sm += 1024; float* pqC = sm; sm += 1024;
  float* ps3 = sm; sm += 2048; float* pq3 = sm; sm += 2048;
  float* psH = sm; sm += 2048; float* pqH = sm; sm += 2048;
  float* gmA = sm; sm += 4;  float* giA = sm; sm += 4;
  float* gmB = sm; sm += 4;  float* giB = sm; sm += 4;
  float* gmC = sm; sm += 4;  float* giC = sm; sm += 4;
  float* gm3 = sm; sm += 16; float* gi3 = sm; sm += 16;
  float* gmH = sm; sm += 4;  float* giH = sm; sm += 4;
  float* pinitb  = sm;             sm += 1024;
  float* fgb     = sm;             sm += 512;
  float* bgb     = sm;             sm += 512;
  float* qkvecb  = sm;             sm += 4096;
  float* kdotb   = sm;             sm += 32;
  float* smaxb   = sm;             sm += 32;
  float* ssumb   = sm;             sm += 32;
  float* wsum4b  = sm;             sm += 16384;
  float* eg1b    = sm;             sm += 1024;
  float* ewb     = sm;             sm += 32;
  float* weffb   = sm;             sm += 4608;
  float* psimb   = sm;             sm += 256;
  float* wTph    = sm;             sm += 128 * 128;
  float* wTpl    = sm;             sm += 64 * 64;
  float* wTfu    = sm;             sm += 192 * 128;
  float* wTse    = sm;             sm += 128 * 128;

  float* pred_out = (float*)d_out;                       // 4*512*512
  float* y_out    = pred_out + (size_t)B_ * 512 * 512;   // 4*128*128*128
  float* fsw_out  = y_out + BIG;                         // 4

  dim3 blk(256);
  const float* NF = nullptr;
  float* NFm = nullptr;

  // 0. merged weight transposes
  k_wtall<<<240, blk, 0, stream>>>(ph_w, pl_w, fu_w, se_w2, wTph, wTpl, wTfu, wTse);
  // 1. resize x_high -> S0
  k_resize<<<(unsigned)(BIG / 256), blk, 0, stream>>>(x_high, S0, B_ * C_, 64, 64, 128, 128);
  // 2. DUAL gemm: ph (S0 -> S1) || pl (x_low -> S2 low)
  k_gemm_dual<<<dim3(B_, 512), blk, 0, stream>>>(S0, wTph, S1, psA, pqA,
                                                 x_low, wTpl, S2, psB, pqB);
  k_stat2_dual<<<8, 128, 0, stream>>>(psA, pqA, gmA, giA, (float)(128 * HW_),
                                      psB, pqB, gmB, giB, (float)(64 * HW_));
  // 3. fu conv: concat(gelu(gn(S1)), gelu(gn(S2 low))) -> S0
  k_gemm1x1<128,192><<<dim3(B_, 256), blk, 0, stream>>>(S1, S2, 128, wTfu, NF,
      gmA,giA,ph_g,ph_b,7,1, gmB,giB,pl_g,pl_b,6,1, S0, psC, pqC);
  k_stat2<<<B_, 128, 0, stream>>>(psC, pqC, gmC, giC, 256, (float)(128 * HW_));
  // 4. se grouped conv3x3 (strip) on x=gelu(gn(S0)) -> S2, GN(4) stats
  k_se3<<<dim3(B_ * 32, 16), blk, 0, stream>>>(S0, gmC, giC, fu_g, fu_b,
      se_w1, se_b1, S2, ps3, pq3);
  k_stat2<<<B_ * 4, 128, 0, stream>>>(ps3, pq3, gm3, gi3, 128, (float)(32 * HW_));
  // 5. se conv1x1 on gelu(gn4(S2)) (+bias) -> S1 = sf
  k_gemm1x1<128,128><<<dim3(B_, 256), blk, 0, stream>>>(S2, NF, 128, wTse, se_b2,
      gm3,gi3,se_g,se_be,5,4, NF,NF,NF,NF,0,0, S1, NFm, NFm);
  // 6. prototypes + folded q
  k_pinit<<<B_, blk, 0, stream>>>(temb, pi_w1, pi_b1, pi_w2, pi_b2, pinitb);
  k_protos<<<1, blk, 0, stream>>>(pinitb, task_ids, fgb, bgb);
  k_qk<<<B_, blk, 0, stream>>>(fgb, bgb, at_in_w, at_in_b, qkvecb, kdotb);
  // 7. fused sim+factor+scores+|sim| partials
  k_simscores<<<dim3(B_, 64), blk, 0, stream>>>(S1, fgb, bgb, qkvecb, kdotb,
                                                sim, factor, scores, psimb);
  // 8. softmax stats + weighted sums (4-way j-split)
  k_smstats<<<B_ * 8, blk, 0, stream>>>(scores, smaxb, ssumb);
  k_wsum<<<dim3(B_ * C_, 4), blk, 0, stream>>>(S1, scores, smaxb, ssumb, wsum4b);
  // 9. small head chain + w_eff
  k_small<<<B_, blk, 0, stream>>>(wsum4b, at_in_w, at_in_b, at_out_w, at_out_b,
                                  pf_w, pf_b, eg_w1, eg_b1, ewg_w, ewg_b, eg1b, ewb);
  k_weff<<<dim3(B_, 5), blk, 0, stream>>>(eg1b, ewb, eg_w2, eg_b2, eis, weffb);
  // 10. fused x_enh -> y -> h (x = fu raw out = S0; h -> S2)
  k_ydw<<<dim3(B_ * C_, 4), blk, 0, stream>>>(S0, factor, gmC, giC, fu_g, fu_b,
      weffb, hd_w1, hd_b1, y_out, S2, psH, pqH);
  k_stat2<<<B_, 128, 0, stream>>>(psH, pqH, gmH, giH, 512, (float)(128 * HW_));
  // 11. logits
  k_logits<<<dim3(B_, 64), blk, 0, stream>>>(S2, gmH, giH, hd_g, hd_be, hd_w2, hd_b2,
                                             task_ids, logitsb);
  // 12. sim scaling + fsw
  k_final<<<(unsigned)((size_t)B_ * HW_ / 256), blk, 0, stream>>>(logitsb, sim, psimb,
                                                                  sim_temp, proto_amp,
                                                                  asw, fsw_out);
  // 13. resize logits 128->512 -> pred
  k_resize<<<(unsigned)((size_t)B_ * 512 * 512 / 256), blk, 0, stream>>>(logitsb, pred_out,
                                                                          B_, 128, 128, 512, 512);
}

// Round 19
// 501.322 us; speedup vs baseline: 1.1237x; 1.0478x over previous
//
#include <hip/hip_runtime.h>
#include <math.h>

constexpr int B_ = 4;
constexpr int C_ = 128;
constexpr int HW_ = 16384;
constexpr int W_ = 128;
constexpr int M_ = 6;
constexpr int TDIM_ = 64;
constexpr int NT_ = 1; // NUM_TASKS

static __device__ __forceinline__ float gelu_f(float x){
  return 0.5f * x * (1.0f + erff(x * 0.7071067811865476f));
}
static __device__ __forceinline__ int imin(int a, int b){ return a < b ? a : b; }

// ---------- block reduce (256 threads) ----------
static __device__ __forceinline__ float block_reduce_sum256(float v, float* lds){
  int t = threadIdx.x;
  lds[t] = v; __syncthreads();
  for (int s = 128; s > 0; s >>= 1){ if (t < s) lds[t] += lds[t + s]; __syncthreads(); }
  float r = lds[0]; __syncthreads();
  return r;
}

// ---------- align-corners bilinear resize ----------
__global__ void k_resize(const float* __restrict__ in, float* __restrict__ out,
                         int BC, int Hi, int Wi, int Ho, int Wo){
  int idx = blockIdx.x * 256 + threadIdx.x;
  int total = BC * Ho * Wo;
  if (idx >= total) return;
  int xo = idx % Wo; int yo = (idx / Wo) % Ho; int bc = idx / (Wo * Ho);
  float sy = (Ho > 1) ? yo * (float)(Hi - 1) / (float)(Ho - 1) : 0.f;
  float sx = (Wo > 1) ? xo * (float)(Wi - 1) / (float)(Wo - 1) : 0.f;
  int y0 = (int)floorf(sy); int y1 = imin(y0 + 1, Hi - 1); float wy = sy - (float)y0;
  int x0 = (int)floorf(sx); int x1 = imin(x0 + 1, Wi - 1); float wx = sx - (float)x0;
  const float* p = in + (size_t)bc * Hi * Wi;
  float a = p[y0 * Wi + x0], b = p[y1 * Wi + x0];
  float c = p[y0 * Wi + x1], d = p[y1 * Wi + x1];
  float t0 = a * (1.f - wy) + b * wy;
  float t1 = c * (1.f - wy) + d * wy;
  out[idx] = t0 * (1.f - wx) + t1 * wx;
}

// ---------- stats finalize ----------
__global__ void k_stat2(const float* __restrict__ ps, const float* __restrict__ pq,
                        float* __restrict__ gm, float* __restrict__ gi,
                        int nper, float nelem){
  int idx = blockIdx.x; int t = threadIdx.x;
  __shared__ float l1[128], l2[128];
  float s = 0.f, ss = 0.f;
  for (int i = t; i < nper; i += 128){ s += ps[idx * nper + i]; ss += pq[idx * nper + i]; }
  l1[t] = s; l2[t] = ss; __syncthreads();
  for (int st = 64; st > 0; st >>= 1){
    if (t < st){ l1[t] += l1[t + st]; l2[t] += l2[t + st]; }
    __syncthreads();
  }
  if (t == 0){
    float mu = l1[0] / nelem;
    float var = l2[0] / nelem - mu * mu;
    gm[idx] = mu; gi[idx] = rsqrtf(var + 1e-5f);
  }
}

// ---------- dual stats finalize ----------
__global__ void k_stat2_dual(const float* __restrict__ psA, const float* __restrict__ pqA,
                             float* __restrict__ gmA, float* __restrict__ giA, float nelemA,
                             const float* __restrict__ psB, const float* __restrict__ pqB,
                             float* __restrict__ gmB, float* __restrict__ giB, float nelemB){
  int idx = blockIdx.x; int t = threadIdx.x;
  __shared__ float l1[128], l2[128];
  const float* ps; const float* pq; float* gm; float* gi; float nelem; int id2;
  if (idx < 4){ ps = psA; pq = pqA; gm = gmA; gi = giA; nelem = nelemA; id2 = idx; }
  else        { ps = psB; pq = pqB; gm = gmB; gi = giB; nelem = nelemB; id2 = idx - 4; }
  float s = 0.f, ss = 0.f;
  for (int i = t; i < 256; i += 128){ s += ps[id2 * 256 + i]; ss += pq[id2 * 256 + i]; }
  l1[t] = s; l2[t] = ss; __syncthreads();
  for (int st = 64; st > 0; st >>= 1){
    if (t < st){ l1[t] += l1[t + st]; l2[t] += l2[t + st]; }
    __syncthreads();
  }
  if (t == 0){
    float mu = l1[0] / nelem;
    float var = l2[0] / nelem - mu * mu;
    gm[id2] = mu; gi[id2] = rsqrtf(var + 1e-5f);
  }
}

// ---------- merged weight transposes ----------
__global__ void k_wtall(const float* __restrict__ ph_w, const float* __restrict__ pl_w,
                        const float* __restrict__ fu_w, const float* __restrict__ se_w2,
                        float* __restrict__ wTph, float* __restrict__ wTpl,
                        float* __restrict__ wTfu, float* __restrict__ wTse){
  int idx = blockIdx.x * 256 + threadIdx.x;
  if (idx < 16384){
    int ci = idx / 128, co = idx % 128;
    wTph[idx] = ph_w[co * 128 + ci];
  } else if (idx < 20480){
    int r = idx - 16384; int ci = r / 64, co = r % 64;
    wTpl[r] = pl_w[co * 64 + ci];
  } else if (idx < 45056){
    int r = idx - 20480; int ci = r / 128, co = r % 128;
    wTfu[r] = fu_w[(size_t)co * 192 + ci];
  } else if (idx < 61440){
    int r = idx - 45056; int ci = r / 128, co = r % 128;
    wTse[r] = se_w2[co * 128 + ci];
  }
}

// ---------- shared GEMM body (raw input, K-chunk 16) --------
template<int CO, int CIT>
static __device__ __forceinline__ void gemm_body(
    const float* __restrict__ in1, const float* __restrict__ wT,
    float* __restrict__ out, float* __restrict__ psum, float* __restrict__ psq,
    int b, int j0, int slot, float* As, float* Bs, float* red){
  const int tid = threadIdx.x;
  const int tj = tid & 15, tco = tid >> 4;
  constexpr int CPT = CO / 16;
  constexpr int AST = CO + 4;
  float acc[CPT][4];
  #pragma unroll
  for (int i = 0; i < CPT; ++i)
    #pragma unroll
    for (int j = 0; j < 4; ++j) acc[i][j] = 0.f;

  for (int k0 = 0; k0 < CIT; k0 += 16){
    const int kk = tid >> 4;
    if constexpr (CO == 128){
      int co = (tid & 15) * 8;
      const float* wp = &wT[(size_t)(k0 + kk) * CO + co];
      *(float4*)&As[kk * AST + co] = *(const float4*)wp;
      *(float4*)&As[kk * AST + co + 4] = *(const float4*)(wp + 4);
    } else {
      int co = (tid & 15) * 4;
      *(float4*)&As[kk * AST + co] = *(const float4*)&wT[(size_t)(k0 + kk) * CO + co];
    }
    {
      int jj = (tid & 15) * 4;
      int ci = k0 + kk;
      float4 v = *(const float4*)&in1[((size_t)b * CIT + ci) * HW_ + j0 + jj];
      *(float4*)&Bs[kk * 68 + jj] = v;
    }
    __syncthreads();
    #pragma unroll
    for (int kkk = 0; kkk < 16; ++kkk){
      float4 bq = *(const float4*)&Bs[kkk * 68 + tj * 4];
      float av[CPT];
      if constexpr (CPT == 8){
        float4 a0 = *(const float4*)&As[kkk * AST + tco * 8];
        float4 a1 = *(const float4*)&As[kkk * AST + tco * 8 + 4];
        av[0] = a0.x; av[1] = a0.y; av[2] = a0.z; av[3] = a0.w;
        av[4] = a1.x; av[5] = a1.y; av[6] = a1.z; av[7] = a1.w;
      } else {
        float4 a0 = *(const float4*)&As[kkk * AST + tco * 4];
        av[0] = a0.x; av[1] = a0.y; av[2] = a0.z; av[3] = a0.w;
      }
      #pragma unroll
      for (int i = 0; i < CPT; ++i){
        acc[i][0] = fmaf(av[i], bq.x, acc[i][0]);
        acc[i][1] = fmaf(av[i], bq.y, acc[i][1]);
        acc[i][2] = fmaf(av[i], bq.z, acc[i][2]);
        acc[i][3] = fmaf(av[i], bq.w, acc[i][3]);
      }
    }
    __syncthreads();
  }
  float s = 0.f, ss = 0.f;
  #pragma unroll
  for (int i = 0; i < CPT; ++i){
    int co = tco * CPT + i;
    float4 o;
    o.x = acc[i][0]; o.y = acc[i][1]; o.z = acc[i][2]; o.w = acc[i][3];
    *(float4*)&out[((size_t)b * CO + co) * HW_ + j0 + tj * 4] = o;
    s += o.x + o.y + o.z + o.w;
    ss += o.x * o.x + o.y * o.y + o.z * o.z + o.w * o.w;
  }
  s = block_reduce_sum256(s, red);
  ss = block_reduce_sum256(ss, red);
  if (tid == 0){ psum[slot] = s; psq[slot] = ss; }
}

// ---------- dual GEMM: ph (128->128) || pl (64->64), 2048 blocks -------------
__global__ __launch_bounds__(256, 4) void k_gemm_dual(
    const float* __restrict__ in_ph, const float* __restrict__ wT_ph,
    float* __restrict__ out_ph, float* __restrict__ psA, float* __restrict__ pqA,
    const float* __restrict__ in_pl, const float* __restrict__ wT_pl,
    float* __restrict__ out_pl, float* __restrict__ psB, float* __restrict__ pqB){
  __shared__ float As[16 * 132];
  __shared__ float Bs[16 * 68];
  __shared__ float red[256];
  int b = blockIdx.x;
  if (blockIdx.y < 256){
    int yb = blockIdx.y;
    gemm_body<128, 128>(in_ph, wT_ph, out_ph, psA, pqA, b, yb * 64, b * 256 + yb, As, Bs, red);
  } else {
    int yb = blockIdx.y - 256;
    gemm_body<64, 64>(in_pl, wT_pl, out_pl, psB, pqB, b, yb * 64, b * 256 + yb, As, Bs, red);
  }
}

// ---------- tiled 1x1-conv GEMM (K-chunk 16) with GN+GELU on input -----------
template<int CO, int CIT>
__global__ __launch_bounds__(256, 4) void k_gemm1x1(
    const float* __restrict__ in1, const float* __restrict__ in2, int CI1,
    const float* __restrict__ wT, const float* __restrict__ bias,
    const float* __restrict__ gm1, const float* __restrict__ gi1,
    const float* __restrict__ ga1, const float* __restrict__ be1, int sh1, int ng1,
    const float* __restrict__ gm2, const float* __restrict__ gi2,
    const float* __restrict__ ga2, const float* __restrict__ be2, int sh2, int ng2,
    float* __restrict__ out, float* __restrict__ psum, float* __restrict__ psq){
  __shared__ float As[16][CO + 4];
  __shared__ float Bs[16][68];
  __shared__ float red[256];
  const int b = blockIdx.x;
  const int j0 = blockIdx.y * 64;
  const int tid = threadIdx.x;
  const int tj = tid & 15, tco = tid >> 4;
  constexpr int CPT = CO / 16;

  float acc[CPT][4];
  #pragma unroll
  for (int i = 0; i < CPT; ++i)
    #pragma unroll
    for (int j = 0; j < 4; ++j) acc[i][j] = 0.f;

  for (int k0 = 0; k0 < CIT; k0 += 16){
    const int kk = tid >> 4;
    if constexpr (CO == 128){
      int co = (tid & 15) * 8;
      const float* wp = &wT[(size_t)(k0 + kk) * CO + co];
      *(float4*)&As[kk][co] = *(const float4*)wp;
      *(float4*)&As[kk][co + 4] = *(const float4*)(wp + 4);
    } else {
      int co = (tid & 15) * 4;
      *(float4*)&As[kk][co] = *(const float4*)&wT[(size_t)(k0 + kk) * CO + co];
    }
    {
      int jj = (tid & 15) * 4;
      int ci = k0 + kk;
      float4 v;
      if (ci < CI1){
        v = *(const float4*)&in1[((size_t)b * CI1 + ci) * HW_ + j0 + jj];
        if (gm1){
          int g = ci >> sh1;
          float rs = gi1[b * ng1 + g];
          float ga = ga1[ci] * rs;
          float be = be1[ci] - gm1[b * ng1 + g] * ga;
          v.x = gelu_f(fmaf(v.x, ga, be)); v.y = gelu_f(fmaf(v.y, ga, be));
          v.z = gelu_f(fmaf(v.z, ga, be)); v.w = gelu_f(fmaf(v.w, ga, be));
        }
      } else {
        int c2 = ci - CI1;
        v = *(const float4*)&in2[((size_t)b * (CIT - CI1) + c2) * HW_ + j0 + jj];
        if (gm2){
          int g = c2 >> sh2;
          float rs = gi2[b * ng2 + g];
          float ga = ga2[c2] * rs;
          float be = be2[c2] - gm2[b * ng2 + g] * ga;
          v.x = gelu_f(fmaf(v.x, ga, be)); v.y = gelu_f(fmaf(v.y, ga, be));
          v.z = gelu_f(fmaf(v.z, ga, be)); v.w = gelu_f(fmaf(v.w, ga, be));
        }
      }
      *(float4*)&Bs[kk][jj] = v;
    }
    __syncthreads();
    #pragma unroll
    for (int kkk = 0; kkk < 16; ++kkk){
      float4 bq = *(const float4*)&Bs[kkk][tj * 4];
      float av[CPT];
      if constexpr (CPT == 8){
        float4 a0 = *(const float4*)&As[kkk][tco * 8];
        float4 a1 = *(const float4*)&As[kkk][tco * 8 + 4];
        av[0] = a0.x; av[1] = a0.y; av[2] = a0.z; av[3] = a0.w;
        av[4] = a1.x; av[5] = a1.y; av[6] = a1.z; av[7] = a1.w;
      } else {
        float4 a0 = *(const float4*)&As[kkk][tco * 4];
        av[0] = a0.x; av[1] = a0.y; av[2] = a0.z; av[3] = a0.w;
      }
      #pragma unroll
      for (int i = 0; i < CPT; ++i){
        acc[i][0] = fmaf(av[i], bq.x, acc[i][0]);
        acc[i][1] = fmaf(av[i], bq.y, acc[i][1]);
        acc[i][2] = fmaf(av[i], bq.z, acc[i][2]);
        acc[i][3] = fmaf(av[i], bq.w, acc[i][3]);
      }
    }
    __syncthreads();
  }
  float s = 0.f, ss = 0.f;
  #pragma unroll
  for (int i = 0; i < CPT; ++i){
    int co = tco * CPT + i;
    float bb = bias ? bias[co] : 0.f;
    float4 o;
    o.x = acc[i][0] + bb; o.y = acc[i][1] + bb;
    o.z = acc[i][2] + bb; o.w = acc[i][3] + bb;
    *(float4*)&out[((size_t)b * CO + co) * HW_ + j0 + tj * 4] = o;
    s += o.x + o.y + o.z + o.w;
    ss += o.x * o.x + o.y * o.y + o.z * o.z + o.w * o.w;
  }
  if (psum){
    s = block_reduce_sum256(s, red);
    ss = block_reduce_sum256(ss, red);
    if (tid == 0){
      psum[b * gridDim.y + blockIdx.y] = s;
      psq [b * gridDim.y + blockIdx.y] = ss;
    }
  }
}

// ---------- grouped 3x3 conv, column-scalar mapping --------------------------
// Variants measured: scalar/16-row 70us, scalar/8-row 73us (0 conflicts),
// windowed-b128 117us (VGPR 132), strip-b128 76us (5.4M conflicts).
// Lesson: b128 row-reads by a wave are intrinsically 4x-oversubscribed on
// banks; scalar 1-col/lane reads are conflict-free. This version keeps scalar
// reads but cuts LDS instrs ~2.7x: thread=(half,col) [64 lanes = 64 distinct
// cols -> 2-way, free]; co_l outer so only acc[4]+w9[9] live (VGPR ~40);
// per (co,cil) slide 6 xs rows x 3 guarded scalar reads, fan each row into
// the <=3 output rows it feeds. 288 xs reads + 144 w-loads vs R15's ~1152.
__global__ __launch_bounds__(256) void k_se3(const float* __restrict__ x,
    const float* __restrict__ gm, const float* __restrict__ gi,
    const float* __restrict__ gamma, const float* __restrict__ beta,
    const float* __restrict__ w, const float* __restrict__ bias,
    float* __restrict__ out, float* __restrict__ psum, float* __restrict__ psq){
  __shared__ float xs[4][10][128];
  __shared__ float ws[144];
  __shared__ float wb[4];
  __shared__ float red[256];
  const int bgc = blockIdx.x; const int b = bgc >> 5, gc = bgc & 31;
  const int r0 = blockIdx.y * 8;
  const int tid = threadIdx.x;
  const float mu = gm[b], rs = gi[b];
  for (int ch = 0; ch < 4; ++ch){
    int c = gc * 4 + ch;
    float ga = gamma[c] * rs, be = beta[c] - mu * rs * gamma[c];
    const float* px = x + ((size_t)b * C_ + c) * HW_;
    for (int i = tid; i < 10 * 128; i += 256){
      int rr = i >> 7, cc = i & 127;
      int row = r0 - 1 + rr;
      float v = 0.f;
      if ((unsigned)row < 128u) v = gelu_f(fmaf(px[row * W_ + cc], ga, be));
      xs[ch][rr][cc] = v;
    }
  }
  if (tid < 144) ws[tid] = w[(size_t)(gc * 4) * 36 + tid];
  if (tid < 4)   wb[tid] = bias[gc * 4 + tid];
  __syncthreads();
  // thread = (half, col): half owns output rows 4h..4h+3, xs rows 4h..4h+5
  const int hf = tid >> 7;          // 0..1
  const int cc = tid & 127;         // 0..127 (64 distinct cols per wave)
  float s = 0.f, ss = 0.f;
  for (int co_l = 0; co_l < 4; ++co_l){
    float bb = wb[co_l];
    float a0 = bb, a1 = bb, a2 = bb, a3 = bb;
    #pragma unroll
    for (int cil = 0; cil < 4; ++cil){
      float w9[9];
      #pragma unroll
      for (int i = 0; i < 9; ++i) w9[i] = ws[(co_l * 4 + cil) * 9 + i];
      #pragma unroll
      for (int q = 0; q < 6; ++q){
        int xr = 4 * hf + q;
        float mdl = xs[cil][xr][cc];
        float lft = (cc > 0)   ? xs[cil][xr][cc - 1] : 0.f;
        float rgt = (cc < 127) ? xs[cil][xr][cc + 1] : 0.f;
        // output o receives from q when ky=q-o in [0,2]
        if (q <= 2){        // o = q-ky down to 0
          { int ky = q;     a0 = fmaf(w9[ky*3], lft, a0); a0 = fmaf(w9[ky*3+1], mdl, a0); a0 = fmaf(w9[ky*3+2], rgt, a0); }
        }
        if (q >= 1 && q <= 3){
          int ky = q - 1;   a1 = fmaf(w9[ky*3], lft, a1); a1 = fmaf(w9[ky*3+1], mdl, a1); a1 = fmaf(w9[ky*3+2], rgt, a1);
        }
        if (q >= 2 && q <= 4){
          int ky = q - 2;   a2 = fmaf(w9[ky*3], lft, a2); a2 = fmaf(w9[ky*3+1], mdl, a2); a2 = fmaf(w9[ky*3+2], rgt, a2);
        }
        if (q >= 3){
          int ky = q - 3;   a3 = fmaf(w9[ky*3], lft, a3); a3 = fmaf(w9[ky*3+1], mdl, a3); a3 = fmaf(w9[ky*3+2], rgt, a3);
        }
      }
    }
    float* po = &out[((size_t)b * C_ + gc * 4 + co_l) * HW_ + (r0 + 4 * hf) * W_ + cc];
    po[0]       = a0;
    po[W_]      = a1;
    po[2 * W_]  = a2;
    po[3 * W_]  = a3;
    s += a0 + a1 + a2 + a3;
    ss += a0 * a0 + a1 * a1 + a2 * a2 + a3 * a3;
  }
  s = block_reduce_sum256(s, red);
  ss = block_reduce_sum256(ss, red);
  if (tid == 0){
    int idx = (b * 4 + (gc >> 3)) * 128 + (gc & 7) * 16 + blockIdx.y;
    psum[idx] = s; psq[idx] = ss;
  }
}

// ---------- fused: x_enh -> y (3x3 dyn) -> h (3x3 dw) + GN stats for h -------
__global__ __launch_bounds__(256) void k_ydw(const float* __restrict__ x,
    const float* __restrict__ factor,
    const float* __restrict__ gm, const float* __restrict__ gi,
    const float* __restrict__ gamma, const float* __restrict__ beta,
    const float* __restrict__ w_eff, const float* __restrict__ dw_w,
    const float* __restrict__ dw_b, float* __restrict__ y_out,
    float* __restrict__ h_out, float* __restrict__ psum, float* __restrict__ psq){
  __shared__ float xs[36][128];
  __shared__ float ys[34][128];
  __shared__ float red[256];
  const int bc = blockIdx.x; const int b = bc >> 7, c = bc & 127;
  const int r0 = blockIdx.y * 32;
  const int tid = threadIdx.x;
  const float mu = gm[b], rs = gi[b];
  const float ga = gamma[c] * rs, be = beta[c] - mu * rs * gamma[c];
  const float* px = x + ((size_t)b * C_ + c) * HW_;
  const float* pf = factor + (size_t)b * HW_;
  for (int i = tid; i < 36 * 128; i += 256){
    int rr = i >> 7, cc = i & 127;
    int row = r0 - 2 + rr;
    float v = 0.f;
    if ((unsigned)row < 128u)
      v = gelu_f(fmaf(px[row * W_ + cc], ga, be)) * pf[row * W_ + cc];
    xs[rr][cc] = v;
  }
  __syncthreads();
  float w9[9];
  #pragma unroll
  for (int r = 0; r < 9; ++r) w9[r] = w_eff[b * 1152 + c * 9 + r];
  for (int i = tid; i < 34 * 128; i += 256){
    int rr = i >> 7, cc = i & 127;
    int row = r0 - 1 + rr;
    float acc = 0.f;
    if ((unsigned)row < 128u){
      #pragma unroll
      for (int ky = 0; ky < 3; ++ky){
        #pragma unroll
        for (int kx = 0; kx < 3; ++kx){
          int xc = cc + kx - 1;
          if ((unsigned)xc < 128u) acc += w9[ky * 3 + kx] * xs[rr + ky][xc];
        }
      }
    }
    ys[rr][cc] = acc;
    if (rr >= 1 && rr <= 32)
      y_out[((size_t)b * C_ + c) * HW_ + row * W_ + cc] = acc;
  }
  __syncthreads();
  float wd[9];
  #pragma unroll
  for (int r = 0; r < 9; ++r) wd[r] = dw_w[c * 9 + r];
  const float bb = dw_b[c];
  float s = 0.f, ss = 0.f;
  for (int i = tid; i < 32 * 128; i += 256){
    int rr = i >> 7, cc = i & 127;
    int row = r0 + rr;
    float acc = bb;
    #pragma unroll
    for (int ky = 0; ky < 3; ++ky){
      #pragma unroll
      for (int kx = 0; kx < 3; ++kx){
        int yc = cc + kx - 1;
        if ((unsigned)yc < 128u) acc += wd[ky * 3 + kx] * ys[rr + ky][yc];
      }
    }
    h_out[((size_t)b * C_ + c) * HW_ + row * W_ + cc] = acc;
    s += acc; ss += acc * acc;
  }
  s = block_reduce_sum256(s, red);
  ss = block_reduce_sum256(ss, red);
  if (tid == 0){
    int idx = b * 512 + c * 4 + blockIdx.y;
    psum[idx] = s; psq[idx] = ss;
  }
}

// ---------- prototype init MLP (per b) ----------
__global__ void k_pinit(const float* __restrict__ temb, const float* __restrict__ w1,
                        const float* __restrict__ b1, const float* __restrict__ w2,
                        const float* __restrict__ b2, float* __restrict__ pinit){
  int b = blockIdx.x; int t = threadIdx.x;
  __shared__ float h1[256], p2[256], nrm[2];
  float acc = b1[t];
  for (int i = 0; i < TDIM_; ++i) acc += temb[b * TDIM_ + i] * w1[t * TDIM_ + i];
  h1[t] = gelu_f(acc); __syncthreads();
  acc = b2[t];
  for (int i = 0; i < 256; ++i) acc += h1[i] * w2[t * 256 + i];
  p2[t] = acc; __syncthreads();
  if (t < 2){
    float s = 0.f;
    for (int c = 0; c < 128; ++c){ float v = p2[t * 128 + c]; s += v * v; }
    nrm[t] = fmaxf(sqrtf(s), 1e-12f);
  }
  __syncthreads();
  pinit[b * 256 + t] = p2[t] / nrm[t / 128];
}

// ---------- table / protos / fg,bg ----------
__global__ void k_protos(const float* __restrict__ pinit, const int* __restrict__ task_ids,
                         float* __restrict__ fg, float* __restrict__ bg){
  __shared__ int tbl[NT_];
  __shared__ int src[B_];
  __shared__ float nr[B_ * 2];
  int t = threadIdx.x;
  if (t < NT_){
    int idx = 0;
    for (int b = B_ - 1; b >= 0; --b) if (task_ids[b] == t) idx = b;
    tbl[t] = idx;
  }
  __syncthreads();
  if (t < B_){
    int ti = task_ids[t]; ti = ti < 0 ? 0 : (ti >= NT_ ? NT_ - 1 : ti);
    src[t] = tbl[ti];
  }
  __syncthreads();
  if (t < 2 * B_){
    int b = t / 2, r = t % 2;
    float s = 0.f;
    for (int c = 0; c < 128; ++c){ float v = pinit[src[b] * 256 + r * 128 + c]; s += v * v; }
    nr[t] = fmaxf(sqrtf(s), 1e-12f);
  }
  __syncthreads();
  for (int i = t; i < B_ * 128; i += 256){
    int b = i / 128, c = i % 128;
    fg[i] = pinit[src[b] * 256 + c] / nr[b * 2 + 0];
    bg[i] = pinit[src[b] * 256 + 128 + c] / nr[b * 2 + 1];
  }
}

// ---------- q projection folded into key space ----------
__global__ void k_qk(const float* __restrict__ fg, const float* __restrict__ bg,
                     const float* __restrict__ at_in_w, const float* __restrict__ at_in_b,
                     float* __restrict__ qkvec, float* __restrict__ kdot){
  int b = blockIdx.x, t = threadIdx.x;
  __shared__ float pq[256], qf[256];
  pq[t] = (t < 128) ? fg[b * 128 + t] : bg[b * 128 + (t - 128)];
  __syncthreads();
  {
    int qi = t / 128, o = t % 128;
    float acc = at_in_b[o];
    const float* wr = at_in_w + (size_t)o * 128;
    for (int c = 0; c < 128; ++c) acc += wr[c] * pq[qi * 128 + c];
    qf[qi * 128 + o] = acc;
  }
  __syncthreads();
  for (int e = t; e < 1024; e += 256){
    int p = e / 128, c = e % 128, qi = p / 4, h = p % 4;
    float acc = 0.f;
    for (int d = 0; d < 32; ++d)
      acc += qf[qi * 128 + h * 32 + d] * at_in_w[(size_t)(128 + h * 32 + d) * 128 + c];
    qkvec[b * 1024 + e] = acc;
  }
  if (t < 8){
    int qi = t / 4, h = t % 4;
    float acc = 0.f;
    for (int d = 0; d < 32; ++d) acc += qf[qi * 128 + h * 32 + d] * at_in_b[128 + h * 32 + d];
    kdot[b * 8 + t] = acc;
  }
}

// ---------- fused: sim + factor + 8 score rows + |sim| partials --------------
__global__ __launch_bounds__(256) void k_simscores(const float* __restrict__ sf,
                          const float* __restrict__ fg, const float* __restrict__ bg,
                          const float* __restrict__ qkvec, const float* __restrict__ kdot,
                          float* __restrict__ sim, float* __restrict__ factor,
                          float* __restrict__ scores, float* __restrict__ psim){
  int b = blockIdx.x; int j = blockIdx.y * 256 + threadIdx.x;
  __shared__ float L[10 * 128];
  __shared__ float red[256];
  for (int i = threadIdx.x; i < 1280; i += 256){
    int r = i >> 7, c = i & 127;
    L[i] = (r == 0) ? fg[b * 128 + c]
         : (r == 1) ? bg[b * 128 + c]
                    : qkvec[b * 1024 + (r - 2) * 128 + c];
  }
  __syncthreads();
  const float* p = sf + (size_t)b * C_ * HW_ + j;
  float a0=0,a1=0,q0=0,q1=0,q2=0,q3=0,q4=0,q5=0,q6=0,q7=0,nn=0;
  #pragma unroll 8
  for (int c = 0; c < C_; ++c){
    float v = p[(size_t)c * HW_];
    nn += v * v;
    a0 += L[c] * v;          a1 += L[128 + c] * v;
    q0 += L[256 + c] * v;    q1 += L[384 + c] * v;
    q2 += L[512 + c] * v;    q3 += L[640 + c] * v;
    q4 += L[768 + c] * v;    q5 += L[896 + c] * v;
    q6 += L[1024 + c] * v;   q7 += L[1152 + c] * v;
  }
  float inv = 1.f / fmaxf(sqrtf(nn), 1e-12f);
  float sv = (a0 - a1) * inv;
  sim[b * HW_ + j] = sv;
  factor[b * HW_ + j] = 1.f + 0.5f / (1.f + expf(-sv));
  const float scale = 0.17677669529663689f;
  float qs[8] = {q0,q1,q2,q3,q4,q5,q6,q7};
  #pragma unroll
  for (int pp = 0; pp < 8; ++pp)
    scores[((size_t)(b * 8 + pp)) * HW_ + j] = (qs[pp] + kdot[b * 8 + pp]) * scale;
  float as = block_reduce_sum256(fabsf(sv), red);
  if (threadIdx.x == 0) psim[b * 64 + blockIdx.y] = as;
}

__global__ void k_smstats(const float* __restrict__ scores, float* __restrict__ smax,
                          float* __restrict__ ssum){
  __shared__ float lds[256];
  int row = blockIdx.x;
  const float* p = scores + (size_t)row * HW_;
  float m = -1e30f;
  for (int j = threadIdx.x; j < HW_; j += 256) m = fmaxf(m, p[j]);
  lds[threadIdx.x] = m; __syncthreads();
  for (int s = 128; s > 0; s >>= 1){
    if (threadIdx.x < s) lds[threadIdx.x] = fmaxf(lds[threadIdx.x], lds[threadIdx.x + s]);
    __syncthreads();
  }
  m = lds[0]; __syncthreads();
  float z = 0.f;
  for (int j = threadIdx.x; j < HW_; j += 256) z += expf(p[j] - m);
  z = block_reduce_sum256(z, lds);
  if (threadIdx.x == 0){ smax[row] = m; ssum[row] = z; }
}

// ---------- wsum, 4-way j-split ----------------------------------------------
__global__ void k_wsum(const float* __restrict__ sf, const float* __restrict__ scores,
                       const float* __restrict__ smax, const float* __restrict__ ssum,
                       float* __restrict__ wsum4){
  int bc = blockIdx.x; int b = bc / C_, c = bc % C_;
  int chunk = blockIdx.y;
  __shared__ float lds[8 * 256];
  __shared__ float mr[8], zr[8];
  if (threadIdx.x < 8){
    mr[threadIdx.x] = smax[b * 8 + threadIdx.x];
    zr[threadIdx.x] = 1.f / ssum[b * 8 + threadIdx.x];
  }
  __syncthreads();
  const float* p = sf + (size_t)bc * HW_;
  const float* sc = scores + (size_t)b * 8 * HW_;
  int j0 = chunk * (HW_ / 4), j1 = j0 + HW_ / 4;
  float acc[8] = {0,0,0,0,0,0,0,0};
  for (int j = j0 + threadIdx.x; j < j1; j += 256){
    float v = p[j];
    #pragma unroll
    for (int pp = 0; pp < 8; ++pp)
      acc[pp] = fmaf(expf(sc[(size_t)pp * HW_ + j] - mr[pp]) * zr[pp], v, acc[pp]);
  }
  #pragma unroll
  for (int pp = 0; pp < 8; ++pp) lds[pp * 256 + threadIdx.x] = acc[pp];
  __syncthreads();
  for (int s = 128; s > 0; s >>= 1){
    if (threadIdx.x < s){
      #pragma unroll
      for (int pp = 0; pp < 8; ++pp) lds[pp * 256 + threadIdx.x] += lds[pp * 256 + threadIdx.x + s];
    }
    __syncthreads();
  }
  if (threadIdx.x < 8)
    wsum4[chunk * 4096 + b * 1024 + threadIdx.x * 128 + c] = lds[threadIdx.x * 256];
}

// ---------- small head chain (sums the 4 wsum partials on load) --------------
__global__ void k_small(const float* __restrict__ wsum4, const float* __restrict__ at_in_w,
                        const float* __restrict__ at_in_b, const float* __restrict__ at_out_w,
                        const float* __restrict__ at_out_b, const float* __restrict__ pf_w,
                        const float* __restrict__ pf_b, const float* __restrict__ eg_w1,
                        const float* __restrict__ eg_b1, const float* __restrict__ ewg_w,
                        const float* __restrict__ ewg_b, float* __restrict__ eg1_out,
                        float* __restrict__ ew_out){
  int b = blockIdx.x; int t = threadIdx.x;
  __shared__ float wsl[1024], att[256], ao[256], pf[128], ewl[8];
  for (int i = t; i < 1024; i += 256)
    wsl[i] = wsum4[b * 1024 + i] + wsum4[4096 + b * 1024 + i]
           + wsum4[8192 + b * 1024 + i] + wsum4[12288 + b * 1024 + i];
  __syncthreads();
  {
    int qi = t / 128, o = t % 128, h = o / 32, d = o % 32, p = qi * 4 + h;
    float acc = at_in_b[256 + h * 32 + d];
    const float* wr = at_in_w + (size_t)(256 + h * 32 + d) * 128;
    for (int c = 0; c < 128; ++c) acc += wr[c] * wsl[p * 128 + c];
    att[qi * 128 + o] = acc;
  }
  __syncthreads();
  {
    int qi = t / 128, o = t % 128;
    float acc = at_out_b[o];
    const float* wr = at_out_w + (size_t)o * 128;
    for (int c = 0; c < 128; ++c) acc += wr[c] * att[qi * 128 + c];
    ao[qi * 128 + o] = acc;
  }
  __syncthreads();
  if (t < 128){
    float acc = pf_b[t];
    const float* wr = pf_w + (size_t)t * 384;
    for (int c = 0; c < 128; ++c){
      float fa = ao[c], ba = ao[128 + c];
      acc += wr[c] * fa + wr[128 + c] * ba + wr[256 + c] * (fa - ba);
    }
    pf[t] = acc;
  }
  __syncthreads();
  {
    float acc = eg_b1[t];
    const float* wr = eg_w1 + (size_t)t * 128;
    for (int c = 0; c < 128; ++c) acc += wr[c] * pf[c];
    eg1_out[b * 256 + t] = gelu_f(acc);
  }
  if (t < M_){
    float acc = ewg_b[t];
    const float* wr = ewg_w + (size_t)t * 128;
    for (int c = 0; c < 128; ++c) acc += wr[c] * pf[c];
    ewl[t] = acc;
  }
  __syncthreads();
  if (t == 0){
    float m = -1e30f;
    for (int i = 0; i < M_; ++i) m = fmaxf(m, ewl[i]);
    float z = 0.f;
    for (int i = 0; i < M_; ++i){ ewl[i] = expf(ewl[i] - m); z += ewl[i]; }
    for (int i = 0; i < M_; ++i) ew_out[b * M_ + i] = ewl[i] / z;
  }
}

// ---------- w_eff[b,c,r] ----------
__global__ void k_weff(const float* __restrict__ eg1, const float* __restrict__ ew,
                       const float* __restrict__ eg_w2, const float* __restrict__ eg_b2,
                       const float* __restrict__ eis_p, float* __restrict__ w_eff){
  int b = blockIdx.x; int cr = blockIdx.y * 256 + threadIdx.x;
  __shared__ float e1[256]; __shared__ float ewl[M_];
  e1[threadIdx.x] = eg1[b * 256 + threadIdx.x];
  if (threadIdx.x < M_) ewl[threadIdx.x] = ew[b * M_ + threadIdx.x];
  __syncthreads();
  if (cr >= C_ * 9) return;
  int c = cr / 9, r = cr % 9;
  float eis = eis_p[0];
  float acc = 0.f;
  for (int m = 0; m < M_; ++m){
    size_t row = ((size_t)m * C_ + c) * 9 + r;
    float v = eg_b2[row];
    const float* wr = eg_w2 + row * 256;
    for (int i = 0; i < 256; ++i) v += wr[i] * e1[i];
    float ekv = v * eis + ((r == 4) ? (1.f - eis) : 0.f);
    acc += ewl[m] * ekv;
  }
  w_eff[b * (C_ * 9) + cr] = acc;
}

// ---------- head: gn+gelu fused into 1x1 conv to NT channel ----------
__global__ void k_logits(const float* __restrict__ h, const float* __restrict__ gmean,
                         const float* __restrict__ ginv, const float* __restrict__ hd_g,
                         const float* __restrict__ hd_be, const float* __restrict__ hd_w2,
                         const float* __restrict__ hd_b2, const int* __restrict__ task_ids,
                         float* __restrict__ logits){
  int b = blockIdx.x; int j = blockIdx.y * 256 + threadIdx.x;
  int it = task_ids[b]; it = it < 0 ? 0 : (it >= NT_ ? NT_ - 1 : it);
  __shared__ float wg[128], wb[128], w2[128];
  if (threadIdx.x < 128){
    wg[threadIdx.x] = hd_g[threadIdx.x];
    wb[threadIdx.x] = hd_be[threadIdx.x];
    w2[threadIdx.x] = hd_w2[it * C_ + threadIdx.x];
  }
  __syncthreads();
  float mu = gmean[b], rs = ginv[b];
  const float* p = h + (size_t)b * C_ * HW_ + j;
  float acc = hd_b2[it];
  #pragma unroll 4
  for (int c = 0; c < C_; ++c){
    float v = p[(size_t)c * HW_];
    v = (v - mu) * rs * wg[c] + wb[c];
    acc += w2[c] * gelu_f(v);
  }
  logits[b * HW_ + j] = acc;
}

// ---------- final: |sim| partial reduce inline + fsw write -------------------
__global__ void k_final(float* __restrict__ logits, const float* __restrict__ sim,
                        const float* __restrict__ psim, const float* __restrict__ sim_temp,
                        const float* __restrict__ proto_amp,
                        const float* __restrict__ asw, float* __restrict__ fsw_out){
  __shared__ float red[256];
  float s = psim[threadIdx.x];  // exactly B_*64 = 256 partials
  s = block_reduce_sum256(s, red);
  int idx = blockIdx.x * 256 + threadIdx.x;
  float mean = s / (float)(B_ * HW_);
  float denom = mean + 1e-6f;
  float temp = fmaxf(sim_temp[0], 0.001f);
  float v = tanhf(sim[idx] / denom / temp);
  logits[idx] += 5.0f * proto_amp[0] * v;
  if (blockIdx.x == 0 && threadIdx.x < B_){
    float a = 1.0f * asw[0];
    fsw_out[threadIdx.x] = a / a;
  }
}

extern "C" void kernel_launch(void* const* d_in, const int* in_sizes, int n_in,
                              void* d_out, int out_size, void* d_ws, size_t ws_size,
                              hipStream_t stream){
  const float* x_low   = (const float*)d_in[0];
  const float* x_high  = (const float*)d_in[1];
  const float* temb    = (const float*)d_in[2];
  const float* pl_w    = (const float*)d_in[3];
  const float* pl_g    = (const float*)d_in[4];
  const float* pl_b    = (const float*)d_in[5];
  const float* ph_w    = (const float*)d_in[6];
  const float* ph_g    = (const float*)d_in[7];
  const float* ph_b    = (const float*)d_in[8];
  const float* fu_w    = (const float*)d_in[9];
  const float* fu_g    = (const float*)d_in[10];
  const float* fu_b    = (const float*)d_in[11];
  const float* pi_w1   = (const float*)d_in[12];
  const float* pi_b1   = (const float*)d_in[13];
  const float* pi_w2   = (const float*)d_in[14];
  const float* pi_b2   = (const float*)d_in[15];
  const float* se_w1   = (const float*)d_in[16];
  const float* se_b1   = (const float*)d_in[17];
  const float* se_g    = (const float*)d_in[18];
  const float* se_be   = (const float*)d_in[19];
  const float* se_w2   = (const float*)d_in[20];
  const float* se_b2   = (const float*)d_in[21];
  const float* at_in_w = (const float*)d_in[22];
  const float* at_in_b = (const float*)d_in[23];
  const float* at_out_w= (const float*)d_in[24];
  const float* at_out_b= (const float*)d_in[25];
  const float* pf_w    = (const float*)d_in[26];
  const float* pf_b    = (const float*)d_in[27];
  const float* asw     = (const float*)d_in[32];
  const float* eg_w1   = (const float*)d_in[33];
  const float* eg_b1   = (const float*)d_in[34];
  const float* eg_w2   = (const float*)d_in[35];
  const float* eg_b2   = (const float*)d_in[36];
  const float* ewg_w   = (const float*)d_in[37];
  const float* ewg_b   = (const float*)d_in[38];
  const float* hd_w1   = (const float*)d_in[39];
  const float* hd_b1   = (const float*)d_in[40];
  const float* hd_g    = (const float*)d_in[41];
  const float* hd_be   = (const float*)d_in[42];
  const float* hd_w2   = (const float*)d_in[43];
  const float* hd_b2   = (const float*)d_in[44];
  const float* eis     = (const float*)d_in[45];
  const float* sim_temp= (const float*)d_in[46];
  const float* proto_amp=(const float*)d_in[47];
  const int*   task_ids= (const int*)d_in[48];

  float* ws = (float*)d_ws;
  const size_t BIG = (size_t)B_ * C_ * HW_; // 8,388,608
  float* S0 = ws;
  float* S1 = ws + BIG;
  float* S2 = ws + 2 * BIG;
  float* scores = ws + 3 * BIG;              // B*8*HW = 524288
  float* sm = scores + (size_t)B_ * 8 * HW_;
  float* sim     = sm;             sm += (size_t)B_ * HW_;
  float* factor  = sm;             sm += (size_t)B_ * HW_;
  float* logitsb = sm;             sm += (size_t)B_ * HW_;
  float* psA = sm; sm += 1024; float* pqA = sm; sm += 1024;
  float* psB = sm; sm += 1024; float* pqB = sm; sm += 1024;
  float* psC = sm; sm += 1024; float* pqC = sm; sm += 1024;
  float* ps3 = sm; sm += 2048; float* pq3 = sm; sm += 2048;
  float* psH = sm; sm += 2048; float* pqH = sm; sm += 2048;
  float* gmA = sm; sm += 4;  float* giA = sm; sm += 4;
  float* gmB = sm; sm += 4;  float* giB = sm; sm += 4;
  float* gmC = sm; sm += 4;  float* giC = sm; sm += 4;
  float* gm3 = sm; sm += 16; float* gi3 = sm; sm += 16;
  float* gmH = sm; sm += 4;  float* giH = sm; sm += 4;
  float* pinitb  = sm;             sm += 1024;
  float* fgb     = sm;             sm += 512;
  float* bgb     = sm;             sm += 512;
  float* qkvecb  = sm;             sm += 4096;
  float* kdotb   = sm;             sm += 32;
  float* smaxb   = sm;             sm += 32;
  float* ssumb   = sm;             sm += 32;
  float* wsum4b  = sm;             sm += 16384;
  float* eg1b    = sm;             sm += 1024;
  float* ewb     = sm;             sm += 32;
  float* weffb   = sm;             sm += 4608;
  float* psimb   = sm;             sm += 256;
  float* wTph    = sm;             sm += 128 * 128;
  float* wTpl    = sm;             sm += 64 * 64;
  float* wTfu    = sm;             sm += 192 * 128;
  float* wTse    = sm;             sm += 128 * 128;

  float* pred_out = (float*)d_out;                       // 4*512*512
  float* y_out    = pred_out + (size_t)B_ * 512 * 512;   // 4*128*128*128
  float* fsw_out  = y_out + BIG;                         // 4

  dim3 blk(256);
  const float* NF = nullptr;
  float* NFm = nullptr;

  // 0. merged weight transposes
  k_wtall<<<240, blk, 0, stream>>>(ph_w, pl_w, fu_w, se_w2, wTph, wTpl, wTfu, wTse);
  // 1. resize x_high -> S0
  k_resize<<<(unsigned)(BIG / 256), blk, 0, stream>>>(x_high, S0, B_ * C_, 64, 64, 128, 128);
  // 2. DUAL gemm: ph (S0 -> S1) || pl (x_low -> S2 low)
  k_gemm_dual<<<dim3(B_, 512), blk, 0, stream>>>(S0, wTph, S1, psA, pqA,
                                                 x_low, wTpl, S2, psB, pqB);
  k_stat2_dual<<<8, 128, 0, stream>>>(psA, pqA, gmA, giA, (float)(128 * HW_),
                                      psB, pqB, gmB, giB, (float)(64 * HW_));
  // 3. fu conv: concat(gelu(gn(S1)), gelu(gn(S2 low))) -> S0
  k_gemm1x1<128,192><<<dim3(B_, 256), blk, 0, stream>>>(S1, S2, 128, wTfu, NF,
      gmA,giA,ph_g,ph_b,7,1, gmB,giB,pl_g,pl_b,6,1, S0, psC, pqC);
  k_stat2<<<B_, 128, 0, stream>>>(psC, pqC, gmC, giC, 256, (float)(128 * HW_));
  // 4. se grouped conv3x3 (column-scalar) on x=gelu(gn(S0)) -> S2, GN(4) stats
  k_se3<<<dim3(B_ * 32, 16), blk, 0, stream>>>(S0, gmC, giC, fu_g, fu_b,
      se_w1, se_b1, S2, ps3, pq3);
  k_stat2<<<B_ * 4, 128, 0, stream>>>(ps3, pq3, gm3, gi3, 128, (float)(32 * HW_));
  // 5. se conv1x1 on gelu(gn4(S2)) (+bias) -> S1 = sf
  k_gemm1x1<128,128><<<dim3(B_, 256), blk, 0, stream>>>(S2, NF, 128, wTse, se_b2,
      gm3,gi3,se_g,se_be,5,4, NF,NF,NF,NF,0,0, S1, NFm, NFm);
  // 6. prototypes + folded q
  k_pinit<<<B_, blk, 0, stream>>>(temb, pi_w1, pi_b1, pi_w2, pi_b2, pinitb);
  k_protos<<<1, blk, 0, stream>>>(pinitb, task_ids, fgb, bgb);
  k_qk<<<B_, blk, 0, stream>>>(fgb, bgb, at_in_w, at_in_b, qkvecb, kdotb);
  // 7. fused sim+factor+scores+|sim| partials
  k_simscores<<<dim3(B_, 64), blk, 0, stream>>>(S1, fgb, bgb, qkvecb, kdotb,
                                                sim, factor, scores, psimb);
  // 8. softmax stats + weighted sums (4-way j-split)
  k_smstats<<<B_ * 8, blk, 0, stream>>>(scores, smaxb, ssumb);
  k_wsum<<<dim3(B_ * C_, 4), blk, 0, stream>>>(S1, scores, smaxb, ssumb, wsum4b);
  // 9. small head chain + w_eff
  k_small<<<B_, blk, 0, stream>>>(wsum4b, at_in_w, at_in_b, at_out_w, at_out_b,
                                  pf_w, pf_b, eg_w1, eg_b1, ewg_w, ewg_b, eg1b, ewb);
  k_weff<<<dim3(B_, 5), blk, 0, stream>>>(eg1b, ewb, eg_w2, eg_b2, eis, weffb);
  // 10. fused x_enh -> y -> h (x = fu raw out = S0; h -> S2)
  k_ydw<<<dim3(B_ * C_, 4), blk, 0, stream>>>(S0, factor, gmC, giC, fu_g, fu_b,
      weffb, hd_w1, hd_b1, y_out, S2, psH, pqH);
  k_stat2<<<B_, 128, 0, stream>>>(psH, pqH, gmH, giH, 512, (float)(128 * HW_));
  // 11. logits
  k_logits<<<dim3(B_, 64), blk, 0, stream>>>(S2, gmH, giH, hd_g, hd_be, hd_w2, hd_b2,
                                             task_ids, logitsb);
  // 12. sim scaling + fsw
  k_final<<<(unsigned)((size_t)B_ * HW_ / 256), blk, 0, stream>>>(logitsb, sim, psimb,
                                                                  sim_temp, proto_amp,
                                                                  asw, fsw_out);
  // 13. resize logits 128->512 -> pred
  k_resize<<<(unsigned)((size_t)B_ * 512 * 512 / 256), blk, 0, stream>>>(logitsb, pred_out,
                                                                          B_, 128, 128, 512, 512);
}

// Round 20
// 462.218 us; speedup vs baseline: 1.2188x; 1.0846x over previous
//
#include <hip/hip_runtime.h>
#include <math.h>

constexpr int B_ = 4;
constexpr int C_ = 128;
constexpr int HW_ = 16384;
constexpr int W_ = 128;
constexpr int M_ = 6;
constexpr int TDIM_ = 64;
constexpr int NT_ = 1; // NUM_TASKS

static __device__ __forceinline__ float gelu_f(float x){
  return 0.5f * x * (1.0f + erff(x * 0.7071067811865476f));
}
static __device__ __forceinline__ int imin(int a, int b){ return a < b ? a : b; }

// ---------- block reduce (256 threads) ----------
static __device__ __forceinline__ float block_reduce_sum256(float v, float* lds){
  int t = threadIdx.x;
  lds[t] = v; __syncthreads();
  for (int s = 128; s > 0; s >>= 1){ if (t < s) lds[t] += lds[t + s]; __syncthreads(); }
  float r = lds[0]; __syncthreads();
  return r;
}

// ---------- align-corners bilinear resize ----------
__global__ void k_resize(const float* __restrict__ in, float* __restrict__ out,
                         int BC, int Hi, int Wi, int Ho, int Wo){
  int idx = blockIdx.x * 256 + threadIdx.x;
  int total = BC * Ho * Wo;
  if (idx >= total) return;
  int xo = idx % Wo; int yo = (idx / Wo) % Ho; int bc = idx / (Wo * Ho);
  float sy = (Ho > 1) ? yo * (float)(Hi - 1) / (float)(Ho - 1) : 0.f;
  float sx = (Wo > 1) ? xo * (float)(Wi - 1) / (float)(Wo - 1) : 0.f;
  int y0 = (int)floorf(sy); int y1 = imin(y0 + 1, Hi - 1); float wy = sy - (float)y0;
  int x0 = (int)floorf(sx); int x1 = imin(x0 + 1, Wi - 1); float wx = sx - (float)x0;
  const float* p = in + (size_t)bc * Hi * Wi;
  float a = p[y0 * Wi + x0], b = p[y1 * Wi + x0];
  float c = p[y0 * Wi + x1], d = p[y1 * Wi + x1];
  float t0 = a * (1.f - wy) + b * wy;
  float t1 = c * (1.f - wy) + d * wy;
  out[idx] = t0 * (1.f - wx) + t1 * wx;
}

// ---------- stats finalize ----------
__global__ void k_stat2(const float* __restrict__ ps, const float* __restrict__ pq,
                        float* __restrict__ gm, float* __restrict__ gi,
                        int nper, float nelem){
  int idx = blockIdx.x; int t = threadIdx.x;
  __shared__ float l1[128], l2[128];
  float s = 0.f, ss = 0.f;
  for (int i = t; i < nper; i += 128){ s += ps[idx * nper + i]; ss += pq[idx * nper + i]; }
  l1[t] = s; l2[t] = ss; __syncthreads();
  for (int st = 64; st > 0; st >>= 1){
    if (t < st){ l1[t] += l1[t + st]; l2[t] += l2[t + st]; }
    __syncthreads();
  }
  if (t == 0){
    float mu = l1[0] / nelem;
    float var = l2[0] / nelem - mu * mu;
    gm[idx] = mu; gi[idx] = rsqrtf(var + 1e-5f);
  }
}

// ---------- dual stats finalize ----------
__global__ void k_stat2_dual(const float* __restrict__ psA, const float* __restrict__ pqA,
                             float* __restrict__ gmA, float* __restrict__ giA, float nelemA,
                             const float* __restrict__ psB, const float* __restrict__ pqB,
                             float* __restrict__ gmB, float* __restrict__ giB, float nelemB){
  int idx = blockIdx.x; int t = threadIdx.x;
  __shared__ float l1[128], l2[128];
  const float* ps; const float* pq; float* gm; float* gi; float nelem; int id2;
  if (idx < 4){ ps = psA; pq = pqA; gm = gmA; gi = giA; nelem = nelemA; id2 = idx; }
  else        { ps = psB; pq = pqB; gm = gmB; gi = giB; nelem = nelemB; id2 = idx - 4; }
  float s = 0.f, ss = 0.f;
  for (int i = t; i < 256; i += 128){ s += ps[id2 * 256 + i]; ss += pq[id2 * 256 + i]; }
  l1[t] = s; l2[t] = ss; __syncthreads();
  for (int st = 64; st > 0; st >>= 1){
    if (t < st){ l1[t] += l1[t + st]; l2[t] += l2[t + st]; }
    __syncthreads();
  }
  if (t == 0){
    float mu = l1[0] / nelem;
    float var = l2[0] / nelem - mu * mu;
    gm[id2] = mu; gi[id2] = rsqrtf(var + 1e-5f);
  }
}

// ---------- merged weight transposes ----------
__global__ void k_wtall(const float* __restrict__ ph_w, const float* __restrict__ pl_w,
                        const float* __restrict__ fu_w, const float* __restrict__ se_w2,
                        float* __restrict__ wTph, float* __restrict__ wTpl,
                        float* __restrict__ wTfu, float* __restrict__ wTse){
  int idx = blockIdx.x * 256 + threadIdx.x;
  if (idx < 16384){
    int ci = idx / 128, co = idx % 128;
    wTph[idx] = ph_w[co * 128 + ci];
  } else if (idx < 20480){
    int r = idx - 16384; int ci = r / 64, co = r % 64;
    wTpl[r] = pl_w[co * 64 + ci];
  } else if (idx < 45056){
    int r = idx - 20480; int ci = r / 128, co = r % 128;
    wTfu[r] = fu_w[(size_t)co * 192 + ci];
  } else if (idx < 61440){
    int r = idx - 45056; int ci = r / 128, co = r % 128;
    wTse[r] = se_w2[co * 128 + ci];
  }
}

// ---------- shared GEMM body (raw input, K-chunk 16) --------
template<int CO, int CIT>
static __device__ __forceinline__ void gemm_body(
    const float* __restrict__ in1, const float* __restrict__ wT,
    float* __restrict__ out, float* __restrict__ psum, float* __restrict__ psq,
    int b, int j0, int slot, float* As, float* Bs, float* red){
  const int tid = threadIdx.x;
  const int tj = tid & 15, tco = tid >> 4;
  constexpr int CPT = CO / 16;
  constexpr int AST = CO + 4;
  float acc[CPT][4];
  #pragma unroll
  for (int i = 0; i < CPT; ++i)
    #pragma unroll
    for (int j = 0; j < 4; ++j) acc[i][j] = 0.f;

  for (int k0 = 0; k0 < CIT; k0 += 16){
    const int kk = tid >> 4;
    if constexpr (CO == 128){
      int co = (tid & 15) * 8;
      const float* wp = &wT[(size_t)(k0 + kk) * CO + co];
      *(float4*)&As[kk * AST + co] = *(const float4*)wp;
      *(float4*)&As[kk * AST + co + 4] = *(const float4*)(wp + 4);
    } else {
      int co = (tid & 15) * 4;
      *(float4*)&As[kk * AST + co] = *(const float4*)&wT[(size_t)(k0 + kk) * CO + co];
    }
    {
      int jj = (tid & 15) * 4;
      int ci = k0 + kk;
      float4 v = *(const float4*)&in1[((size_t)b * CIT + ci) * HW_ + j0 + jj];
      *(float4*)&Bs[kk * 68 + jj] = v;
    }
    __syncthreads();
    #pragma unroll
    for (int kkk = 0; kkk < 16; ++kkk){
      float4 bq = *(const float4*)&Bs[kkk * 68 + tj * 4];
      float av[CPT];
      if constexpr (CPT == 8){
        float4 a0 = *(const float4*)&As[kkk * AST + tco * 8];
        float4 a1 = *(const float4*)&As[kkk * AST + tco * 8 + 4];
        av[0] = a0.x; av[1] = a0.y; av[2] = a0.z; av[3] = a0.w;
        av[4] = a1.x; av[5] = a1.y; av[6] = a1.z; av[7] = a1.w;
      } else {
        float4 a0 = *(const float4*)&As[kkk * AST + tco * 4];
        av[0] = a0.x; av[1] = a0.y; av[2] = a0.z; av[3] = a0.w;
      }
      #pragma unroll
      for (int i = 0; i < CPT; ++i){
        acc[i][0] = fmaf(av[i], bq.x, acc[i][0]);
        acc[i][1] = fmaf(av[i], bq.y, acc[i][1]);
        acc[i][2] = fmaf(av[i], bq.z, acc[i][2]);
        acc[i][3] = fmaf(av[i], bq.w, acc[i][3]);
      }
    }
    __syncthreads();
  }
  float s = 0.f, ss = 0.f;
  #pragma unroll
  for (int i = 0; i < CPT; ++i){
    int co = tco * CPT + i;
    float4 o;
    o.x = acc[i][0]; o.y = acc[i][1]; o.z = acc[i][2]; o.w = acc[i][3];
    *(float4*)&out[((size_t)b * CO + co) * HW_ + j0 + tj * 4] = o;
    s += o.x + o.y + o.z + o.w;
    ss += o.x * o.x + o.y * o.y + o.z * o.z + o.w * o.w;
  }
  s = block_reduce_sum256(s, red);
  ss = block_reduce_sum256(ss, red);
  if (tid == 0){ psum[slot] = s; psq[slot] = ss; }
}

// ---------- dual GEMM: ph (128->128) || pl (64->64), 2048 blocks -------------
__global__ __launch_bounds__(256, 4) void k_gemm_dual(
    const float* __restrict__ in_ph, const float* __restrict__ wT_ph,
    float* __restrict__ out_ph, float* __restrict__ psA, float* __restrict__ pqA,
    const float* __restrict__ in_pl, const float* __restrict__ wT_pl,
    float* __restrict__ out_pl, float* __restrict__ psB, float* __restrict__ pqB){
  __shared__ float As[16 * 132];
  __shared__ float Bs[16 * 68];
  __shared__ float red[256];
  int b = blockIdx.x;
  if (blockIdx.y < 256){
    int yb = blockIdx.y;
    gemm_body<128, 128>(in_ph, wT_ph, out_ph, psA, pqA, b, yb * 64, b * 256 + yb, As, Bs, red);
  } else {
    int yb = blockIdx.y - 256;
    gemm_body<64, 64>(in_pl, wT_pl, out_pl, psB, pqB, b, yb * 64, b * 256 + yb, As, Bs, red);
  }
}

// ---------- tiled 1x1-conv GEMM (K-chunk 16) with GN+GELU on input -----------
template<int CO, int CIT>
__global__ __launch_bounds__(256, 4) void k_gemm1x1(
    const float* __restrict__ in1, const float* __restrict__ in2, int CI1,
    const float* __restrict__ wT, const float* __restrict__ bias,
    const float* __restrict__ gm1, const float* __restrict__ gi1,
    const float* __restrict__ ga1, const float* __restrict__ be1, int sh1, int ng1,
    const float* __restrict__ gm2, const float* __restrict__ gi2,
    const float* __restrict__ ga2, const float* __restrict__ be2, int sh2, int ng2,
    float* __restrict__ out, float* __restrict__ psum, float* __restrict__ psq){
  __shared__ float As[16][CO + 4];
  __shared__ float Bs[16][68];
  __shared__ float red[256];
  const int b = blockIdx.x;
  const int j0 = blockIdx.y * 64;
  const int tid = threadIdx.x;
  const int tj = tid & 15, tco = tid >> 4;
  constexpr int CPT = CO / 16;

  float acc[CPT][4];
  #pragma unroll
  for (int i = 0; i < CPT; ++i)
    #pragma unroll
    for (int j = 0; j < 4; ++j) acc[i][j] = 0.f;

  for (int k0 = 0; k0 < CIT; k0 += 16){
    const int kk = tid >> 4;
    if constexpr (CO == 128){
      int co = (tid & 15) * 8;
      const float* wp = &wT[(size_t)(k0 + kk) * CO + co];
      *(float4*)&As[kk][co] = *(const float4*)wp;
      *(float4*)&As[kk][co + 4] = *(const float4*)(wp + 4);
    } else {
      int co = (tid & 15) * 4;
      *(float4*)&As[kk][co] = *(const float4*)&wT[(size_t)(k0 + kk) * CO + co];
    }
    {
      int jj = (tid & 15) * 4;
      int ci = k0 + kk;
      float4 v;
      if (ci < CI1){
        v = *(const float4*)&in1[((size_t)b * CI1 + ci) * HW_ + j0 + jj];
        if (gm1){
          int g = ci >> sh1;
          float rs = gi1[b * ng1 + g];
          float ga = ga1[ci] * rs;
          float be = be1[ci] - gm1[b * ng1 + g] * ga;
          v.x = gelu_f(fmaf(v.x, ga, be)); v.y = gelu_f(fmaf(v.y, ga, be));
          v.z = gelu_f(fmaf(v.z, ga, be)); v.w = gelu_f(fmaf(v.w, ga, be));
        }
      } else {
        int c2 = ci - CI1;
        v = *(const float4*)&in2[((size_t)b * (CIT - CI1) + c2) * HW_ + j0 + jj];
        if (gm2){
          int g = c2 >> sh2;
          float rs = gi2[b * ng2 + g];
          float ga = ga2[c2] * rs;
          float be = be2[c2] - gm2[b * ng2 + g] * ga;
          v.x = gelu_f(fmaf(v.x, ga, be)); v.y = gelu_f(fmaf(v.y, ga, be));
          v.z = gelu_f(fmaf(v.z, ga, be)); v.w = gelu_f(fmaf(v.w, ga, be));
        }
      }
      *(float4*)&Bs[kk][jj] = v;
    }
    __syncthreads();
    #pragma unroll
    for (int kkk = 0; kkk < 16; ++kkk){
      float4 bq = *(const float4*)&Bs[kkk][tj * 4];
      float av[CPT];
      if constexpr (CPT == 8){
        float4 a0 = *(const float4*)&As[kkk][tco * 8];
        float4 a1 = *(const float4*)&As[kkk][tco * 8 + 4];
        av[0] = a0.x; av[1] = a0.y; av[2] = a0.z; av[3] = a0.w;
        av[4] = a1.x; av[5] = a1.y; av[6] = a1.z; av[7] = a1.w;
      } else {
        float4 a0 = *(const float4*)&As[kkk][tco * 4];
        av[0] = a0.x; av[1] = a0.y; av[2] = a0.z; av[3] = a0.w;
      }
      #pragma unroll
      for (int i = 0; i < CPT; ++i){
        acc[i][0] = fmaf(av[i], bq.x, acc[i][0]);
        acc[i][1] = fmaf(av[i], bq.y, acc[i][1]);
        acc[i][2] = fmaf(av[i], bq.z, acc[i][2]);
        acc[i][3] = fmaf(av[i], bq.w, acc[i][3]);
      }
    }
    __syncthreads();
  }
  float s = 0.f, ss = 0.f;
  #pragma unroll
  for (int i = 0; i < CPT; ++i){
    int co = tco * CPT + i;
    float bb = bias ? bias[co] : 0.f;
    float4 o;
    o.x = acc[i][0] + bb; o.y = acc[i][1] + bb;
    o.z = acc[i][2] + bb; o.w = acc[i][3] + bb;
    *(float4*)&out[((size_t)b * CO + co) * HW_ + j0 + tj * 4] = o;
    s += o.x + o.y + o.z + o.w;
    ss += o.x * o.x + o.y * o.y + o.z * o.z + o.w * o.w;
  }
  if (psum){
    s = block_reduce_sum256(s, red);
    ss = block_reduce_sum256(ss, red);
    if (tid == 0){
      psum[b * gridDim.y + blockIdx.y] = s;
      psq [b * gridDim.y + blockIdx.y] = ss;
    }
  }
}

// ---------- grouped 3x3 conv, column-scalar mapping (R18, measured best) -----
__global__ __launch_bounds__(256) void k_se3(const float* __restrict__ x,
    const float* __restrict__ gm, const float* __restrict__ gi,
    const float* __restrict__ gamma, const float* __restrict__ beta,
    const float* __restrict__ w, const float* __restrict__ bias,
    float* __restrict__ out, float* __restrict__ psum, float* __restrict__ psq){
  __shared__ float xs[4][10][128];
  __shared__ float ws[144];
  __shared__ float wb[4];
  __shared__ float red[256];
  const int bgc = blockIdx.x; const int b = bgc >> 5, gc = bgc & 31;
  const int r0 = blockIdx.y * 8;
  const int tid = threadIdx.x;
  const float mu = gm[b], rs = gi[b];
  for (int ch = 0; ch < 4; ++ch){
    int c = gc * 4 + ch;
    float ga = gamma[c] * rs, be = beta[c] - mu * rs * gamma[c];
    const float* px = x + ((size_t)b * C_ + c) * HW_;
    for (int i = tid; i < 10 * 128; i += 256){
      int rr = i >> 7, cc = i & 127;
      int row = r0 - 1 + rr;
      float v = 0.f;
      if ((unsigned)row < 128u) v = gelu_f(fmaf(px[row * W_ + cc], ga, be));
      xs[ch][rr][cc] = v;
    }
  }
  if (tid < 144) ws[tid] = w[(size_t)(gc * 4) * 36 + tid];
  if (tid < 4)   wb[tid] = bias[gc * 4 + tid];
  __syncthreads();
  const int hf = tid >> 7;
  const int cc = tid & 127;
  float s = 0.f, ss = 0.f;
  for (int co_l = 0; co_l < 4; ++co_l){
    float bb = wb[co_l];
    float a0 = bb, a1 = bb, a2 = bb, a3 = bb;
    #pragma unroll
    for (int cil = 0; cil < 4; ++cil){
      float w9[9];
      #pragma unroll
      for (int i = 0; i < 9; ++i) w9[i] = ws[(co_l * 4 + cil) * 9 + i];
      #pragma unroll
      for (int q = 0; q < 6; ++q){
        int xr = 4 * hf + q;
        float mdl = xs[cil][xr][cc];
        float lft = (cc > 0)   ? xs[cil][xr][cc - 1] : 0.f;
        float rgt = (cc < 127) ? xs[cil][xr][cc + 1] : 0.f;
        if (q <= 2){
          int ky = q;       a0 = fmaf(w9[ky*3], lft, a0); a0 = fmaf(w9[ky*3+1], mdl, a0); a0 = fmaf(w9[ky*3+2], rgt, a0);
        }
        if (q >= 1 && q <= 3){
          int ky = q - 1;   a1 = fmaf(w9[ky*3], lft, a1); a1 = fmaf(w9[ky*3+1], mdl, a1); a1 = fmaf(w9[ky*3+2], rgt, a1);
        }
        if (q >= 2 && q <= 4){
          int ky = q - 2;   a2 = fmaf(w9[ky*3], lft, a2); a2 = fmaf(w9[ky*3+1], mdl, a2); a2 = fmaf(w9[ky*3+2], rgt, a2);
        }
        if (q >= 3){
          int ky = q - 3;   a3 = fmaf(w9[ky*3], lft, a3); a3 = fmaf(w9[ky*3+1], mdl, a3); a3 = fmaf(w9[ky*3+2], rgt, a3);
        }
      }
    }
    float* po = &out[((size_t)b * C_ + gc * 4 + co_l) * HW_ + (r0 + 4 * hf) * W_ + cc];
    po[0]       = a0;
    po[W_]      = a1;
    po[2 * W_]  = a2;
    po[3 * W_]  = a3;
    s += a0 + a1 + a2 + a3;
    ss += a0 * a0 + a1 * a1 + a2 * a2 + a3 * a3;
  }
  s = block_reduce_sum256(s, red);
  ss = block_reduce_sum256(ss, red);
  if (tid == 0){
    int idx = (b * 4 + (gc >> 3)) * 128 + (gc & 7) * 16 + blockIdx.y;
    psum[idx] = s; psq[idx] = ss;
  }
}

// ---------- fused: x_enh -> y (3x3 dyn) -> h (3x3 dw) + GN stats for h -------
__global__ __launch_bounds__(256) void k_ydw(const float* __restrict__ x,
    const float* __restrict__ factor,
    const float* __restrict__ gm, const float* __restrict__ gi,
    const float* __restrict__ gamma, const float* __restrict__ beta,
    const float* __restrict__ w_eff, const float* __restrict__ dw_w,
    const float* __restrict__ dw_b, float* __restrict__ y_out,
    float* __restrict__ h_out, float* __restrict__ psum, float* __restrict__ psq){
  __shared__ float xs[36][128];
  __shared__ float ys[34][128];
  __shared__ float red[256];
  const int bc = blockIdx.x; const int b = bc >> 7, c = bc & 127;
  const int r0 = blockIdx.y * 32;
  const int tid = threadIdx.x;
  const float mu = gm[b], rs = gi[b];
  const float ga = gamma[c] * rs, be = beta[c] - mu * rs * gamma[c];
  const float* px = x + ((size_t)b * C_ + c) * HW_;
  const float* pf = factor + (size_t)b * HW_;
  for (int i = tid; i < 36 * 128; i += 256){
    int rr = i >> 7, cc = i & 127;
    int row = r0 - 2 + rr;
    float v = 0.f;
    if ((unsigned)row < 128u)
      v = gelu_f(fmaf(px[row * W_ + cc], ga, be)) * pf[row * W_ + cc];
    xs[rr][cc] = v;
  }
  __syncthreads();
  float w9[9];
  #pragma unroll
  for (int r = 0; r < 9; ++r) w9[r] = w_eff[b * 1152 + c * 9 + r];
  for (int i = tid; i < 34 * 128; i += 256){
    int rr = i >> 7, cc = i & 127;
    int row = r0 - 1 + rr;
    float acc = 0.f;
    if ((unsigned)row < 128u){
      #pragma unroll
      for (int ky = 0; ky < 3; ++ky){
        #pragma unroll
        for (int kx = 0; kx < 3; ++kx){
          int xc = cc + kx - 1;
          if ((unsigned)xc < 128u) acc += w9[ky * 3 + kx] * xs[rr + ky][xc];
        }
      }
    }
    ys[rr][cc] = acc;
    if (rr >= 1 && rr <= 32)
      y_out[((size_t)b * C_ + c) * HW_ + row * W_ + cc] = acc;
  }
  __syncthreads();
  float wd[9];
  #pragma unroll
  for (int r = 0; r < 9; ++r) wd[r] = dw_w[c * 9 + r];
  const float bb = dw_b[c];
  float s = 0.f, ss = 0.f;
  for (int i = tid; i < 32 * 128; i += 256){
    int rr = i >> 7, cc = i & 127;
    int row = r0 + rr;
    float acc = bb;
    #pragma unroll
    for (int ky = 0; ky < 3; ++ky){
      #pragma unroll
      for (int kx = 0; kx < 3; ++kx){
        int yc = cc + kx - 1;
        if ((unsigned)yc < 128u) acc += wd[ky * 3 + kx] * ys[rr + ky][yc];
      }
    }
    h_out[((size_t)b * C_ + c) * HW_ + row * W_ + cc] = acc;
    s += acc; ss += acc * acc;
  }
  s = block_reduce_sum256(s, red);
  ss = block_reduce_sum256(ss, red);
  if (tid == 0){
    int idx = b * 512 + c * 4 + blockIdx.y;
    psum[idx] = s; psq[idx] = ss;
  }
}

// ---------- prototype init MLP (per b) ----------
__global__ void k_pinit(const float* __restrict__ temb, const float* __restrict__ w1,
                        const float* __restrict__ b1, const float* __restrict__ w2,
                        const float* __restrict__ b2, float* __restrict__ pinit){
  int b = blockIdx.x; int t = threadIdx.x;
  __shared__ float h1[256], p2[256], nrm[2];
  float acc = b1[t];
  for (int i = 0; i < TDIM_; ++i) acc += temb[b * TDIM_ + i] * w1[t * TDIM_ + i];
  h1[t] = gelu_f(acc); __syncthreads();
  acc = b2[t];
  for (int i = 0; i < 256; ++i) acc += h1[i] * w2[t * 256 + i];
  p2[t] = acc; __syncthreads();
  if (t < 2){
    float s = 0.f;
    for (int c = 0; c < 128; ++c){ float v = p2[t * 128 + c]; s += v * v; }
    nrm[t] = fmaxf(sqrtf(s), 1e-12f);
  }
  __syncthreads();
  pinit[b * 256 + t] = p2[t] / nrm[t / 128];
}

// ---------- table / protos / fg,bg ----------
__global__ void k_protos(const float* __restrict__ pinit, const int* __restrict__ task_ids,
                         float* __restrict__ fg, float* __restrict__ bg){
  __shared__ int tbl[NT_];
  __shared__ int src[B_];
  __shared__ float nr[B_ * 2];
  int t = threadIdx.x;
  if (t < NT_){
    int idx = 0;
    for (int b = B_ - 1; b >= 0; --b) if (task_ids[b] == t) idx = b;
    tbl[t] = idx;
  }
  __syncthreads();
  if (t < B_){
    int ti = task_ids[t]; ti = ti < 0 ? 0 : (ti >= NT_ ? NT_ - 1 : ti);
    src[t] = tbl[ti];
  }
  __syncthreads();
  if (t < 2 * B_){
    int b = t / 2, r = t % 2;
    float s = 0.f;
    for (int c = 0; c < 128; ++c){ float v = pinit[src[b] * 256 + r * 128 + c]; s += v * v; }
    nr[t] = fmaxf(sqrtf(s), 1e-12f);
  }
  __syncthreads();
  for (int i = t; i < B_ * 128; i += 256){
    int b = i / 128, c = i % 128;
    fg[i] = pinit[src[b] * 256 + c] / nr[b * 2 + 0];
    bg[i] = pinit[src[b] * 256 + 128 + c] / nr[b * 2 + 1];
  }
}

// ---------- q projection folded into key space ----------
__global__ void k_qk(const float* __restrict__ fg, const float* __restrict__ bg,
                     const float* __restrict__ at_in_w, const float* __restrict__ at_in_b,
                     float* __restrict__ qkvec, float* __restrict__ kdot){
  int b = blockIdx.x, t = threadIdx.x;
  __shared__ float pq[256], qf[256];
  pq[t] = (t < 128) ? fg[b * 128 + t] : bg[b * 128 + (t - 128)];
  __syncthreads();
  {
    int qi = t / 128, o = t % 128;
    float acc = at_in_b[o];
    const float* wr = at_in_w + (size_t)o * 128;
    for (int c = 0; c < 128; ++c) acc += wr[c] * pq[qi * 128 + c];
    qf[qi * 128 + o] = acc;
  }
  __syncthreads();
  for (int e = t; e < 1024; e += 256){
    int p = e / 128, c = e % 128, qi = p / 4, h = p % 4;
    float acc = 0.f;
    for (int d = 0; d < 32; ++d)
      acc += qf[qi * 128 + h * 32 + d] * at_in_w[(size_t)(128 + h * 32 + d) * 128 + c];
    qkvec[b * 1024 + e] = acc;
  }
  if (t < 8){
    int qi = t / 4, h = t % 4;
    float acc = 0.f;
    for (int d = 0; d < 32; ++d) acc += qf[qi * 128 + h * 32 + d] * at_in_b[128 + h * 32 + d];
    kdot[b * 8 + t] = acc;
  }
}

// ---------- fused sim/factor/scores, c-split 4-way (occupancy fix) -----------
// R19: old grid (B,64)=256 blocks = 1 block/CU, 128-deep channel loop ->
// latency-bound. New: grid (B,256), 64 j/block; thread=(cgroup g, j); each
// thread sums 32 channels; LDS 4-way reduce. 4x blocks AND 4x shorter loops.
__global__ __launch_bounds__(256) void k_simscores(const float* __restrict__ sf,
                          const float* __restrict__ fg, const float* __restrict__ bg,
                          const float* __restrict__ qkvec, const float* __restrict__ kdot,
                          float* __restrict__ sim, float* __restrict__ factor,
                          float* __restrict__ scores, float* __restrict__ psim){
  int b = blockIdx.x; int j0 = blockIdx.y * 64;
  int t = threadIdx.x;
  int g = t >> 6, jl = t & 63;
  int j = j0 + jl;
  __shared__ float L[10 * 128];
  __shared__ float part[11 * 256];
  __shared__ float red64[64];
  for (int i = t; i < 1280; i += 256){
    int r = i >> 7, c = i & 127;
    L[i] = (r == 0) ? fg[b * 128 + c]
         : (r == 1) ? bg[b * 128 + c]
                    : qkvec[b * 1024 + (r - 2) * 128 + c];
  }
  __syncthreads();
  const float* p = sf + (size_t)b * C_ * HW_ + j;
  float a0=0,a1=0,q0=0,q1=0,q2=0,q3=0,q4=0,q5=0,q6=0,q7=0,nn=0;
  int c0 = g * 32;
  #pragma unroll 8
  for (int c = c0; c < c0 + 32; ++c){
    float v = p[(size_t)c * HW_];
    nn += v * v;
    a0 += L[c] * v;          a1 += L[128 + c] * v;
    q0 += L[256 + c] * v;    q1 += L[384 + c] * v;
    q2 += L[512 + c] * v;    q3 += L[640 + c] * v;
    q4 += L[768 + c] * v;    q5 += L[896 + c] * v;
    q6 += L[1024 + c] * v;   q7 += L[1152 + c] * v;
  }
  part[0 * 256 + t] = nn;  part[1 * 256 + t] = a0;  part[2 * 256 + t] = a1;
  part[3 * 256 + t] = q0;  part[4 * 256 + t] = q1;  part[5 * 256 + t] = q2;
  part[6 * 256 + t] = q3;  part[7 * 256 + t] = q4;  part[8 * 256 + t] = q5;
  part[9 * 256 + t] = q6;  part[10 * 256 + t] = q7;
  __syncthreads();
  float sv = 0.f;
  if (t < 64){
    float tot[11];
    #pragma unroll
    for (int i = 0; i < 11; ++i)
      tot[i] = part[i * 256 + t] + part[i * 256 + t + 64]
             + part[i * 256 + t + 128] + part[i * 256 + t + 192];
    float inv = 1.f / fmaxf(sqrtf(tot[0]), 1e-12f);
    sv = (tot[1] - tot[2]) * inv;
    sim[b * HW_ + j0 + t] = sv;
    factor[b * HW_ + j0 + t] = 1.f + 0.5f / (1.f + expf(-sv));
    const float scale = 0.17677669529663689f;
    #pragma unroll
    for (int pp = 0; pp < 8; ++pp)
      scores[((size_t)(b * 8 + pp)) * HW_ + j0 + t] = (tot[3 + pp] + kdot[b * 8 + pp]) * scale;
  }
  __syncthreads();
  if (t < 64) red64[t] = fabsf(sv);
  __syncthreads();
  for (int s2 = 32; s2 > 0; s2 >>= 1){
    if (t < s2) red64[t] += red64[t + s2];
    __syncthreads();
  }
  if (t == 0) psim[b * 256 + blockIdx.y] = red64[0];
}

__global__ void k_smstats(const float* __restrict__ scores, float* __restrict__ smax,
                          float* __restrict__ ssum){
  __shared__ float lds[256];
  int row = blockIdx.x;
  const float* p = scores + (size_t)row * HW_;
  float m = -1e30f;
  for (int j = threadIdx.x; j < HW_; j += 256) m = fmaxf(m, p[j]);
  lds[threadIdx.x] = m; __syncthreads();
  for (int s = 128; s > 0; s >>= 1){
    if (threadIdx.x < s) lds[threadIdx.x] = fmaxf(lds[threadIdx.x], lds[threadIdx.x + s]);
    __syncthreads();
  }
  m = lds[0]; __syncthreads();
  float z = 0.f;
  for (int j = threadIdx.x; j < HW_; j += 256) z += expf(p[j] - m);
  z = block_reduce_sum256(z, lds);
  if (threadIdx.x == 0){ smax[row] = m; ssum[row] = z; }
}

// ---------- wsum, 4-way j-split ----------------------------------------------
__global__ void k_wsum(const float* __restrict__ sf, const float* __restrict__ scores,
                       const float* __restrict__ smax, const float* __restrict__ ssum,
                       float* __restrict__ wsum4){
  int bc = blockIdx.x; int b = bc / C_, c = bc % C_;
  int chunk = blockIdx.y;
  __shared__ float lds[8 * 256];
  __shared__ float mr[8], zr[8];
  if (threadIdx.x < 8){
    mr[threadIdx.x] = smax[b * 8 + threadIdx.x];
    zr[threadIdx.x] = 1.f / ssum[b * 8 + threadIdx.x];
  }
  __syncthreads();
  const float* p = sf + (size_t)bc * HW_;
  const float* sc = scores + (size_t)b * 8 * HW_;
  int j0 = chunk * (HW_ / 4), j1 = j0 + HW_ / 4;
  float acc[8] = {0,0,0,0,0,0,0,0};
  for (int j = j0 + threadIdx.x; j < j1; j += 256){
    float v = p[j];
    #pragma unroll
    for (int pp = 0; pp < 8; ++pp)
      acc[pp] = fmaf(expf(sc[(size_t)pp * HW_ + j] - mr[pp]) * zr[pp], v, acc[pp]);
  }
  #pragma unroll
  for (int pp = 0; pp < 8; ++pp) lds[pp * 256 + threadIdx.x] = acc[pp];
  __syncthreads();
  for (int s = 128; s > 0; s >>= 1){
    if (threadIdx.x < s){
      #pragma unroll
      for (int pp = 0; pp < 8; ++pp) lds[pp * 256 + threadIdx.x] += lds[pp * 256 + threadIdx.x + s];
    }
    __syncthreads();
  }
  if (threadIdx.x < 8)
    wsum4[chunk * 4096 + b * 1024 + threadIdx.x * 128 + c] = lds[threadIdx.x * 256];
}

// ---------- small head chain (sums the 4 wsum partials on load) --------------
__global__ void k_small(const float* __restrict__ wsum4, const float* __restrict__ at_in_w,
                        const float* __restrict__ at_in_b, const float* __restrict__ at_out_w,
                        const float* __restrict__ at_out_b, const float* __restrict__ pf_w,
                        const float* __restrict__ pf_b, const float* __restrict__ eg_w1,
                        const float* __restrict__ eg_b1, const float* __restrict__ ewg_w,
                        const float* __restrict__ ewg_b, float* __restrict__ eg1_out,
                        float* __restrict__ ew_out){
  int b = blockIdx.x; int t = threadIdx.x;
  __shared__ float wsl[1024], att[256], ao[256], pf[128], ewl[8];
  for (int i = t; i < 1024; i += 256)
    wsl[i] = wsum4[b * 1024 + i] + wsum4[4096 + b * 1024 + i]
           + wsum4[8192 + b * 1024 + i] + wsum4[12288 + b * 1024 + i];
  __syncthreads();
  {
    int qi = t / 128, o = t % 128, h = o / 32, d = o % 32, p = qi * 4 + h;
    float acc = at_in_b[256 + h * 32 + d];
    const float* wr = at_in_w + (size_t)(256 + h * 32 + d) * 128;
    for (int c = 0; c < 128; ++c) acc += wr[c] * wsl[p * 128 + c];
    att[qi * 128 + o] = acc;
  }
  __syncthreads();
  {
    int qi = t / 128, o = t % 128;
    float acc = at_out_b[o];
    const float* wr = at_out_w + (size_t)o * 128;
    for (int c = 0; c < 128; ++c) acc += wr[c] * att[qi * 128 + c];
    ao[qi * 128 + o] = acc;
  }
  __syncthreads();
  if (t < 128){
    float acc = pf_b[t];
    const float* wr = pf_w + (size_t)t * 384;
    for (int c = 0; c < 128; ++c){
      float fa = ao[c], ba = ao[128 + c];
      acc += wr[c] * fa + wr[128 + c] * ba + wr[256 + c] * (fa - ba);
    }
    pf[t] = acc;
  }
  __syncthreads();
  {
    float acc = eg_b1[t];
    const float* wr = eg_w1 + (size_t)t * 128;
    for (int c = 0; c < 128; ++c) acc += wr[c] * pf[c];
    eg1_out[b * 256 + t] = gelu_f(acc);
  }
  if (t < M_){
    float acc = ewg_b[t];
    const float* wr = ewg_w + (size_t)t * 128;
    for (int c = 0; c < 128; ++c) acc += wr[c] * pf[c];
    ewl[t] = acc;
  }
  __syncthreads();
  if (t == 0){
    float m = -1e30f;
    for (int i = 0; i < M_; ++i) m = fmaxf(m, ewl[i]);
    float z = 0.f;
    for (int i = 0; i < M_; ++i){ ewl[i] = expf(ewl[i] - m); z += ewl[i]; }
    for (int i = 0; i < M_; ++i) ew_out[b * M_ + i] = ewl[i] / z;
  }
}

// ---------- w_eff[b,c,r] ----------
__global__ void k_weff(const float* __restrict__ eg1, const float* __restrict__ ew,
                       const float* __restrict__ eg_w2, const float* __restrict__ eg_b2,
                       const float* __restrict__ eis_p, float* __restrict__ w_eff){
  int b = blockIdx.x; int cr = blockIdx.y * 256 + threadIdx.x;
  __shared__ float e1[256]; __shared__ float ewl[M_];
  e1[threadIdx.x] = eg1[b * 256 + threadIdx.x];
  if (threadIdx.x < M_) ewl[threadIdx.x] = ew[b * M_ + threadIdx.x];
  __syncthreads();
  if (cr >= C_ * 9) return;
  int c = cr / 9, r = cr % 9;
  float eis = eis_p[0];
  float acc = 0.f;
  for (int m = 0; m < M_; ++m){
    size_t row = ((size_t)m * C_ + c) * 9 + r;
    float v = eg_b2[row];
    const float* wr = eg_w2 + row * 256;
    for (int i = 0; i < 256; ++i) v += wr[i] * e1[i];
    float ekv = v * eis + ((r == 4) ? (1.f - eis) : 0.f);
    acc += ewl[m] * ekv;
  }
  w_eff[b * (C_ * 9) + cr] = acc;
}

// ---------- logits, c-split 4-way (occupancy fix, same scheme as simscores) --
__global__ __launch_bounds__(256) void k_logits(const float* __restrict__ h,
                         const float* __restrict__ gmean,
                         const float* __restrict__ ginv, const float* __restrict__ hd_g,
                         const float* __restrict__ hd_be, const float* __restrict__ hd_w2,
                         const float* __restrict__ hd_b2, const int* __restrict__ task_ids,
                         float* __restrict__ logits){
  int b = blockIdx.x; int j0 = blockIdx.y * 64;
  int t = threadIdx.x;
  int g = t >> 6, jl = t & 63;
  int it = task_ids[b]; it = it < 0 ? 0 : (it >= NT_ ? NT_ - 1 : it);
  __shared__ float wg[128], wb[128], w2[128];
  __shared__ float part[256];
  if (t < 128){
    wg[t] = hd_g[t];
    wb[t] = hd_be[t];
    w2[t] = hd_w2[it * C_ + t];
  }
  __syncthreads();
  float mu = gmean[b], rs = ginv[b];
  const float* p = h + (size_t)b * C_ * HW_ + j0 + jl;
  float acc = 0.f;
  int c0 = g * 32;
  #pragma unroll 8
  for (int c = c0; c < c0 + 32; ++c){
    float v = p[(size_t)c * HW_];
    v = (v - mu) * rs * wg[c] + wb[c];
    acc += w2[c] * gelu_f(v);
  }
  part[t] = acc;
  __syncthreads();
  if (t < 64){
    float tot = part[t] + part[t + 64] + part[t + 128] + part[t + 192] + hd_b2[it];
    logits[b * HW_ + j0 + t] = tot;
  }
}

// ---------- final: |sim| partial reduce inline (1024 partials) + fsw ---------
__global__ void k_final(float* __restrict__ logits, const float* __restrict__ sim,
                        const float* __restrict__ psim, const float* __restrict__ sim_temp,
                        const float* __restrict__ proto_amp,
                        const float* __restrict__ asw, float* __restrict__ fsw_out){
  __shared__ float red[256];
  float s = psim[threadIdx.x] + psim[256 + threadIdx.x]
          + psim[512 + threadIdx.x] + psim[768 + threadIdx.x];
  s = block_reduce_sum256(s, red);
  int idx = blockIdx.x * 256 + threadIdx.x;
  float mean = s / (float)(B_ * HW_);
  float denom = mean + 1e-6f;
  float temp = fmaxf(sim_temp[0], 0.001f);
  float v = tanhf(sim[idx] / denom / temp);
  logits[idx] += 5.0f * proto_amp[0] * v;
  if (blockIdx.x == 0 && threadIdx.x < B_){
    float a = 1.0f * asw[0];
    fsw_out[threadIdx.x] = a / a;
  }
}

extern "C" void kernel_launch(void* const* d_in, const int* in_sizes, int n_in,
                              void* d_out, int out_size, void* d_ws, size_t ws_size,
                              hipStream_t stream){
  const float* x_low   = (const float*)d_in[0];
  const float* x_high  = (const float*)d_in[1];
  const float* temb    = (const float*)d_in[2];
  const float* pl_w    = (const float*)d_in[3];
  const float* pl_g    = (const float*)d_in[4];
  const float* pl_b    = (const float*)d_in[5];
  const float* ph_w    = (const float*)d_in[6];
  const float* ph_g    = (const float*)d_in[7];
  const float* ph_b    = (const float*)d_in[8];
  const float* fu_w    = (const float*)d_in[9];
  const float* fu_g    = (const float*)d_in[10];
  const float* fu_b    = (const float*)d_in[11];
  const float* pi_w1   = (const float*)d_in[12];
  const float* pi_b1   = (const float*)d_in[13];
  const float* pi_w2   = (const float*)d_in[14];
  const float* pi_b2   = (const float*)d_in[15];
  const float* se_w1   = (const float*)d_in[16];
  const float* se_b1   = (const float*)d_in[17];
  const float* se_g    = (const float*)d_in[18];
  const float* se_be   = (const float*)d_in[19];
  const float* se_w2   = (const float*)d_in[20];
  const float* se_b2   = (const float*)d_in[21];
  const float* at_in_w = (const float*)d_in[22];
  const float* at_in_b = (const float*)d_in[23];
  const float* at_out_w= (const float*)d_in[24];
  const float* at_out_b= (const float*)d_in[25];
  const float* pf_w    = (const float*)d_in[26];
  const float* pf_b    = (const float*)d_in[27];
  const float* asw     = (const float*)d_in[32];
  const float* eg_w1   = (const float*)d_in[33];
  const float* eg_b1   = (const float*)d_in[34];
  const float* eg_w2   = (const float*)d_in[35];
  const float* eg_b2   = (const float*)d_in[36];
  const float* ewg_w   = (const float*)d_in[37];
  const float* ewg_b   = (const float*)d_in[38];
  const float* hd_w1   = (const float*)d_in[39];
  const float* hd_b1   = (const float*)d_in[40];
  const float* hd_g    = (const float*)d_in[41];
  const float* hd_be   = (const float*)d_in[42];
  const float* hd_w2   = (const float*)d_in[43];
  const float* hd_b2   = (const float*)d_in[44];
  const float* eis     = (const float*)d_in[45];
  const float* sim_temp= (const float*)d_in[46];
  const float* proto_amp=(const float*)d_in[47];
  const int*   task_ids= (const int*)d_in[48];

  float* ws = (float*)d_ws;
  const size_t BIG = (size_t)B_ * C_ * HW_; // 8,388,608
  float* S0 = ws;
  float* S1 = ws + BIG;
  float* S2 = ws + 2 * BIG;
  float* scores = ws + 3 * BIG;              // B*8*HW = 524288
  float* sm = scores + (size_t)B_ * 8 * HW_;
  float* sim     = sm;             sm += (size_t)B_ * HW_;
  float* factor  = sm;             sm += (size_t)B_ * HW_;
  float* logitsb = sm;             sm += (size_t)B_ * HW_;
  float* psA = sm; sm += 1024; float* pqA = sm; sm += 1024;
  float* psB = sm; sm += 1024; float* pqB = sm; sm += 1024;
  float* psC = sm; sm += 1024; float* pqC = sm; sm += 1024;
  float* ps3 = sm; sm += 2048; float* pq3 = sm; sm += 2048;
  float* psH = sm; sm += 2048; float* pqH = sm; sm += 2048;
  float* gmA = sm; sm += 4;  float* giA = sm; sm += 4;
  float* gmB = sm; sm += 4;  float* giB = sm; sm += 4;
  float* gmC = sm; sm += 4;  float* giC = sm; sm += 4;
  float* gm3 = sm; sm += 16; float* gi3 = sm; sm += 16;
  float* gmH = sm; sm += 4;  float* giH = sm; sm += 4;
  float* pinitb  = sm;             sm += 1024;
  float* fgb     = sm;             sm += 512;
  float* bgb     = sm;             sm += 512;
  float* qkvecb  = sm;             sm += 4096;
  float* kdotb   = sm;             sm += 32;
  float* smaxb   = sm;             sm += 32;
  float* ssumb   = sm;             sm += 32;
  float* wsum4b  = sm;             sm += 16384;
  float* eg1b    = sm;             sm += 1024;
  float* ewb     = sm;             sm += 32;
  float* weffb   = sm;             sm += 4608;
  float* psimb   = sm;             sm += 1024;
  float* wTph    = sm;             sm += 128 * 128;
  float* wTpl    = sm;             sm += 64 * 64;
  float* wTfu    = sm;             sm += 192 * 128;
  float* wTse    = sm;             sm += 128 * 128;

  float* pred_out = (float*)d_out;                       // 4*512*512
  float* y_out    = pred_out + (size_t)B_ * 512 * 512;   // 4*128*128*128
  float* fsw_out  = y_out + BIG;                         // 4

  dim3 blk(256);
  const float* NF = nullptr;
  float* NFm = nullptr;

  // 0. merged weight transposes
  k_wtall<<<240, blk, 0, stream>>>(ph_w, pl_w, fu_w, se_w2, wTph, wTpl, wTfu, wTse);
  // 1. resize x_high -> S0
  k_resize<<<(unsigned)(BIG / 256), blk, 0, stream>>>(x_high, S0, B_ * C_, 64, 64, 128, 128);
  // 2. DUAL gemm: ph (S0 -> S1) || pl (x_low -> S2 low)
  k_gemm_dual<<<dim3(B_, 512), blk, 0, stream>>>(S0, wTph, S1, psA, pqA,
                                                 x_low, wTpl, S2, psB, pqB);
  k_stat2_dual<<<8, 128, 0, stream>>>(psA, pqA, gmA, giA, (float)(128 * HW_),
                                      psB, pqB, gmB, giB, (float)(64 * HW_));
  // 3. fu conv: concat(gelu(gn(S1)), gelu(gn(S2 low))) -> S0
  k_gemm1x1<128,192><<<dim3(B_, 256), blk, 0, stream>>>(S1, S2, 128, wTfu, NF,
      gmA,giA,ph_g,ph_b,7,1, gmB,giB,pl_g,pl_b,6,1, S0, psC, pqC);
  k_stat2<<<B_, 128, 0, stream>>>(psC, pqC, gmC, giC, 256, (float)(128 * HW_));
  // 4. se grouped conv3x3 (column-scalar) on x=gelu(gn(S0)) -> S2, GN(4) stats
  k_se3<<<dim3(B_ * 32, 16), blk, 0, stream>>>(S0, gmC, giC, fu_g, fu_b,
      se_w1, se_b1, S2, ps3, pq3);
  k_stat2<<<B_ * 4, 128, 0, stream>>>(ps3, pq3, gm3, gi3, 128, (float)(32 * HW_));
  // 5. se conv1x1 on gelu(gn4(S2)) (+bias) -> S1 = sf
  k_gemm1x1<128,128><<<dim3(B_, 256), blk, 0, stream>>>(S2, NF, 128, wTse, se_b2,
      gm3,gi3,se_g,se_be,5,4, NF,NF,NF,NF,0,0, S1, NFm, NFm);
  // 6. prototypes + folded q
  k_pinit<<<B_, blk, 0, stream>>>(temb, pi_w1, pi_b1, pi_w2, pi_b2, pinitb);
  k_protos<<<1, blk, 0, stream>>>(pinitb, task_ids, fgb, bgb);
  k_qk<<<B_, blk, 0, stream>>>(fgb, bgb, at_in_w, at_in_b, qkvecb, kdotb);
  // 7. fused sim+factor+scores+|sim| partials (c-split, grid (B,256))
  k_simscores<<<dim3(B_, 256), blk, 0, stream>>>(S1, fgb, bgb, qkvecb, kdotb,
                                                 sim, factor, scores, psimb);
  // 8. softmax stats + weighted sums (4-way j-split)
  k_smstats<<<B_ * 8, blk, 0, stream>>>(scores, smaxb, ssumb);
  k_wsum<<<dim3(B_ * C_, 4), blk, 0, stream>>>(S1, scores, smaxb, ssumb, wsum4b);
  // 9. small head chain + w_eff
  k_small<<<B_, blk, 0, stream>>>(wsum4b, at_in_w, at_in_b, at_out_w, at_out_b,
                                  pf_w, pf_b, eg_w1, eg_b1, ewg_w, ewg_b, eg1b, ewb);
  k_weff<<<dim3(B_, 5), blk, 0, stream>>>(eg1b, ewb, eg_w2, eg_b2, eis, weffb);
  // 10. fused x_enh -> y -> h (x = fu raw out = S0; h -> S2)
  k_ydw<<<dim3(B_ * C_, 4), blk, 0, stream>>>(S0, factor, gmC, giC, fu_g, fu_b,
      weffb, hd_w1, hd_b1, y_out, S2, psH, pqH);
  k_stat2<<<B_, 128, 0, stream>>>(psH, pqH, gmH, giH, 512, (float)(128 * HW_));
  // 11. logits (c-split, grid (B,256))
  k_logits<<<dim3(B_, 256), blk, 0, stream>>>(S2, gmH, giH, hd_g, hd_be, hd_w2, hd_b2,
                                              task_ids, logitsb);
  // 12. sim scaling + fsw
  k_final<<<(unsigned)((size_t)B_ * HW_ / 256), blk, 0, stream>>>(logitsb, sim, psimb,
                                                                  sim_temp, proto_amp,
                                                                  asw, fsw_out);
  // 13. resize logits 128->512 -> pred
  k_resize<<<(unsigned)((size_t)B_ * 512 * 512 / 256), blk, 0, stream>>>(logitsb, pred_out,
                                                                          B_, 128, 128, 512, 512);
}

// Round 21
// 420.069 us; speedup vs baseline: 1.3411x; 1.1003x over previous
//
#include <hip/hip_runtime.h>
#include <math.h>

constexpr int B_ = 4;
constexpr int C_ = 128;
constexpr int HW_ = 16384;
constexpr int W_ = 128;
constexpr int M_ = 6;
constexpr int TDIM_ = 64;
constexpr int NT_ = 1; // NUM_TASKS

static __device__ __forceinline__ float gelu_f(float x){
  return 0.5f * x * (1.0f + erff(x * 0.7071067811865476f));
}
static __device__ __forceinline__ int imin(int a, int b){ return a < b ? a : b; }

// ---------- block reduce (256 threads) ----------
static __device__ __forceinline__ float block_reduce_sum256(float v, float* lds){
  int t = threadIdx.x;
  lds[t] = v; __syncthreads();
  for (int s = 128; s > 0; s >>= 1){ if (t < s) lds[t] += lds[t + s]; __syncthreads(); }
  float r = lds[0]; __syncthreads();
  return r;
}

// ---------- align-corners bilinear resize (generic; used for final 128->512) -
__global__ void k_resize(const float* __restrict__ in, float* __restrict__ out,
                         int BC, int Hi, int Wi, int Ho, int Wo){
  int idx = blockIdx.x * 256 + threadIdx.x;
  int total = BC * Ho * Wo;
  if (idx >= total) return;
  int xo = idx % Wo; int yo = (idx / Wo) % Ho; int bc = idx / (Wo * Ho);
  float sy = (Ho > 1) ? yo * (float)(Hi - 1) / (float)(Ho - 1) : 0.f;
  float sx = (Wo > 1) ? xo * (float)(Wi - 1) / (float)(Wo - 1) : 0.f;
  int y0 = (int)floorf(sy); int y1 = imin(y0 + 1, Hi - 1); float wy = sy - (float)y0;
  int x0 = (int)floorf(sx); int x1 = imin(x0 + 1, Wi - 1); float wx = sx - (float)x0;
  const float* p = in + (size_t)bc * Hi * Wi;
  float a = p[y0 * Wi + x0], b = p[y1 * Wi + x0];
  float c = p[y0 * Wi + x1], d = p[y1 * Wi + x1];
  float t0 = a * (1.f - wy) + b * wy;
  float t1 = c * (1.f - wy) + d * wy;
  out[idx] = t0 * (1.f - wx) + t1 * wx;
}

// ---------- resize 64->128 of ph conv output + GN stats partials -------------
// R21: resize and 1x1-conv commute (both linear; conv is pointwise in space,
// resize is per-channel). ph GEMM now runs at 64x64 (4x less work); this pass
// upsamples to 128x128 and accumulates sum/sumsq for the GN over the RESIZED
// tensor (matching the reference order).
__global__ void k_resize_stat(const float* __restrict__ in,  // (B,128,64,64)
                              float* __restrict__ out,       // (B,128,128,128)
                              float* __restrict__ psum, float* __restrict__ psq){
  int b = blockIdx.x; int y = blockIdx.y;  // 256 blocks per b
  int t = threadIdx.x;
  __shared__ float red[256];
  float s = 0.f, ss = 0.f;
  const float SC = 63.f / 127.f;
  for (int k = 0; k < 32; ++k){
    int e = y * 8192 + k * 256 + t;          // e in [0, 128*16384)
    int c = e >> 14, p = e & 16383;
    int yo = p >> 7, xo = p & 127;
    float sy = yo * SC, sx = xo * SC;
    int y0 = (int)sy; int y1 = imin(y0 + 1, 63); float wy = sy - (float)y0;
    int x0 = (int)sx; int x1 = imin(x0 + 1, 63); float wx = sx - (float)x0;
    const float* pp = in + ((size_t)b * 128 + c) * 4096;
    float a = pp[y0 * 64 + x0], bb = pp[y1 * 64 + x0];
    float cc = pp[y0 * 64 + x1], d = pp[y1 * 64 + x1];
    float t0 = a * (1.f - wy) + bb * wy;
    float t1 = cc * (1.f - wy) + d * wy;
    float v = t0 * (1.f - wx) + t1 * wx;
    out[((size_t)b * 128 + c) * (size_t)HW_ + p] = v;
    s += v; ss += v * v;
  }
  s = block_reduce_sum256(s, red);
  ss = block_reduce_sum256(ss, red);
  if (t == 0){ psum[b * 256 + y] = s; psq[b * 256 + y] = ss; }
}

// ---------- stats finalize ----------
__global__ void k_stat2(const float* __restrict__ ps, const float* __restrict__ pq,
                        float* __restrict__ gm, float* __restrict__ gi,
                        int nper, float nelem){
  int idx = blockIdx.x; int t = threadIdx.x;
  __shared__ float l1[128], l2[128];
  float s = 0.f, ss = 0.f;
  for (int i = t; i < nper; i += 128){ s += ps[idx * nper + i]; ss += pq[idx * nper + i]; }
  l1[t] = s; l2[t] = ss; __syncthreads();
  for (int st = 64; st > 0; st >>= 1){
    if (t < st){ l1[t] += l1[t + st]; l2[t] += l2[t + st]; }
    __syncthreads();
  }
  if (t == 0){
    float mu = l1[0] / nelem;
    float var = l2[0] / nelem - mu * mu;
    gm[idx] = mu; gi[idx] = rsqrtf(var + 1e-5f);
  }
}

// ---------- dual stats finalize ----------
__global__ void k_stat2_dual(const float* __restrict__ psA, const float* __restrict__ pqA,
                             float* __restrict__ gmA, float* __restrict__ giA, float nelemA,
                             const float* __restrict__ psB, const float* __restrict__ pqB,
                             float* __restrict__ gmB, float* __restrict__ giB, float nelemB){
  int idx = blockIdx.x; int t = threadIdx.x;
  __shared__ float l1[128], l2[128];
  const float* ps; const float* pq; float* gm; float* gi; float nelem; int id2;
  if (idx < 4){ ps = psA; pq = pqA; gm = gmA; gi = giA; nelem = nelemA; id2 = idx; }
  else        { ps = psB; pq = pqB; gm = gmB; gi = giB; nelem = nelemB; id2 = idx - 4; }
  float s = 0.f, ss = 0.f;
  for (int i = t; i < 256; i += 128){ s += ps[id2 * 256 + i]; ss += pq[id2 * 256 + i]; }
  l1[t] = s; l2[t] = ss; __syncthreads();
  for (int st = 64; st > 0; st >>= 1){
    if (t < st){ l1[t] += l1[t + st]; l2[t] += l2[t + st]; }
    __syncthreads();
  }
  if (t == 0){
    float mu = l1[0] / nelem;
    float var = l2[0] / nelem - mu * mu;
    gm[id2] = mu; gi[id2] = rsqrtf(var + 1e-5f);
  }
}

// ---------- merged weight transposes ----------
__global__ void k_wtall(const float* __restrict__ ph_w, const float* __restrict__ pl_w,
                        const float* __restrict__ fu_w, const float* __restrict__ se_w2,
                        float* __restrict__ wTph, float* __restrict__ wTpl,
                        float* __restrict__ wTfu, float* __restrict__ wTse){
  int idx = blockIdx.x * 256 + threadIdx.x;
  if (idx < 16384){
    int ci = idx / 128, co = idx % 128;
    wTph[idx] = ph_w[co * 128 + ci];
  } else if (idx < 20480){
    int r = idx - 16384; int ci = r / 64, co = r % 64;
    wTpl[r] = pl_w[co * 64 + ci];
  } else if (idx < 45056){
    int r = idx - 20480; int ci = r / 128, co = r % 128;
    wTfu[r] = fu_w[(size_t)co * 192 + ci];
  } else if (idx < 61440){
    int r = idx - 45056; int ci = r / 128, co = r % 128;
    wTse[r] = se_w2[co * 128 + ci];
  }
}

// ---------- shared GEMM body (raw input, K-chunk 16, pixel-count param) ------
template<int CO, int CIT, int HWN>
static __device__ __forceinline__ void gemm_body(
    const float* __restrict__ in1, const float* __restrict__ wT,
    float* __restrict__ out, float* __restrict__ psum, float* __restrict__ psq,
    int b, int j0, int slot, float* As, float* Bs, float* red){
  const int tid = threadIdx.x;
  const int tj = tid & 15, tco = tid >> 4;
  constexpr int CPT = CO / 16;
  constexpr int AST = CO + 4;
  float acc[CPT][4];
  #pragma unroll
  for (int i = 0; i < CPT; ++i)
    #pragma unroll
    for (int j = 0; j < 4; ++j) acc[i][j] = 0.f;

  for (int k0 = 0; k0 < CIT; k0 += 16){
    const int kk = tid >> 4;
    if constexpr (CO == 128){
      int co = (tid & 15) * 8;
      const float* wp = &wT[(size_t)(k0 + kk) * CO + co];
      *(float4*)&As[kk * AST + co] = *(const float4*)wp;
      *(float4*)&As[kk * AST + co + 4] = *(const float4*)(wp + 4);
    } else {
      int co = (tid & 15) * 4;
      *(float4*)&As[kk * AST + co] = *(const float4*)&wT[(size_t)(k0 + kk) * CO + co];
    }
    {
      int jj = (tid & 15) * 4;
      int ci = k0 + kk;
      float4 v = *(const float4*)&in1[((size_t)b * CIT + ci) * HWN + j0 + jj];
      *(float4*)&Bs[kk * 68 + jj] = v;
    }
    __syncthreads();
    #pragma unroll
    for (int kkk = 0; kkk < 16; ++kkk){
      float4 bq = *(const float4*)&Bs[kkk * 68 + tj * 4];
      float av[CPT];
      if constexpr (CPT == 8){
        float4 a0 = *(const float4*)&As[kkk * AST + tco * 8];
        float4 a1 = *(const float4*)&As[kkk * AST + tco * 8 + 4];
        av[0] = a0.x; av[1] = a0.y; av[2] = a0.z; av[3] = a0.w;
        av[4] = a1.x; av[5] = a1.y; av[6] = a1.z; av[7] = a1.w;
      } else {
        float4 a0 = *(const float4*)&As[kkk * AST + tco * 4];
        av[0] = a0.x; av[1] = a0.y; av[2] = a0.z; av[3] = a0.w;
      }
      #pragma unroll
      for (int i = 0; i < CPT; ++i){
        acc[i][0] = fmaf(av[i], bq.x, acc[i][0]);
        acc[i][1] = fmaf(av[i], bq.y, acc[i][1]);
        acc[i][2] = fmaf(av[i], bq.z, acc[i][2]);
        acc[i][3] = fmaf(av[i], bq.w, acc[i][3]);
      }
    }
    __syncthreads();
  }
  float s = 0.f, ss = 0.f;
  #pragma unroll
  for (int i = 0; i < CPT; ++i){
    int co = tco * CPT + i;
    float4 o;
    o.x = acc[i][0]; o.y = acc[i][1]; o.z = acc[i][2]; o.w = acc[i][3];
    *(float4*)&out[((size_t)b * CO + co) * HWN + j0 + tj * 4] = o;
    s += o.x + o.y + o.z + o.w;
    ss += o.x * o.x + o.y * o.y + o.z * o.z + o.w * o.w;
  }
  s = block_reduce_sum256(s, red);
  ss = block_reduce_sum256(ss, red);
  if (tid == 0){ psum[slot] = s; psq[slot] = ss; }
}

// ---------- dual GEMM: ph at 64x64 (4x less work) || pl at 128x128 -----------
__global__ __launch_bounds__(256, 4) void k_gemm_dual(
    const float* __restrict__ in_ph, const float* __restrict__ wT_ph,
    float* __restrict__ out_ph, float* __restrict__ psD, float* __restrict__ pqD,
    const float* __restrict__ in_pl, const float* __restrict__ wT_pl,
    float* __restrict__ out_pl, float* __restrict__ psB, float* __restrict__ pqB){
  __shared__ float As[16 * 132];
  __shared__ float Bs[16 * 68];
  __shared__ float red[256];
  int b = blockIdx.x;
  if (blockIdx.y < 64){
    int yb = blockIdx.y;   // 4096 px -> 64 tiles of 64
    gemm_body<128, 128, 4096>(in_ph, wT_ph, out_ph, psD, pqD, b, yb * 64, b * 64 + yb, As, Bs, red);
  } else {
    int yb = blockIdx.y - 64;
    gemm_body<64, 64, 16384>(in_pl, wT_pl, out_pl, psB, pqB, b, yb * 64, b * 256 + yb, As, Bs, red);
  }
}

// ---------- tiled 1x1-conv GEMM (K-chunk 16) with GN+GELU on input -----------
template<int CO, int CIT>
__global__ __launch_bounds__(256, 4) void k_gemm1x1(
    const float* __restrict__ in1, const float* __restrict__ in2, int CI1,
    const float* __restrict__ wT, const float* __restrict__ bias,
    const float* __restrict__ gm1, const float* __restrict__ gi1,
    const float* __restrict__ ga1, const float* __restrict__ be1, int sh1, int ng1,
    const float* __restrict__ gm2, const float* __restrict__ gi2,
    const float* __restrict__ ga2, const float* __restrict__ be2, int sh2, int ng2,
    float* __restrict__ out, float* __restrict__ psum, float* __restrict__ psq){
  __shared__ float As[16][CO + 4];
  __shared__ float Bs[16][68];
  __shared__ float red[256];
  const int b = blockIdx.x;
  const int j0 = blockIdx.y * 64;
  const int tid = threadIdx.x;
  const int tj = tid & 15, tco = tid >> 4;
  constexpr int CPT = CO / 16;

  float acc[CPT][4];
  #pragma unroll
  for (int i = 0; i < CPT; ++i)
    #pragma unroll
    for (int j = 0; j < 4; ++j) acc[i][j] = 0.f;

  for (int k0 = 0; k0 < CIT; k0 += 16){
    const int kk = tid >> 4;
    if constexpr (CO == 128){
      int co = (tid & 15) * 8;
      const float* wp = &wT[(size_t)(k0 + kk) * CO + co];
      *(float4*)&As[kk][co] = *(const float4*)wp;
      *(float4*)&As[kk][co + 4] = *(const float4*)(wp + 4);
    } else {
      int co = (tid & 15) * 4;
      *(float4*)&As[kk][co] = *(const float4*)&wT[(size_t)(k0 + kk) * CO + co];
    }
    {
      int jj = (tid & 15) * 4;
      int ci = k0 + kk;
      float4 v;
      if (ci < CI1){
        v = *(const float4*)&in1[((size_t)b * CI1 + ci) * HW_ + j0 + jj];
        if (gm1){
          int g = ci >> sh1;
          float rs = gi1[b * ng1 + g];
          float ga = ga1[ci] * rs;
          float be = be1[ci] - gm1[b * ng1 + g] * ga;
          v.x = gelu_f(fmaf(v.x, ga, be)); v.y = gelu_f(fmaf(v.y, ga, be));
          v.z = gelu_f(fmaf(v.z, ga, be)); v.w = gelu_f(fmaf(v.w, ga, be));
        }
      } else {
        int c2 = ci - CI1;
        v = *(const float4*)&in2[((size_t)b * (CIT - CI1) + c2) * HW_ + j0 + jj];
        if (gm2){
          int g = c2 >> sh2;
          float rs = gi2[b * ng2 + g];
          float ga = ga2[c2] * rs;
          float be = be2[c2] - gm2[b * ng2 + g] * ga;
          v.x = gelu_f(fmaf(v.x, ga, be)); v.y = gelu_f(fmaf(v.y, ga, be));
          v.z = gelu_f(fmaf(v.z, ga, be)); v.w = gelu_f(fmaf(v.w, ga, be));
        }
      }
      *(float4*)&Bs[kk][jj] = v;
    }
    __syncthreads();
    #pragma unroll
    for (int kkk = 0; kkk < 16; ++kkk){
      float4 bq = *(const float4*)&Bs[kkk][tj * 4];
      float av[CPT];
      if constexpr (CPT == 8){
        float4 a0 = *(const float4*)&As[kkk][tco * 8];
        float4 a1 = *(const float4*)&As[kkk][tco * 8 + 4];
        av[0] = a0.x; av[1] = a0.y; av[2] = a0.z; av[3] = a0.w;
        av[4] = a1.x; av[5] = a1.y; av[6] = a1.z; av[7] = a1.w;
      } else {
        float4 a0 = *(const float4*)&As[kkk][tco * 4];
        av[0] = a0.x; av[1] = a0.y; av[2] = a0.z; av[3] = a0.w;
      }
      #pragma unroll
      for (int i = 0; i < CPT; ++i){
        acc[i][0] = fmaf(av[i], bq.x, acc[i][0]);
        acc[i][1] = fmaf(av[i], bq.y, acc[i][1]);
        acc[i][2] = fmaf(av[i], bq.z, acc[i][2]);
        acc[i][3] = fmaf(av[i], bq.w, acc[i][3]);
      }
    }
    __syncthreads();
  }
  float s = 0.f, ss = 0.f;
  #pragma unroll
  for (int i = 0; i < CPT; ++i){
    int co = tco * CPT + i;
    float bb = bias ? bias[co] : 0.f;
    float4 o;
    o.x = acc[i][0] + bb; o.y = acc[i][1] + bb;
    o.z = acc[i][2] + bb; o.w = acc[i][3] + bb;
    *(float4*)&out[((size_t)b * CO + co) * HW_ + j0 + tj * 4] = o;
    s += o.x + o.y + o.z + o.w;
    ss += o.x * o.x + o.y * o.y + o.z * o.z + o.w * o.w;
  }
  if (psum){
    s = block_reduce_sum256(s, red);
    ss = block_reduce_sum256(ss, red);
    if (tid == 0){
      psum[b * gridDim.y + blockIdx.y] = s;
      psq [b * gridDim.y + blockIdx.y] = ss;
    }
  }
}

// ---------- grouped 3x3 conv, column-scalar mapping (R18, measured best) -----
__global__ __launch_bounds__(256) void k_se3(const float* __restrict__ x,
    const float* __restrict__ gm, const float* __restrict__ gi,
    const float* __restrict__ gamma, const float* __restrict__ beta,
    const float* __restrict__ w, const float* __restrict__ bias,
    float* __restrict__ out, float* __restrict__ psum, float* __restrict__ psq){
  __shared__ float xs[4][10][128];
  __shared__ float ws[144];
  __shared__ float wb[4];
  __shared__ float red[256];
  const int bgc = blockIdx.x; const int b = bgc >> 5, gc = bgc & 31;
  const int r0 = blockIdx.y * 8;
  const int tid = threadIdx.x;
  const float mu = gm[b], rs = gi[b];
  for (int ch = 0; ch < 4; ++ch){
    int c = gc * 4 + ch;
    float ga = gamma[c] * rs, be = beta[c] - mu * rs * gamma[c];
    const float* px = x + ((size_t)b * C_ + c) * HW_;
    for (int i = tid; i < 10 * 128; i += 256){
      int rr = i >> 7, cc = i & 127;
      int row = r0 - 1 + rr;
      float v = 0.f;
      if ((unsigned)row < 128u) v = gelu_f(fmaf(px[row * W_ + cc], ga, be));
      xs[ch][rr][cc] = v;
    }
  }
  if (tid < 144) ws[tid] = w[(size_t)(gc * 4) * 36 + tid];
  if (tid < 4)   wb[tid] = bias[gc * 4 + tid];
  __syncthreads();
  const int hf = tid >> 7;
  const int cc = tid & 127;
  float s = 0.f, ss = 0.f;
  for (int co_l = 0; co_l < 4; ++co_l){
    float bb = wb[co_l];
    float a0 = bb, a1 = bb, a2 = bb, a3 = bb;
    #pragma unroll
    for (int cil = 0; cil < 4; ++cil){
      float w9[9];
      #pragma unroll
      for (int i = 0; i < 9; ++i) w9[i] = ws[(co_l * 4 + cil) * 9 + i];
      #pragma unroll
      for (int q = 0; q < 6; ++q){
        int xr = 4 * hf + q;
        float mdl = xs[cil][xr][cc];
        float lft = (cc > 0)   ? xs[cil][xr][cc - 1] : 0.f;
        float rgt = (cc < 127) ? xs[cil][xr][cc + 1] : 0.f;
        if (q <= 2){
          int ky = q;       a0 = fmaf(w9[ky*3], lft, a0); a0 = fmaf(w9[ky*3+1], mdl, a0); a0 = fmaf(w9[ky*3+2], rgt, a0);
        }
        if (q >= 1 && q <= 3){
          int ky = q - 1;   a1 = fmaf(w9[ky*3], lft, a1); a1 = fmaf(w9[ky*3+1], mdl, a1); a1 = fmaf(w9[ky*3+2], rgt, a1);
        }
        if (q >= 2 && q <= 4){
          int ky = q - 2;   a2 = fmaf(w9[ky*3], lft, a2); a2 = fmaf(w9[ky*3+1], mdl, a2); a2 = fmaf(w9[ky*3+2], rgt, a2);
        }
        if (q >= 3){
          int ky = q - 3;   a3 = fmaf(w9[ky*3], lft, a3); a3 = fmaf(w9[ky*3+1], mdl, a3); a3 = fmaf(w9[ky*3+2], rgt, a3);
        }
      }
    }
    float* po = &out[((size_t)b * C_ + gc * 4 + co_l) * HW_ + (r0 + 4 * hf) * W_ + cc];
    po[0]       = a0;
    po[W_]      = a1;
    po[2 * W_]  = a2;
    po[3 * W_]  = a3;
    s += a0 + a1 + a2 + a3;
    ss += a0 * a0 + a1 * a1 + a2 * a2 + a3 * a3;
  }
  s = block_reduce_sum256(s, red);
  ss = block_reduce_sum256(ss, red);
  if (tid == 0){
    int idx = (b * 4 + (gc >> 3)) * 128 + (gc & 7) * 16 + blockIdx.y;
    psum[idx] = s; psq[idx] = ss;
  }
}

// ---------- fused: x_enh -> y (3x3 dyn) -> h (3x3 dw) + GN stats for h -------
__global__ __launch_bounds__(256) void k_ydw(const float* __restrict__ x,
    const float* __restrict__ factor,
    const float* __restrict__ gm, const float* __restrict__ gi,
    const float* __restrict__ gamma, const float* __restrict__ beta,
    const float* __restrict__ w_eff, const float* __restrict__ dw_w,
    const float* __restrict__ dw_b, float* __restrict__ y_out,
    float* __restrict__ h_out, float* __restrict__ psum, float* __restrict__ psq){
  __shared__ float xs[36][128];
  __shared__ float ys[34][128];
  __shared__ float red[256];
  const int bc = blockIdx.x; const int b = bc >> 7, c = bc & 127;
  const int r0 = blockIdx.y * 32;
  const int tid = threadIdx.x;
  const float mu = gm[b], rs = gi[b];
  const float ga = gamma[c] * rs, be = beta[c] - mu * rs * gamma[c];
  const float* px = x + ((size_t)b * C_ + c) * HW_;
  const float* pf = factor + (size_t)b * HW_;
  for (int i = tid; i < 36 * 128; i += 256){
    int rr = i >> 7, cc = i & 127;
    int row = r0 - 2 + rr;
    float v = 0.f;
    if ((unsigned)row < 128u)
      v = gelu_f(fmaf(px[row * W_ + cc], ga, be)) * pf[row * W_ + cc];
    xs[rr][cc] = v;
  }
  __syncthreads();
  float w9[9];
  #pragma unroll
  for (int r = 0; r < 9; ++r) w9[r] = w_eff[b * 1152 + c * 9 + r];
  for (int i = tid; i < 34 * 128; i += 256){
    int rr = i >> 7, cc = i & 127;
    int row = r0 - 1 + rr;
    float acc = 0.f;
    if ((unsigned)row < 128u){
      #pragma unroll
      for (int ky = 0; ky < 3; ++ky){
        #pragma unroll
        for (int kx = 0; kx < 3; ++kx){
          int xc = cc + kx - 1;
          if ((unsigned)xc < 128u) acc += w9[ky * 3 + kx] * xs[rr + ky][xc];
        }
      }
    }
    ys[rr][cc] = acc;
    if (rr >= 1 && rr <= 32)
      y_out[((size_t)b * C_ + c) * HW_ + row * W_ + cc] = acc;
  }
  __syncthreads();
  float wd[9];
  #pragma unroll
  for (int r = 0; r < 9; ++r) wd[r] = dw_w[c * 9 + r];
  const float bb = dw_b[c];
  float s = 0.f, ss = 0.f;
  for (int i = tid; i < 32 * 128; i += 256){
    int rr = i >> 7, cc = i & 127;
    int row = r0 + rr;
    float acc = bb;
    #pragma unroll
    for (int ky = 0; ky < 3; ++ky){
      #pragma unroll
      for (int kx = 0; kx < 3; ++kx){
        int yc = cc + kx - 1;
        if ((unsigned)yc < 128u) acc += wd[ky * 3 + kx] * ys[rr + ky][yc];
      }
    }
    h_out[((size_t)b * C_ + c) * HW_ + row * W_ + cc] = acc;
    s += acc; ss += acc * acc;
  }
  s = block_reduce_sum256(s, red);
  ss = block_reduce_sum256(ss, red);
  if (tid == 0){
    int idx = b * 512 + c * 4 + blockIdx.y;
    psum[idx] = s; psq[idx] = ss;
  }
}

// ---------- prototype init MLP (per b) ----------
__global__ void k_pinit(const float* __restrict__ temb, const float* __restrict__ w1,
                        const float* __restrict__ b1, const float* __restrict__ w2,
                        const float* __restrict__ b2, float* __restrict__ pinit){
  int b = blockIdx.x; int t = threadIdx.x;
  __shared__ float h1[256], p2[256], nrm[2];
  float acc = b1[t];
  for (int i = 0; i < TDIM_; ++i) acc += temb[b * TDIM_ + i] * w1[t * TDIM_ + i];
  h1[t] = gelu_f(acc); __syncthreads();
  acc = b2[t];
  for (int i = 0; i < 256; ++i) acc += h1[i] * w2[t * 256 + i];
  p2[t] = acc; __syncthreads();
  if (t < 2){
    float s = 0.f;
    for (int c = 0; c < 128; ++c){ float v = p2[t * 128 + c]; s += v * v; }
    nrm[t] = fmaxf(sqrtf(s), 1e-12f);
  }
  __syncthreads();
  pinit[b * 256 + t] = p2[t] / nrm[t / 128];
}

// ---------- table / protos / fg,bg ----------
__global__ void k_protos(const float* __restrict__ pinit, const int* __restrict__ task_ids,
                         float* __restrict__ fg, float* __restrict__ bg){
  __shared__ int tbl[NT_];
  __shared__ int src[B_];
  __shared__ float nr[B_ * 2];
  int t = threadIdx.x;
  if (t < NT_){
    int idx = 0;
    for (int b = B_ - 1; b >= 0; --b) if (task_ids[b] == t) idx = b;
    tbl[t] = idx;
  }
  __syncthreads();
  if (t < B_){
    int ti = task_ids[t]; ti = ti < 0 ? 0 : (ti >= NT_ ? NT_ - 1 : ti);
    src[t] = tbl[ti];
  }
  __syncthreads();
  if (t < 2 * B_){
    int b = t / 2, r = t % 2;
    float s = 0.f;
    for (int c = 0; c < 128; ++c){ float v = pinit[src[b] * 256 + r * 128 + c]; s += v * v; }
    nr[t] = fmaxf(sqrtf(s), 1e-12f);
  }
  __syncthreads();
  for (int i = t; i < B_ * 128; i += 256){
    int b = i / 128, c = i % 128;
    fg[i] = pinit[src[b] * 256 + c] / nr[b * 2 + 0];
    bg[i] = pinit[src[b] * 256 + 128 + c] / nr[b * 2 + 1];
  }
}

// ---------- q projection folded into key space ----------
__global__ void k_qk(const float* __restrict__ fg, const float* __restrict__ bg,
                     const float* __restrict__ at_in_w, const float* __restrict__ at_in_b,
                     float* __restrict__ qkvec, float* __restrict__ kdot){
  int b = blockIdx.x, t = threadIdx.x;
  __shared__ float pq[256], qf[256];
  pq[t] = (t < 128) ? fg[b * 128 + t] : bg[b * 128 + (t - 128)];
  __syncthreads();
  {
    int qi = t / 128, o = t % 128;
    float acc = at_in_b[o];
    const float* wr = at_in_w + (size_t)o * 128;
    for (int c = 0; c < 128; ++c) acc += wr[c] * pq[qi * 128 + c];
    qf[qi * 128 + o] = acc;
  }
  __syncthreads();
  for (int e = t; e < 1024; e += 256){
    int p = e / 128, c = e % 128, qi = p / 4, h = p % 4;
    float acc = 0.f;
    for (int d = 0; d < 32; ++d)
      acc += qf[qi * 128 + h * 32 + d] * at_in_w[(size_t)(128 + h * 32 + d) * 128 + c];
    qkvec[b * 1024 + e] = acc;
  }
  if (t < 8){
    int qi = t / 4, h = t % 4;
    float acc = 0.f;
    for (int d = 0; d < 32; ++d) acc += qf[qi * 128 + h * 32 + d] * at_in_b[128 + h * 32 + d];
    kdot[b * 8 + t] = acc;
  }
}

// ---------- fused sim/factor/scores, c-split 4-way ---------------------------
__global__ __launch_bounds__(256) void k_simscores(const float* __restrict__ sf,
                          const float* __restrict__ fg, const float* __restrict__ bg,
                          const float* __restrict__ qkvec, const float* __restrict__ kdot,
                          float* __restrict__ sim, float* __restrict__ factor,
                          float* __restrict__ scores, float* __restrict__ psim){
  int b = blockIdx.x; int j0 = blockIdx.y * 64;
  int t = threadIdx.x;
  int g = t >> 6, jl = t & 63;
  int j = j0 + jl;
  __shared__ float L[10 * 128];
  __shared__ float part[11 * 256];
  __shared__ float red64[64];
  for (int i = t; i < 1280; i += 256){
    int r = i >> 7, c = i & 127;
    L[i] = (r == 0) ? fg[b * 128 + c]
         : (r == 1) ? bg[b * 128 + c]
                    : qkvec[b * 1024 + (r - 2) * 128 + c];
  }
  __syncthreads();
  const float* p = sf + (size_t)b * C_ * HW_ + j;
  float a0=0,a1=0,q0=0,q1=0,q2=0,q3=0,q4=0,q5=0,q6=0,q7=0,nn=0;
  int c0 = g * 32;
  #pragma unroll 8
  for (int c = c0; c < c0 + 32; ++c){
    float v = p[(size_t)c * HW_];
    nn += v * v;
    a0 += L[c] * v;          a1 += L[128 + c] * v;
    q0 += L[256 + c] * v;    q1 += L[384 + c] * v;
    q2 += L[512 + c] * v;    q3 += L[640 + c] * v;
    q4 += L[768 + c] * v;    q5 += L[896 + c] * v;
    q6 += L[1024 + c] * v;   q7 += L[1152 + c] * v;
  }
  part[0 * 256 + t] = nn;  part[1 * 256 + t] = a0;  part[2 * 256 + t] = a1;
  part[3 * 256 + t] = q0;  part[4 * 256 + t] = q1;  part[5 * 256 + t] = q2;
  part[6 * 256 + t] = q3;  part[7 * 256 + t] = q4;  part[8 * 256 + t] = q5;
  part[9 * 256 + t] = q6;  part[10 * 256 + t] = q7;
  __syncthreads();
  float sv = 0.f;
  if (t < 64){
    float tot[11];
    #pragma unroll
    for (int i = 0; i < 11; ++i)
      tot[i] = part[i * 256 + t] + part[i * 256 + t + 64]
             + part[i * 256 + t + 128] + part[i * 256 + t + 192];
    float inv = 1.f / fmaxf(sqrtf(tot[0]), 1e-12f);
    sv = (tot[1] - tot[2]) * inv;
    sim[b * HW_ + j0 + t] = sv;
    factor[b * HW_ + j0 + t] = 1.f + 0.5f / (1.f + expf(-sv));
    const float scale = 0.17677669529663689f;
    #pragma unroll
    for (int pp = 0; pp < 8; ++pp)
      scores[((size_t)(b * 8 + pp)) * HW_ + j0 + t] = (tot[3 + pp] + kdot[b * 8 + pp]) * scale;
  }
  __syncthreads();
  if (t < 64) red64[t] = fabsf(sv);
  __syncthreads();
  for (int s2 = 32; s2 > 0; s2 >>= 1){
    if (t < s2) red64[t] += red64[t + s2];
    __syncthreads();
  }
  if (t == 0) psim[b * 256 + blockIdx.y] = red64[0];
}

// ---------- softmax stats, j-split 8-way partials (occupancy fix) ------------
// R21: old k_smstats was 32 blocks = 0.125/CU. Now (32,8) partial (max, sumexp
// with local max); k_wsum combines online: z = sum z_i * exp(m_i - m).
__global__ void k_smpart(const float* __restrict__ scores, float* __restrict__ pm,
                         float* __restrict__ pz){
  __shared__ float lds[256];
  int row = blockIdx.x; int chunk = blockIdx.y;
  const float* p = scores + (size_t)row * HW_ + chunk * 2048;
  float m = -1e30f;
  for (int j = threadIdx.x; j < 2048; j += 256) m = fmaxf(m, p[j]);
  lds[threadIdx.x] = m; __syncthreads();
  for (int s = 128; s > 0; s >>= 1){
    if (threadIdx.x < s) lds[threadIdx.x] = fmaxf(lds[threadIdx.x], lds[threadIdx.x + s]);
    __syncthreads();
  }
  m = lds[0]; __syncthreads();
  float z = 0.f;
  for (int j = threadIdx.x; j < 2048; j += 256) z += expf(p[j] - m);
  z = block_reduce_sum256(z, lds);
  if (threadIdx.x == 0){ pm[row * 8 + chunk] = m; pz[row * 8 + chunk] = z; }
}

// ---------- wsum, 4-way j-split; combines smpart partials inline -------------
__global__ void k_wsum(const float* __restrict__ sf, const float* __restrict__ scores,
                       const float* __restrict__ pm, const float* __restrict__ pz,
                       float* __restrict__ wsum4){
  int bc = blockIdx.x; int b = bc / C_, c = bc % C_;
  int chunk = blockIdx.y;
  __shared__ float lds[8 * 256];
  __shared__ float mr[8], zr[8];
  if (threadIdx.x < 8){
    int r = b * 8 + threadIdx.x;
    float m = -1e30f;
    #pragma unroll
    for (int i = 0; i < 8; ++i) m = fmaxf(m, pm[r * 8 + i]);
    float z = 0.f;
    #pragma unroll
    for (int i = 0; i < 8; ++i) z += pz[r * 8 + i] * expf(pm[r * 8 + i] - m);
    mr[threadIdx.x] = m;
    zr[threadIdx.x] = 1.f / z;
  }
  __syncthreads();
  const float* p = sf + (size_t)bc * HW_;
  const float* sc = scores + (size_t)b * 8 * HW_;
  int j0 = chunk * (HW_ / 4), j1 = j0 + HW_ / 4;
  float acc[8] = {0,0,0,0,0,0,0,0};
  for (int j = j0 + threadIdx.x; j < j1; j += 256){
    float v = p[j];
    #pragma unroll
    for (int pp = 0; pp < 8; ++pp)
      acc[pp] = fmaf(expf(sc[(size_t)pp * HW_ + j] - mr[pp]) * zr[pp], v, acc[pp]);
  }
  #pragma unroll
  for (int pp = 0; pp < 8; ++pp) lds[pp * 256 + threadIdx.x] = acc[pp];
  __syncthreads();
  for (int s = 128; s > 0; s >>= 1){
    if (threadIdx.x < s){
      #pragma unroll
      for (int pp = 0; pp < 8; ++pp) lds[pp * 256 + threadIdx.x] += lds[pp * 256 + threadIdx.x + s];
    }
    __syncthreads();
  }
  if (threadIdx.x < 8)
    wsum4[chunk * 4096 + b * 1024 + threadIdx.x * 128 + c] = lds[threadIdx.x * 256];
}

// ---------- small head chain (sums the 4 wsum partials on load) --------------
__global__ void k_small(const float* __restrict__ wsum4, const float* __restrict__ at_in_w,
                        const float* __restrict__ at_in_b, const float* __restrict__ at_out_w,
                        const float* __restrict__ at_out_b, const float* __restrict__ pf_w,
                        const float* __restrict__ pf_b, const float* __restrict__ eg_w1,
                        const float* __restrict__ eg_b1, const float* __restrict__ ewg_w,
                        const float* __restrict__ ewg_b, float* __restrict__ eg1_out,
                        float* __restrict__ ew_out){
  int b = blockIdx.x; int t = threadIdx.x;
  __shared__ float wsl[1024], att[256], ao[256], pf[128], ewl[8];
  for (int i = t; i < 1024; i += 256)
    wsl[i] = wsum4[b * 1024 + i] + wsum4[4096 + b * 1024 + i]
           + wsum4[8192 + b * 1024 + i] + wsum4[12288 + b * 1024 + i];
  __syncthreads();
  {
    int qi = t / 128, o = t % 128, h = o / 32, d = o % 32, p = qi * 4 + h;
    float acc = at_in_b[256 + h * 32 + d];
    const float* wr = at_in_w + (size_t)(256 + h * 32 + d) * 128;
    for (int c = 0; c < 128; ++c) acc += wr[c] * wsl[p * 128 + c];
    att[qi * 128 + o] = acc;
  }
  __syncthreads();
  {
    int qi = t / 128, o = t % 128;
    float acc = at_out_b[o];
    const float* wr = at_out_w + (size_t)o * 128;
    for (int c = 0; c < 128; ++c) acc += wr[c] * att[qi * 128 + c];
    ao[qi * 128 + o] = acc;
  }
  __syncthreads();
  if (t < 128){
    float acc = pf_b[t];
    const float* wr = pf_w + (size_t)t * 384;
    for (int c = 0; c < 128; ++c){
      float fa = ao[c], ba = ao[128 + c];
      acc += wr[c] * fa + wr[128 + c] * ba + wr[256 + c] * (fa - ba);
    }
    pf[t] = acc;
  }
  __syncthreads();
  {
    float acc = eg_b1[t];
    const float* wr = eg_w1 + (size_t)t * 128;
    for (int c = 0; c < 128; ++c) acc += wr[c] * pf[c];
    eg1_out[b * 256 + t] = gelu_f(acc);
  }
  if (t < M_){
    float acc = ewg_b[t];
    const float* wr = ewg_w + (size_t)t * 128;
    for (int c = 0; c < 128; ++c) acc += wr[c] * pf[c];
    ewl[t] = acc;
  }
  __syncthreads();
  if (t == 0){
    float m = -1e30f;
    for (int i = 0; i < M_; ++i) m = fmaxf(m, ewl[i]);
    float z = 0.f;
    for (int i = 0; i < M_; ++i){ ewl[i] = expf(ewl[i] - m); z += ewl[i]; }
    for (int i = 0; i < M_; ++i) ew_out[b * M_ + i] = ewl[i] / z;
  }
}

// ---------- w_eff[b,c,r] ----------
__global__ void k_weff(const float* __restrict__ eg1, const float* __restrict__ ew,
                       const float* __restrict__ eg_w2, const float* __restrict__ eg_b2,
                       const float* __restrict__ eis_p, float* __restrict__ w_eff){
  int b = blockIdx.x; int cr = blockIdx.y * 256 + threadIdx.x;
  __shared__ float e1[256]; __shared__ float ewl[M_];
  e1[threadIdx.x] = eg1[b * 256 + threadIdx.x];
  if (threadIdx.x < M_) ewl[threadIdx.x] = ew[b * M_ + threadIdx.x];
  __syncthreads();
  if (cr >= C_ * 9) return;
  int c = cr / 9, r = cr % 9;
  float eis = eis_p[0];
  float acc = 0.f;
  for (int m = 0; m < M_; ++m){
    size_t row = ((size_t)m * C_ + c) * 9 + r;
    float v = eg_b2[row];
    const float* wr = eg_w2 + row * 256;
    for (int i = 0; i < 256; ++i) v += wr[i] * e1[i];
    float ekv = v * eis + ((r == 4) ? (1.f - eis) : 0.f);
    acc += ewl[m] * ekv;
  }
  w_eff[b * (C_ * 9) + cr] = acc;
}

// ---------- logits, c-split 4-way ----------
__global__ __launch_bounds__(256) void k_logits(const float* __restrict__ h,
                         const float* __restrict__ gmean,
                         const float* __restrict__ ginv, const float* __restrict__ hd_g,
                         const float* __restrict__ hd_be, const float* __restrict__ hd_w2,
                         const float* __restrict__ hd_b2, const int* __restrict__ task_ids,
                         float* __restrict__ logits){
  int b = blockIdx.x; int j0 = blockIdx.y * 64;
  int t = threadIdx.x;
  int g = t >> 6, jl = t & 63;
  int it = task_ids[b]; it = it < 0 ? 0 : (it >= NT_ ? NT_ - 1 : it);
  __shared__ float wg[128], wb[128], w2[128];
  __shared__ float part[256];
  if (t < 128){
    wg[t] = hd_g[t];
    wb[t] = hd_be[t];
    w2[t] = hd_w2[it * C_ + t];
  }
  __syncthreads();
  float mu = gmean[b], rs = ginv[b];
  const float* p = h + (size_t)b * C_ * HW_ + j0 + jl;
  float acc = 0.f;
  int c0 = g * 32;
  #pragma unroll 8
  for (int c = c0; c < c0 + 32; ++c){
    float v = p[(size_t)c * HW_];
    v = (v - mu) * rs * wg[c] + wb[c];
    acc += w2[c] * gelu_f(v);
  }
  part[t] = acc;
  __syncthreads();
  if (t < 64){
    float tot = part[t] + part[t + 64] + part[t + 128] + part[t + 192] + hd_b2[it];
    logits[b * HW_ + j0 + t] = tot;
  }
}

// ---------- final: |sim| partial reduce inline (1024 partials) + fsw ---------
__global__ void k_final(float* __restrict__ logits, const float* __restrict__ sim,
                        const float* __restrict__ psim, const float* __restrict__ sim_temp,
                        const float* __restrict__ proto_amp,
                        const float* __restrict__ asw, float* __restrict__ fsw_out){
  __shared__ float red[256];
  float s = psim[threadIdx.x] + psim[256 + threadIdx.x]
          + psim[512 + threadIdx.x] + psim[768 + threadIdx.x];
  s = block_reduce_sum256(s, red);
  int idx = blockIdx.x * 256 + threadIdx.x;
  float mean = s / (float)(B_ * HW_);
  float denom = mean + 1e-6f;
  float temp = fmaxf(sim_temp[0], 0.001f);
  float v = tanhf(sim[idx] / denom / temp);
  logits[idx] += 5.0f * proto_amp[0] * v;
  if (blockIdx.x == 0 && threadIdx.x < B_){
    float a = 1.0f * asw[0];
    fsw_out[threadIdx.x] = a / a;
  }
}

extern "C" void kernel_launch(void* const* d_in, const int* in_sizes, int n_in,
                              void* d_out, int out_size, void* d_ws, size_t ws_size,
                              hipStream_t stream){
  const float* x_low   = (const float*)d_in[0];
  const float* x_high  = (const float*)d_in[1];
  const float* temb    = (const float*)d_in[2];
  const float* pl_w    = (const float*)d_in[3];
  const float* pl_g    = (const float*)d_in[4];
  const float* pl_b    = (const float*)d_in[5];
  const float* ph_w    = (const float*)d_in[6];
  const float* ph_g    = (const float*)d_in[7];
  const float* ph_b    = (const float*)d_in[8];
  const float* fu_w    = (const float*)d_in[9];
  const float* fu_g    = (const float*)d_in[10];
  const float* fu_b    = (const float*)d_in[11];
  const float* pi_w1   = (const float*)d_in[12];
  const float* pi_b1   = (const float*)d_in[13];
  const float* pi_w2   = (const float*)d_in[14];
  const float* pi_b2   = (const float*)d_in[15];
  const float* se_w1   = (const float*)d_in[16];
  const float* se_b1   = (const float*)d_in[17];
  const float* se_g    = (const float*)d_in[18];
  const float* se_be   = (const float*)d_in[19];
  const float* se_w2   = (const float*)d_in[20];
  const float* se_b2   = (const float*)d_in[21];
  const float* at_in_w = (const float*)d_in[22];
  const float* at_in_b = (const float*)d_in[23];
  const float* at_out_w= (const float*)d_in[24];
  const float* at_out_b= (const float*)d_in[25];
  const float* pf_w    = (const float*)d_in[26];
  const float* pf_b    = (const float*)d_in[27];
  const float* asw     = (const float*)d_in[32];
  const float* eg_w1   = (const float*)d_in[33];
  const float* eg_b1   = (const float*)d_in[34];
  const float* eg_w2   = (const float*)d_in[35];
  const float* eg_b2   = (const float*)d_in[36];
  const float* ewg_w   = (const float*)d_in[37];
  const float* ewg_b   = (const float*)d_in[38];
  const float* hd_w1   = (const float*)d_in[39];
  const float* hd_b1   = (const float*)d_in[40];
  const float* hd_g    = (const float*)d_in[41];
  const float* hd_be   = (const float*)d_in[42];
  const float* hd_w2   = (const float*)d_in[43];
  const float* hd_b2   = (const float*)d_in[44];
  const float* eis     = (const float*)d_in[45];
  const float* sim_temp= (const float*)d_in[46];
  const float* proto_amp=(const float*)d_in[47];
  const int*   task_ids= (const int*)d_in[48];

  float* ws = (float*)d_ws;
  const size_t BIG = (size_t)B_ * C_ * HW_; // 8,388,608
  float* S0 = ws;
  float* S1 = ws + BIG;
  float* S2 = ws + 2 * BIG;
  float* scores = ws + 3 * BIG;              // B*8*HW = 524288
  float* sm = scores + (size_t)B_ * 8 * HW_;
  float* sim     = sm;             sm += (size_t)B_ * HW_;
  float* factor  = sm;             sm += (size_t)B_ * HW_;
  float* logitsb = sm;             sm += (size_t)B_ * HW_;
  float* psA = sm; sm += 1024; float* pqA = sm; sm += 1024;
  float* psB = sm; sm += 1024; float* pqB = sm; sm += 1024;
  float* psC = sm; sm += 1024; float* pqC = sm; sm += 1024;
  float* psD = sm; sm += 256;  float* pqD = sm; sm += 256;   // dummy (ph64 stats unused)
  float* ps3 = sm; sm += 2048; float* pq3 = sm; sm += 2048;
  float* psH = sm; sm += 2048; float* pqH = sm; sm += 2048;
  float* gmA = sm; sm += 4;  float* giA = sm; sm += 4;
  float* gmB = sm; sm += 4;  float* giB = sm; sm += 4;
  float* gmC = sm; sm += 4;  float* giC = sm; sm += 4;
  float* gm3 = sm; sm += 16; float* gi3 = sm; sm += 16;
  float* gmH = sm; sm += 4;  float* giH = sm; sm += 4;
  float* pinitb  = sm;             sm += 1024;
  float* fgb     = sm;             sm += 512;
  float* bgb     = sm;             sm += 512;
  float* qkvecb  = sm;             sm += 4096;
  float* kdotb   = sm;             sm += 32;
  float* pmb     = sm;             sm += 256;
  float* pzb     = sm;             sm += 256;
  float* wsum4b  = sm;             sm += 16384;
  float* eg1b    = sm;             sm += 1024;
  float* ewb     = sm;             sm += 32;
  float* weffb   = sm;             sm += 4608;
  float* psimb   = sm;             sm += 1024;
  float* wTph    = sm;             sm += 128 * 128;
  float* wTpl    = sm;             sm += 64 * 64;
  float* wTfu    = sm;             sm += 192 * 128;
  float* wTse    = sm;             sm += 128 * 128;

  float* pred_out = (float*)d_out;                       // 4*512*512
  float* y_out    = pred_out + (size_t)B_ * 512 * 512;   // 4*128*128*128
  float* fsw_out  = y_out + BIG;                         // 4

  dim3 blk(256);
  const float* NF = nullptr;
  float* NFm = nullptr;

  // 0. merged weight transposes
  k_wtall<<<240, blk, 0, stream>>>(ph_w, pl_w, fu_w, se_w2, wTph, wTpl, wTfu, wTse);
  // 1. DUAL gemm: ph at 64x64 (x_high -> S0[0:2.1M]) || pl at 128x128 (x_low -> S2)
  //    (resize commutes with 1x1 conv: conv(resize(x)) == resize(conv(x)))
  k_gemm_dual<<<dim3(B_, 320), blk, 0, stream>>>(x_high, wTph, S0, psD, pqD,
                                                 x_low, wTpl, S2, psB, pqB);
  // 2. resize ph64 -> S1 (128x128) + GN stats partials for A (over resized tensor)
  k_resize_stat<<<dim3(B_, 256), blk, 0, stream>>>(S0, S1, psA, pqA);
  k_stat2_dual<<<8, 128, 0, stream>>>(psA, pqA, gmA, giA, (float)(128 * HW_),
                                      psB, pqB, gmB, giB, (float)(64 * HW_));
  // 3. fu conv: concat(gelu(gn(S1)), gelu(gn(S2 low))) -> S0
  k_gemm1x1<128,192><<<dim3(B_, 256), blk, 0, stream>>>(S1, S2, 128, wTfu, NF,
      gmA,giA,ph_g,ph_b,7,1, gmB,giB,pl_g,pl_b,6,1, S0, psC, pqC);
  k_stat2<<<B_, 128, 0, stream>>>(psC, pqC, gmC, giC, 256, (float)(128 * HW_));
  // 4. se grouped conv3x3 (column-scalar) on x=gelu(gn(S0)) -> S2, GN(4) stats
  k_se3<<<dim3(B_ * 32, 16), blk, 0, stream>>>(S0, gmC, giC, fu_g, fu_b,
      se_w1, se_b1, S2, ps3, pq3);
  k_stat2<<<B_ * 4, 128, 0, stream>>>(ps3, pq3, gm3, gi3, 128, (float)(32 * HW_));
  // 5. se conv1x1 on gelu(gn4(S2)) (+bias) -> S1 = sf
  k_gemm1x1<128,128><<<dim3(B_, 256), blk, 0, stream>>>(S2, NF, 128, wTse, se_b2,
      gm3,gi3,se_g,se_be,5,4, NF,NF,NF,NF,0,0, S1, NFm, NFm);
  // 6. prototypes + folded q
  k_pinit<<<B_, blk, 0, stream>>>(temb, pi_w1, pi_b1, pi_w2, pi_b2, pinitb);
  k_protos<<<1, blk, 0, stream>>>(pinitb, task_ids, fgb, bgb);
  k_qk<<<B_, blk, 0, stream>>>(fgb, bgb, at_in_w, at_in_b, qkvecb, kdotb);
  // 7. fused sim+factor+scores+|sim| partials (c-split, grid (B,256))
  k_simscores<<<dim3(B_, 256), blk, 0, stream>>>(S1, fgb, bgb, qkvecb, kdotb,
                                                 sim, factor, scores, psimb);
  // 8. softmax stats partials (32x8 blocks) + weighted sums (combine inline)
  k_smpart<<<dim3(B_ * 8, 8), blk, 0, stream>>>(scores, pmb, pzb);
  k_wsum<<<dim3(B_ * C_, 4), blk, 0, stream>>>(S1, scores, pmb, pzb, wsum4b);
  // 9. small head chain + w_eff
  k_small<<<B_, blk, 0, stream>>>(wsum4b, at_in_w, at_in_b, at_out_w, at_out_b,
                                  pf_w, pf_b, eg_w1, eg_b1, ewg_w, ewg_b, eg1b, ewb);
  k_weff<<<dim3(B_, 5), blk, 0, stream>>>(eg1b, ewb, eg_w2, eg_b2, eis, weffb);
  // 10. fused x_enh -> y -> h (x = fu raw out = S0; h -> S2)
  k_ydw<<<dim3(B_ * C_, 4), blk, 0, stream>>>(S0, factor, gmC, giC, fu_g, fu_b,
      weffb, hd_w1, hd_b1, y_out, S2, psH, pqH);
  k_stat2<<<B_, 128, 0, stream>>>(psH, pqH, gmH, giH, 512, (float)(128 * HW_));
  // 11. logits (c-split, grid (B,256))
  k_logits<<<dim3(B_, 256), blk, 0, stream>>>(S2, gmH, giH, hd_g, hd_be, hd_w2, hd_b2,
                                              task_ids, logitsb);
  // 12. sim scaling + fsw
  k_final<<<(unsigned)((size_t)B_ * HW_ / 256), blk, 0, stream>>>(logitsb, sim, psimb,
                                                                  sim_temp, proto_amp,
                                                                  asw, fsw_out);
  // 13. resize logits 128->512 -> pred
  k_resize<<<(unsigned)((size_t)B_ * 512 * 512 / 256), blk, 0, stream>>>(logitsb, pred_out,
                                                                          B_, 128, 128, 512, 512);
}